// Round 5
// baseline (167.039 us; speedup 1.0000x reference)
//
#include <hip/hip_runtime.h>

#define NDIM 128
#define NOBS 16
#define LOG2E 1.44269504088896341f

__device__ __forceinline__ float frcp(float x) { return __builtin_amdgcn_rcpf(x); }
__device__ __forceinline__ float fexp2(float x) { return __builtin_amdgcn_exp2f(x); }
__device__ __forceinline__ float fexp(float x) { return __builtin_amdgcn_exp2f(x * LOG2E); }
__device__ __forceinline__ float sigf(float v) { return frcp(1.0f + fexp(-v)); }
__device__ __forceinline__ float siluf(float v) { return v * sigf(v); }
__device__ __forceinline__ float dsiluf(float v) {
    float s = sigf(v);
    return s * (1.0f + v * (1.0f - s));
}

// ---------------------------------------------------------------------------
// Kernel 1: H-module gradient. One block = 4 rows (half a batch), 256 threads.
// tl = tid&127 owns dim tl; tg = tid>>7 owns rows 2*tg, 2*tg+1 (local).
// 1024 blocks -> 50% device. LDS ~20KB (h/z aliased; KVQ buffer reused as D).
// Writes dHdz (512 x 16) into d_out staging; kernel 2 overwrites with u.
// ---------------------------------------------------------------------------
__global__ __launch_bounds__(256) void k_hgrad(
    const float* __restrict__ x,
    const float* __restrict__ Win, const float* __restrict__ bin,
    const float* __restrict__ Aq, const float* __restrict__ Ak, const float* __restrict__ Av,
    const float* __restrict__ Bq, const float* __restrict__ Bk, const float* __restrict__ Bv,
    const float* __restrict__ Wout, const float* __restrict__ bout,
    float* __restrict__ dHdz)
{
    const int blk = blockIdx.x;          // 0..1023
    const int b   = blk >> 1;            // batch
    const int hb  = blk & 1;             // which 4-row half of the batch
    const int tid = threadIdx.x;
    const int tl  = tid & 127;
    const int tg  = tid >> 7;
    const int wid = tid >> 6;            // wave 0..3
    const int r0  = tg * 2;              // local row base (2 rows per thread)

    __shared__ float  sx[4][NOBS];
    __shared__ float  shz[4][NDIM];      // h (stages A-B), then z
    __shared__ float4 sA[4][NDIM];       // {K,V,K*V,Qe} then {dQp,dKp,dVp,0}
    __shared__ float4 sC[4][NDIM];       // {wt, wt*Q, wt*Q*t, Qe}
    __shared__ float  sy[4][26], swp[4][26], sdwp[4][26];
    __shared__ float  skmax[4][2], skmin[4][2];
    __shared__ float  sred[4][2][2];

    if (tid < 64) sx[tid >> 4][tid & 15] = x[(b * 8 + hb * 4) * NOBS + tid];
    __syncthreads();

    // ---- stage A: h[r] = silu(x[r] @ Win + bin) ----
    float hp[2];
    {
        float acc[2];
        const float b0 = bin[tl];
        acc[0] = b0; acc[1] = b0;
        #pragma unroll
        for (int o = 0; o < NOBS; ++o) {
            const float w = Win[o * NDIM + tl];
            acc[0] = fmaf(w, sx[r0][o], acc[0]);
            acc[1] = fmaf(w, sx[r0 + 1][o], acc[1]);
        }
        hp[0] = acc[0]; hp[1] = acc[1];
        shz[r0][tl]     = siluf(acc[0]);
        shz[r0 + 1][tl] = siluf(acc[1]);
    }
    __syncthreads();

    // ---- stage B: Q,K,V = silu(A h + B), 2 rows per weight load ----
    float Qp[2], Kp[2], Vp[2], Qv[2], Kv[2], Vv[2], Qe[2];
    {
        float aq[2], ak[2], av[2];
        const float bq = Bq[tl], bk = Bk[tl], bv = Bv[tl];
        aq[0] = aq[1] = bq; ak[0] = ak[1] = bk; av[0] = av[1] = bv;
        const float4* Aq4 = (const float4*)(Aq + tl * NDIM);
        const float4* Ak4 = (const float4*)(Ak + tl * NDIM);
        const float4* Av4 = (const float4*)(Av + tl * NDIM);
        #pragma unroll 4
        for (int c = 0; c < NDIM / 4; ++c) {
            const float4 wq = Aq4[c], wk = Ak4[c], wv = Av4[c];
            #pragma unroll
            for (int r = 0; r < 2; ++r) {
                const float4 h4 = *(const float4*)&shz[r0 + r][4 * c];
                aq[r] = fmaf(wq.x, h4.x, aq[r]); aq[r] = fmaf(wq.y, h4.y, aq[r]);
                aq[r] = fmaf(wq.z, h4.z, aq[r]); aq[r] = fmaf(wq.w, h4.w, aq[r]);
                ak[r] = fmaf(wk.x, h4.x, ak[r]); ak[r] = fmaf(wk.y, h4.y, ak[r]);
                ak[r] = fmaf(wk.z, h4.z, ak[r]); ak[r] = fmaf(wk.w, h4.w, ak[r]);
                av[r] = fmaf(wv.x, h4.x, av[r]); av[r] = fmaf(wv.y, h4.y, av[r]);
                av[r] = fmaf(wv.z, h4.z, av[r]); av[r] = fmaf(wv.w, h4.w, av[r]);
            }
        }
        float kmx[2], kmn[2];
        #pragma unroll
        for (int r = 0; r < 2; ++r) {
            Qp[r] = aq[r]; Kp[r] = ak[r]; Vp[r] = av[r];
            Qv[r] = siluf(aq[r]); Kv[r] = siluf(ak[r]); Vv[r] = siluf(av[r]);
            Qe[r] = Qv[r] * LOG2E;
            sA[r0 + r][tl] = make_float4(Kv[r], Vv[r], Kv[r] * Vv[r], Qe[r]);
            kmx[r] = Kv[r]; kmn[r] = Kv[r];
        }
        #pragma unroll
        for (int off = 32; off; off >>= 1) {
            #pragma unroll
            for (int r = 0; r < 2; ++r) {
                kmx[r] = fmaxf(kmx[r], __shfl_xor(kmx[r], off));
                kmn[r] = fminf(kmn[r], __shfl_xor(kmn[r], off));
            }
        }
        if ((tid & 63) == 0) {
            skmax[wid][0] = kmx[0]; skmax[wid][1] = kmx[1];
            skmin[wid][0] = kmn[0]; skmin[wid][1] = kmn[1];
        }
    }
    __syncthreads();

    // ---- forward softmax (+ dQ sums folded), log2 domain ----
    float mi2[2], rl[2], ti[2], sk[2], skv[2];
    {
        float l[2], tn[2];
        #pragma unroll
        for (int r = 0; r < 2; ++r) {
            const float kx = fmaxf(skmax[2 * tg][r], skmax[2 * tg + 1][r]);
            const float kn = fminf(skmin[2 * tg][r], skmin[2 * tg + 1][r]);
            mi2[r] = fmaxf(Qe[r] * kx, Qe[r] * kn);   // exact upper bound of log2-logits
            l[r] = 0.f; tn[r] = 0.f; sk[r] = 0.f; skv[r] = 0.f;
        }
        #pragma unroll 2
        for (int j = 0; j < NDIM; ++j) {
            #pragma unroll
            for (int r = 0; r < 2; ++r) {
                const float4 kv4 = sA[r0 + r][j];
                const float e = fexp2(fmaf(Qe[r], kv4.x, -mi2[r]));
                l[r] += e;
                tn[r]  = fmaf(e, kv4.y, tn[r]);
                sk[r]  = fmaf(e, kv4.x, sk[r]);
                skv[r] = fmaf(e, kv4.z, skv[r]);
            }
        }
        #pragma unroll
        for (int r = 0; r < 2; ++r) {
            rl[r] = frcp(l[r]);
            ti[r] = tn[r] * rl[r];
            shz[r0 + r][tl] = siluf(ti[r]);   // z overwrites h (dead)
        }
    }
    __syncthreads();

    // ---- y = silu(z @ Wout + bout), 4x25 tasks ----
    if (tid < 100) {
        const int r = tid / 25, o = tid - 25 * (tid / 25);
        float a = bout[o];
        #pragma unroll 8
        for (int c = 0; c < NDIM / 4; ++c) {
            const float4 z4 = *(const float4*)&shz[r][4 * c];
            a = fmaf(z4.x, Wout[(4 * c + 0) * 25 + o], a);
            a = fmaf(z4.y, Wout[(4 * c + 1) * 25 + o], a);
            a = fmaf(z4.z, Wout[(4 * c + 2) * 25 + o], a);
            a = fmaf(z4.w, Wout[(4 * c + 3) * 25 + o], a);
        }
        swp[r][o] = a;
        sy[r][o] = siluf(a);
    }
    __syncthreads();

    // ---- backward through the quadratic head ----
    if (tid < 100) {
        const int r = tid / 25, o = tid - 25 * (tid / 25);
        float m11 = 0.f, m12 = 0.f, m21 = 0.f, m22 = 0.f;
        for (int k = 0;  k < 5;  ++k) m11 += sy[r][k] * sy[r][k];
        for (int k = 5;  k < 10; ++k) m12 += sy[r][k] * sy[r][k];
        for (int k = 10; k < 15; ++k) m21 += sy[r][k] * sy[r][k];
        for (int k = 15; k < 20; ++k) m22 += sy[r][k] * sy[r][k];
        const float q0 = sy[r][0], q1 = sy[r][1], q2 = sy[r][2], q3 = sy[r][3];
        const float dm11 = q0 * q0 + q1 * q1;
        const float dm12 = q0 * q2 + q1 * q3;
        const float dm22 = q2 * q2 + q3 * q3;
        float dy;
        if      (o < 5)  dy = 2.0f * sy[r][o] * dm11;
        else if (o < 15) dy = 2.0f * sy[r][o] * dm12;
        else if (o < 20) dy = 2.0f * sy[r][o] * dm22;
        else             dy = 2.0f * sy[r][o];
        const float ms = m12 + m21;
        if (o == 0) dy += 2.0f * m11 * q0 + ms * q2;
        if (o == 1) dy += 2.0f * m11 * q1 + ms * q3;
        if (o == 2) dy += ms * q0 + 2.0f * m22 * q2;
        if (o == 3) dy += ms * q1 + 2.0f * m22 * q3;
        sdwp[r][o] = dy * dsiluf(swp[r][o]);
    }
    __syncthreads();

    // ---- dt, closed-form dQ, coefficient pack (2^-m folded) ----
    float dQp_[2];
    {
        float wr[25];
        #pragma unroll
        for (int k = 0; k < 25; ++k) wr[k] = Wout[tl * 25 + k];
        float dt[2] = {0.f, 0.f};
        #pragma unroll
        for (int k = 0; k < 25; ++k) {
            dt[0] = fmaf(wr[k], sdwp[r0][k], dt[0]);
            dt[1] = fmaf(wr[k], sdwp[r0 + 1][k], dt[1]);
        }
        #pragma unroll
        for (int r = 0; r < 2; ++r) {
            dt[r] *= dsiluf(ti[r]);
            const float w = dt[r] * rl[r];
            dQp_[r] = (w * fmaf(-ti[r], sk[r], skv[r])) * dsiluf(Qp[r]);
            const float wt = w * fexp2(-mi2[r]);
            const float c1 = wt * Qv[r];
            sC[r0 + r][tl] = make_float4(wt, c1, c1 * ti[r], Qe[r]);
        }
    }
    __syncthreads();

    // ---- backward dK_j / dV_j: e' = 2^(Qe_i * K_j), coeffs carry 2^-m_i ----
    {
        float accv[2] = {0.f, 0.f}, k1[2] = {0.f, 0.f}, k2[2] = {0.f, 0.f};
        #pragma unroll 2
        for (int i = 0; i < NDIM; ++i) {
            #pragma unroll
            for (int r = 0; r < 2; ++r) {
                const float4 c4 = sC[r0 + r][i];
                const float e = fexp2(c4.w * Kv[r]);
                accv[r] = fmaf(e, c4.x, accv[r]);
                k1[r]   = fmaf(e, c4.y, k1[r]);
                k2[r]   = fmaf(e, c4.z, k2[r]);
            }
        }
        #pragma unroll
        for (int r = 0; r < 2; ++r) {
            const float dVp_ = accv[r] * dsiluf(Vp[r]);
            const float dKp_ = fmaf(Vv[r], k1[r], -k2[r]) * dsiluf(Kp[r]);
            sA[r0 + r][tl] = make_float4(dQp_[r], dKp_, dVp_, 0.f);  // reuse as D
        }
    }
    __syncthreads();

    // ---- dh_d = sum_i Aq[i][d]dQp + Ak[i][d]dKp + Av[i][d]dVp ----
    float dhp[2];
    {
        float acc[2] = {0.f, 0.f};
        #pragma unroll 4
        for (int i = 0; i < NDIM; ++i) {
            const float aqv = Aq[i * NDIM + tl];
            const float akv = Ak[i * NDIM + tl];
            const float avv = Av[i * NDIM + tl];
            #pragma unroll
            for (int r = 0; r < 2; ++r) {
                const float4 d4 = sA[r0 + r][i];
                acc[r] = fmaf(aqv, d4.x, acc[r]);
                acc[r] = fmaf(akv, d4.y, acc[r]);
                acc[r] = fmaf(avv, d4.z, acc[r]);
            }
        }
        dhp[0] = acc[0] * dsiluf(hp[0]);
        dhp[1] = acc[1] * dsiluf(hp[1]);
    }

    // ---- dx_o (o=0,1): shuffle reduce per row, cross-wave combine ----
    {
        const float w0 = Win[tl], w1 = Win[NDIM + tl];
        float t0[2], t1[2];
        #pragma unroll
        for (int r = 0; r < 2; ++r) { t0[r] = w0 * dhp[r]; t1[r] = w1 * dhp[r]; }
        #pragma unroll
        for (int off = 32; off; off >>= 1) {
            #pragma unroll
            for (int r = 0; r < 2; ++r) {
                t0[r] += __shfl_xor(t0[r], off);
                t1[r] += __shfl_xor(t1[r], off);
            }
        }
        if ((tid & 63) == 0) {
            #pragma unroll
            for (int r = 0; r < 2; ++r) { sred[wid][r][0] = t0[r]; sred[wid][r][1] = t1[r]; }
        }
    }
    __syncthreads();
    if (tid < 8) {
        const int o = tid >> 2, q = tid & 3;       // q = local row 0..3
        const int wb = (q >> 1) * 2, rr = q & 1;   // wave-pair base, row-in-pair
        dHdz[b * 16 + o * 8 + hb * 4 + q] = sred[wb][rr][o] + sred[wb + 1][rr][o];
    }
}

// ---------------------------------------------------------------------------
// Kernel 2: one batch per 512-thread block; J on tids 0-255, R on 256-511.
// Within a group: half = agents 4/4 split (stages A,B), j-range 64/64 split
// (stage C). Global-bound shift makes the softmax merge a pure addition.
// `inout` holds dHdz on entry; overwritten with u.
// ---------------------------------------------------------------------------
__global__ __launch_bounds__(512) void k_jr(
    const float* __restrict__ x,
    const float* __restrict__ JWin, const float* __restrict__ Jbin,
    const float* __restrict__ JAq, const float* __restrict__ JAk, const float* __restrict__ JAv,
    const float* __restrict__ JBq, const float* __restrict__ JBk, const float* __restrict__ JBv,
    const float* __restrict__ JWout, const float* __restrict__ Jbout,
    const float* __restrict__ RWin, const float* __restrict__ Rbin,
    const float* __restrict__ RAq, const float* __restrict__ RAk, const float* __restrict__ RAv,
    const float* __restrict__ RBq, const float* __restrict__ RBk, const float* __restrict__ RBv,
    const float* __restrict__ RWout, const float* __restrict__ Rbout,
    float* __restrict__ inout)
{
    __shared__ float  sx[128];
    __shared__ float  sh[2][NDIM][8];     // [g][dim][agent]
    __shared__ float  sQ[2][NDIM][8];     // Qe (prescaled by log2e)
    __shared__ float  sK[2][NDIM][8];
    __shared__ float  sV[2][NDIM][8];
    __shared__ float  skr[2][4][2][4];    // [g][wave-in-group][max/min][local agent]
    __shared__ float  st1[2][8][NDIM];    // half-1 partial t
    __shared__ float  sl1[2][NDIM];       // half-1 partial l
    __shared__ float  sz[2][8][NDIM];
    __shared__ float  sw[2][NDIM];
    __shared__ float  sJv;
    __shared__ double sdH[16], sg[32], sRm[16][17], srs[16], svv[16];

    const int b    = blockIdx.x;
    const int tid  = threadIdx.x;
    const int g    = tid >> 8;       // 0 = J, 1 = R
    const int sub  = tid & 255;
    const int half = sub >> 7;       // agent / j-range half
    const int tl   = sub & 127;      // dim / attention row
    const int w2   = sub >> 6;       // wave within group (0..3)
    const int a0   = half * 4;

    if (tid < 128) sx[tid] = x[b * 128 + tid];
    else if (tid < 144) sdH[tid - 128] = (double)inout[b * 16 + (tid - 128)];
    __syncthreads();

    const float* Win  = g ? RWin  : JWin;
    const float* bin_ = g ? Rbin  : Jbin;
    const float* Aq   = g ? RAq   : JAq;
    const float* Ak   = g ? RAk   : JAk;
    const float* Av   = g ? RAv   : JAv;
    const float* Bq   = g ? RBq   : JBq;
    const float* Bk   = g ? RBk   : JBk;
    const float* Bv   = g ? RBv   : JBv;

    // ---- stage A: h[a][tl] for 4 agents ----
    {
        float acc[4];
        const float b0 = bin_[tl];
        acc[0] = acc[1] = acc[2] = acc[3] = b0;
        #pragma unroll
        for (int c = 0; c < 4; ++c) {
            const float w0 = Win[(4 * c + 0) * NDIM + tl];
            const float w1 = Win[(4 * c + 1) * NDIM + tl];
            const float w2_ = Win[(4 * c + 2) * NDIM + tl];
            const float w3 = Win[(4 * c + 3) * NDIM + tl];
            #pragma unroll
            for (int a = 0; a < 4; ++a) {
                const float4 x4 = *(const float4*)&sx[(a0 + a) * NOBS + 4 * c];
                acc[a] = fmaf(w0, x4.x, acc[a]);
                acc[a] = fmaf(w1, x4.y, acc[a]);
                acc[a] = fmaf(w2_, x4.z, acc[a]);
                acc[a] = fmaf(w3, x4.w, acc[a]);
            }
        }
        *(float4*)&sh[g][tl][a0] =
            make_float4(siluf(acc[0]), siluf(acc[1]), siluf(acc[2]), siluf(acc[3]));
    }
    __syncthreads();

    // ---- stage B: Q,K,V for dim tl, 4 agents ----
    {
        float aq[4], ak[4], av[4];
        const float bq = Bq[tl], bk = Bk[tl], bv = Bv[tl];
        #pragma unroll
        for (int s = 0; s < 4; ++s) { aq[s] = bq; ak[s] = bk; av[s] = bv; }
        const float4* Aq4 = (const float4*)(Aq + tl * NDIM);
        const float4* Ak4 = (const float4*)(Ak + tl * NDIM);
        const float4* Av4 = (const float4*)(Av + tl * NDIM);
        #pragma unroll 2
        for (int c = 0; c < NDIM / 4; ++c) {
            const float4 wq = Aq4[c], wk = Ak4[c], wv = Av4[c];
            const float wqa[4] = {wq.x, wq.y, wq.z, wq.w};
            const float wka[4] = {wk.x, wk.y, wk.z, wk.w};
            const float wva[4] = {wv.x, wv.y, wv.z, wv.w};
            #pragma unroll
            for (int jj = 0; jj < 4; ++jj) {
                const float4 h4 = *(const float4*)&sh[g][4 * c + jj][a0];
                const float q = wqa[jj], k = wka[jj], v = wva[jj];
                aq[0] = fmaf(q, h4.x, aq[0]); aq[1] = fmaf(q, h4.y, aq[1]);
                aq[2] = fmaf(q, h4.z, aq[2]); aq[3] = fmaf(q, h4.w, aq[3]);
                ak[0] = fmaf(k, h4.x, ak[0]); ak[1] = fmaf(k, h4.y, ak[1]);
                ak[2] = fmaf(k, h4.z, ak[2]); ak[3] = fmaf(k, h4.w, ak[3]);
                av[0] = fmaf(v, h4.x, av[0]); av[1] = fmaf(v, h4.y, av[1]);
                av[2] = fmaf(v, h4.z, av[2]); av[3] = fmaf(v, h4.w, av[3]);
            }
        }
        float kk[4], kx[4], kn[4];
        float qe[4], vv[4];
        #pragma unroll
        for (int s = 0; s < 4; ++s) {
            qe[s] = siluf(aq[s]) * LOG2E;
            kk[s] = siluf(ak[s]);
            vv[s] = siluf(av[s]);
            kx[s] = kk[s]; kn[s] = kk[s];
        }
        *(float4*)&sQ[g][tl][a0] = make_float4(qe[0], qe[1], qe[2], qe[3]);
        *(float4*)&sK[g][tl][a0] = make_float4(kk[0], kk[1], kk[2], kk[3]);
        *(float4*)&sV[g][tl][a0] = make_float4(vv[0], vv[1], vv[2], vv[3]);
        #pragma unroll
        for (int off = 32; off; off >>= 1) {
            #pragma unroll
            for (int s = 0; s < 4; ++s) {
                kx[s] = fmaxf(kx[s], __shfl_xor(kx[s], off));
                kn[s] = fminf(kn[s], __shfl_xor(kn[s], off));
            }
        }
        if ((sub & 63) == 0) {
            #pragma unroll
            for (int s = 0; s < 4; ++s) { skr[g][w2][0][s] = kx[s]; skr[g][w2][1][s] = kn[s]; }
        }
    }
    __syncthreads();

    // ---- stage C: attention row tl over j in [64*half, 64*half+64) ----
    float tt0, tt1, tt2, tt3, tt4, tt5, tt6, tt7, lsum;
    {
        const float4 qe0 = *(const float4*)&sQ[g][tl][0];
        const float4 qe1 = *(const float4*)&sQ[g][tl][4];
        const float qe[8] = {qe0.x, qe0.y, qe0.z, qe0.w, qe1.x, qe1.y, qe1.z, qe1.w};
        float bnd2 = 0.f;
        #pragma unroll
        for (int s = 0; s < 8; ++s) {
            const int hs = s >> 2, s4 = s & 3;
            const float kx = fmaxf(skr[g][2 * hs][0][s4], skr[g][2 * hs + 1][0][s4]);
            const float kn = fminf(skr[g][2 * hs][1][s4], skr[g][2 * hs + 1][1][s4]);
            bnd2 += fmaxf(qe[s] * kx, qe[s] * kn);
        }
        lsum = 0.f;
        tt0 = tt1 = tt2 = tt3 = tt4 = tt5 = tt6 = tt7 = 0.f;
        const int jb = half * 64;
        #pragma unroll 2
        for (int jo = 0; jo < 64; ++jo) {
            const int j = jb + jo;
            const float4 k0 = *(const float4*)&sK[g][j][0];
            const float4 k1 = *(const float4*)&sK[g][j][4];
            float d = fmaf(qe[0], k0.x, -bnd2);
            d = fmaf(qe[1], k0.y, d); d = fmaf(qe[2], k0.z, d); d = fmaf(qe[3], k0.w, d);
            d = fmaf(qe[4], k1.x, d); d = fmaf(qe[5], k1.y, d);
            d = fmaf(qe[6], k1.z, d); d = fmaf(qe[7], k1.w, d);
            const float e = fexp2(d);
            const float4 v0 = *(const float4*)&sV[g][j][0];
            const float4 v1 = *(const float4*)&sV[g][j][4];
            lsum += e;
            tt0 = fmaf(e, v0.x, tt0); tt1 = fmaf(e, v0.y, tt1);
            tt2 = fmaf(e, v0.z, tt2); tt3 = fmaf(e, v0.w, tt3);
            tt4 = fmaf(e, v1.x, tt4); tt5 = fmaf(e, v1.y, tt5);
            tt6 = fmaf(e, v1.z, tt6); tt7 = fmaf(e, v1.w, tt7);
        }
        if (half == 1) {
            st1[g][0][tl] = tt0; st1[g][1][tl] = tt1; st1[g][2][tl] = tt2; st1[g][3][tl] = tt3;
            st1[g][4][tl] = tt4; st1[g][5][tl] = tt5; st1[g][6][tl] = tt6; st1[g][7][tl] = tt7;
            sl1[g][tl] = lsum;
        }
    }
    __syncthreads();

    // ---- merge (half 0 threads): partials add directly (same shift) ----
    if (half == 0) {
        const float l = lsum + sl1[g][tl];
        const float rl = frcp(l);
        sz[g][0][tl] = siluf((tt0 + st1[g][0][tl]) * rl);
        sz[g][1][tl] = siluf((tt1 + st1[g][1][tl]) * rl);
        sz[g][2][tl] = siluf((tt2 + st1[g][2][tl]) * rl);
        sz[g][3][tl] = siluf((tt3 + st1[g][3][tl]) * rl);
        sz[g][4][tl] = siluf((tt4 + st1[g][4][tl]) * rl);
        sz[g][5][tl] = siluf((tt5 + st1[g][5][tl]) * rl);
        sz[g][6][tl] = siluf((tt6 + st1[g][6][tl]) * rl);
        sz[g][7][tl] = siluf((tt7 + st1[g][7][tl]) * rl);
    }
    __syncthreads();

    // ---- stage D: w[s,o] = silu(z[s,:] @ Wout[:,o] + bout[o]) ----
    // R tasks (128) on tids 0-127, J tasks (64) on tids 128-191.
    if (tid < 192) {
        const int gm = (tid < 128) ? 1 : 0;
        const int t2 = (tid < 128) ? tid : tid - 128;
        const int lo2 = gm ? 4 : 3;
        const int outd = 1 << lo2;
        const int s = t2 >> lo2, o = t2 & (outd - 1);
        const float* Wo = gm ? RWout : JWout;
        const float* bo = gm ? Rbout : Jbout;
        float a = bo[o];
        #pragma unroll 8
        for (int c = 0; c < NDIM / 4; ++c) {
            const float4 z4 = *(const float4*)&sz[gm][s][4 * c];
            a = fmaf(z4.x, Wo[(4 * c + 0) * outd + o], a);
            a = fmaf(z4.y, Wo[(4 * c + 1) * outd + o], a);
            a = fmaf(z4.z, Wo[(4 * c + 2) * outd + o], a);
            a = fmaf(z4.w, Wo[(4 * c + 3) * outd + o], a);
        }
        sw[gm][t2] = siluf(a);
    }
    __syncthreads();

    // ---- J scalar + R group sums ----
    if (tid < 64) {
        float v = sw[0][tid];
        #pragma unroll
        for (int off = 32; off; off >>= 1) v += __shfl_xor(v, off);
        if (tid == 0) sJv = v;
    } else if (tid < 96) {
        const int t = tid - 64, pq = t >> 3, c = t & 7;
        const int base = c * 16 + pq * 4;
        sg[t] = (double)sw[1][base] + (double)sw[1][base + 1]
              + (double)sw[1][base + 2] + (double)sw[1][base + 3];
    }
    __syncthreads();

    // ---- assembly (tid<256 active; all barriers unconditional) ----
    const int ii = (tid >> 4) & 15, jj = tid & 15;
    if (tid < 256) {
        const double rij = sg[((ii >> 3) * 2 + (jj >> 3)) * 8 + (jj & 7)];
        const double rji = sg[((jj >> 3) * 2 + (ii >> 3)) * 8 + (ii & 7)];
        sRm[ii][jj] = rij * rij + rji * rji;
    }
    __syncthreads();

    if (tid < 16) {
        double a = 0.0;
        for (int j = 0; j < 16; ++j) a += sRm[tid][j];
        srs[tid] = a;
    }
    __syncthreads();

    double vtmp = 0.0;
    if (tid < 256) vtmp = (ii == jj) ? srs[ii] : -sRm[ii][jj];
    __syncthreads();
    if (tid < 256) sRm[ii][jj] = vtmp;
    __syncthreads();

    if (tid < 16) {
        double a = 0.0;
        for (int j = 0; j < 16; ++j) a += sRm[tid][j] * sdH[j];
        svv[tid] = a;
    }
    __syncthreads();

    if (tid < 16) {
        double a = 0.0;
        for (int k = 0; k < 16; ++k) a += sRm[tid][k] * svv[k];
        const double sj = (double)sJv;
        const double jterm = (tid < 8) ? 2.0 * sj * sdH[8 + tid]
                                       : -2.0 * sj * sdH[tid - 8];
        inout[b * 16 + tid] = (float)(jterm - a);
    }
}

// ---------------------------------------------------------------------------
extern "C" void kernel_launch(void* const* d_in, const int* in_sizes, int n_in,
                              void* d_out, int out_size, void* d_ws, size_t ws_size,
                              hipStream_t stream)
{
    const float* x = (const float*)d_in[0];
    float* out = (float*)d_out;

#define ARGS10(base) \
    (const float*)d_in[(base) + 0], (const float*)d_in[(base) + 1], \
    (const float*)d_in[(base) + 2], (const float*)d_in[(base) + 3], \
    (const float*)d_in[(base) + 4], (const float*)d_in[(base) + 5], \
    (const float*)d_in[(base) + 6], (const float*)d_in[(base) + 7], \
    (const float*)d_in[(base) + 8], (const float*)d_in[(base) + 9]

    k_hgrad<<<dim3(1024), dim3(256), 0, stream>>>(x, ARGS10(1), out);
    k_jr<<<dim3(512), dim3(512), 0, stream>>>(x, ARGS10(11), ARGS10(21), out);
#undef ARGS10
}

// Round 6
// 154.011 us; speedup vs baseline: 1.0846x; 1.0846x over previous
//
#include <hip/hip_runtime.h>

#define NDIM 128
#define NOBS 16
#define LOG2E 1.44269504088896341f

__device__ __forceinline__ float frcp(float x) { return __builtin_amdgcn_rcpf(x); }
__device__ __forceinline__ float fexp2(float x) { return __builtin_amdgcn_exp2f(x); }
__device__ __forceinline__ float fexp(float x) { return __builtin_amdgcn_exp2f(x * LOG2E); }
__device__ __forceinline__ float sigf(float v) { return frcp(1.0f + fexp(-v)); }
__device__ __forceinline__ float siluf(float v) { return v * sigf(v); }
__device__ __forceinline__ float dsiluf(float v) {
    float s = sigf(v);
    return s * (1.0f + v * (1.0f - s));
}

// ---- shared-memory views (union -> 26.9 KB/block, 4 blocks/CU) -------------
struct HS {                       // H-gradient path, 23.2 KB
    float  sx[8][NOBS];
    float  shz[8][NDIM];          // h, later z
    float4 sKC[8][NDIM];          // {K,V,K*V,Qe} -> {wt,c1,c2,Qe} -> {dQp,dKp,dVp,0}
    float  sy[8][26], swp[8][26], sdwp[8][26];
    float  skmax[4][4], skmin[4][4];
    float  sred[4][4][2];
};
struct JRS {                      // J/R forward path, 26.3 KB
    float sx[128];
    union { float sh[2][NDIM][8]; float sz[2][8][132]; } hz;  // z aliases h
    float sK[2][NDIM][8];
    float sV[2][NDIM][8];
    float skr[2][2][2][8];        // [g][wave][max/min][agent]
    float sw[2][NDIM];
};
union SU { HS h; JRS jr; };

// ---------------------------------------------------------------------------
// H path: one block = one batch (8 rows), 4 rows per thread-half.
// Writes dHdz(512x16) into out (staging; k_fin overwrites with u).
// ---------------------------------------------------------------------------
__device__ __forceinline__ void h_path(
    int b, int tid, HS& S,
    const float* __restrict__ x,
    const float* __restrict__ Win, const float* __restrict__ bin,
    const float* __restrict__ Aq, const float* __restrict__ Ak, const float* __restrict__ Av,
    const float* __restrict__ Bq, const float* __restrict__ Bk, const float* __restrict__ Bv,
    const float* __restrict__ Wout, const float* __restrict__ bout,
    float* __restrict__ out)
{
    const int tl = tid & 127, tg = tid >> 7, wid = tid >> 6, r0 = tg * 4;

    if (tid < 128) S.sx[tid >> 4][tid & 15] = x[b * 128 + tid];
    __syncthreads();

    // ---- A: h = silu(x @ Win + bin) ----
    float hp[4];
    {
        float acc[4];
        const float b0 = bin[tl];
        #pragma unroll
        for (int r = 0; r < 4; ++r) acc[r] = b0;
        #pragma unroll
        for (int o = 0; o < NOBS; ++o) {
            const float w = Win[o * NDIM + tl];
            #pragma unroll
            for (int r = 0; r < 4; ++r) acc[r] = fmaf(w, S.sx[r0 + r][o], acc[r]);
        }
        #pragma unroll
        for (int r = 0; r < 4; ++r) { hp[r] = acc[r]; S.shz[r0 + r][tl] = siluf(acc[r]); }
    }
    __syncthreads();

    // ---- B: Q,K,V = silu(A h + B), 4 rows per weight load ----
    float Qp[4], Kp[4], Vp[4], Qv[4], Kv[4], Vv[4], Qe[4];
    {
        float aq[4], ak[4], av[4];
        const float bq = Bq[tl], bk = Bk[tl], bv = Bv[tl];
        #pragma unroll
        for (int r = 0; r < 4; ++r) { aq[r] = bq; ak[r] = bk; av[r] = bv; }
        const float4* Aq4 = (const float4*)(Aq + tl * NDIM);
        const float4* Ak4 = (const float4*)(Ak + tl * NDIM);
        const float4* Av4 = (const float4*)(Av + tl * NDIM);
        #pragma unroll 2
        for (int c = 0; c < NDIM / 4; ++c) {
            const float4 wq = Aq4[c], wk = Ak4[c], wv = Av4[c];
            #pragma unroll
            for (int r = 0; r < 4; ++r) {
                const float4 h4 = *(const float4*)&S.shz[r0 + r][4 * c];
                aq[r] = fmaf(wq.x, h4.x, aq[r]); aq[r] = fmaf(wq.y, h4.y, aq[r]);
                aq[r] = fmaf(wq.z, h4.z, aq[r]); aq[r] = fmaf(wq.w, h4.w, aq[r]);
                ak[r] = fmaf(wk.x, h4.x, ak[r]); ak[r] = fmaf(wk.y, h4.y, ak[r]);
                ak[r] = fmaf(wk.z, h4.z, ak[r]); ak[r] = fmaf(wk.w, h4.w, ak[r]);
                av[r] = fmaf(wv.x, h4.x, av[r]); av[r] = fmaf(wv.y, h4.y, av[r]);
                av[r] = fmaf(wv.z, h4.z, av[r]); av[r] = fmaf(wv.w, h4.w, av[r]);
            }
        }
        float kmx[4], kmn[4];
        #pragma unroll
        for (int r = 0; r < 4; ++r) {
            Qp[r] = aq[r]; Kp[r] = ak[r]; Vp[r] = av[r];
            Qv[r] = siluf(aq[r]); Kv[r] = siluf(ak[r]); Vv[r] = siluf(av[r]);
            Qe[r] = Qv[r] * LOG2E;
            S.sKC[r0 + r][tl] = make_float4(Kv[r], Vv[r], Kv[r] * Vv[r], Qe[r]);
            kmx[r] = Kv[r]; kmn[r] = Kv[r];
        }
        #pragma unroll
        for (int off = 32; off; off >>= 1) {
            #pragma unroll
            for (int r = 0; r < 4; ++r) {
                kmx[r] = fmaxf(kmx[r], __shfl_xor(kmx[r], off));
                kmn[r] = fminf(kmn[r], __shfl_xor(kmn[r], off));
            }
        }
        if ((tid & 63) == 0) {
            #pragma unroll
            for (int r = 0; r < 4; ++r) { S.skmax[wid][r] = kmx[r]; S.skmin[wid][r] = kmn[r]; }
        }
    }
    __syncthreads();

    // ---- C: softmax fwd (+ dQ sums folded), log2 domain ----
    float mi2[4], rl[4], ti[4], sk[4], skv[4];
    {
        float l[4], tn[4];
        #pragma unroll
        for (int r = 0; r < 4; ++r) {
            const float kx = fmaxf(S.skmax[2 * tg][r], S.skmax[2 * tg + 1][r]);
            const float kn = fminf(S.skmin[2 * tg][r], S.skmin[2 * tg + 1][r]);
            mi2[r] = fmaxf(Qe[r] * kx, Qe[r] * kn);
            l[r] = 0.f; tn[r] = 0.f; sk[r] = 0.f; skv[r] = 0.f;
        }
        #pragma unroll 2
        for (int j = 0; j < NDIM; ++j) {
            #pragma unroll
            for (int r = 0; r < 4; ++r) {
                const float4 kv4 = S.sKC[r0 + r][j];
                const float e = fexp2(fmaf(Qe[r], kv4.x, -mi2[r]));
                l[r] += e;
                tn[r]  = fmaf(e, kv4.y, tn[r]);
                sk[r]  = fmaf(e, kv4.x, sk[r]);
                skv[r] = fmaf(e, kv4.z, skv[r]);
            }
        }
        #pragma unroll
        for (int r = 0; r < 4; ++r) {
            rl[r] = frcp(l[r]);
            ti[r] = tn[r] * rl[r];
            S.shz[r0 + r][tl] = siluf(ti[r]);   // z overwrites h
        }
    }
    __syncthreads();

    // ---- y = silu(z @ Wout + bout), 8x25 tasks ----
    if (tid < 200) {
        const int r = tid / 25, o = tid - 25 * (tid / 25);
        float a = bout[o];
        #pragma unroll 8
        for (int c = 0; c < NDIM / 4; ++c) {
            const float4 z4 = *(const float4*)&S.shz[r][4 * c];
            a = fmaf(z4.x, Wout[(4 * c + 0) * 25 + o], a);
            a = fmaf(z4.y, Wout[(4 * c + 1) * 25 + o], a);
            a = fmaf(z4.z, Wout[(4 * c + 2) * 25 + o], a);
            a = fmaf(z4.w, Wout[(4 * c + 3) * 25 + o], a);
        }
        S.swp[r][o] = a;
        S.sy[r][o] = siluf(a);
    }
    __syncthreads();

    // ---- backward through the quadratic head ----
    if (tid < 200) {
        const int r = tid / 25, o = tid - 25 * (tid / 25);
        float m11 = 0.f, m12 = 0.f, m21 = 0.f, m22 = 0.f;
        for (int k = 0;  k < 5;  ++k) m11 += S.sy[r][k] * S.sy[r][k];
        for (int k = 5;  k < 10; ++k) m12 += S.sy[r][k] * S.sy[r][k];
        for (int k = 10; k < 15; ++k) m21 += S.sy[r][k] * S.sy[r][k];
        for (int k = 15; k < 20; ++k) m22 += S.sy[r][k] * S.sy[r][k];
        const float q0 = S.sy[r][0], q1 = S.sy[r][1], q2 = S.sy[r][2], q3 = S.sy[r][3];
        const float dm11 = q0 * q0 + q1 * q1;
        const float dm12 = q0 * q2 + q1 * q3;
        const float dm22 = q2 * q2 + q3 * q3;
        float dy;
        if      (o < 5)  dy = 2.0f * S.sy[r][o] * dm11;
        else if (o < 15) dy = 2.0f * S.sy[r][o] * dm12;
        else if (o < 20) dy = 2.0f * S.sy[r][o] * dm22;
        else             dy = 2.0f * S.sy[r][o];
        const float ms = m12 + m21;
        if (o == 0) dy += 2.0f * m11 * q0 + ms * q2;
        if (o == 1) dy += 2.0f * m11 * q1 + ms * q3;
        if (o == 2) dy += ms * q0 + 2.0f * m22 * q2;
        if (o == 3) dy += ms * q1 + 2.0f * m22 * q3;
        S.sdwp[r][o] = dy * dsiluf(S.swp[r][o]);
    }
    __syncthreads();

    // ---- E: dt, closed-form dQ, coefficient pack (overwrites sKC as C) ----
    float dQp_[4];
    {
        float wr[25];
        #pragma unroll
        for (int k = 0; k < 25; ++k) wr[k] = Wout[tl * 25 + k];
        float dt[4] = {0.f, 0.f, 0.f, 0.f};
        #pragma unroll
        for (int k = 0; k < 25; ++k) {
            #pragma unroll
            for (int r = 0; r < 4; ++r)
                dt[r] = fmaf(wr[k], S.sdwp[r0 + r][k], dt[r]);
        }
        #pragma unroll
        for (int r = 0; r < 4; ++r) {
            dt[r] *= dsiluf(ti[r]);
            const float w = dt[r] * rl[r];
            dQp_[r] = (w * fmaf(-ti[r], sk[r], skv[r])) * dsiluf(Qp[r]);
            const float wt = w * fexp2(-mi2[r]);
            const float c1 = wt * Qv[r];
            S.sKC[r0 + r][tl] = make_float4(wt, c1, c1 * ti[r], Qe[r]);
        }
    }
    __syncthreads();

    // ---- F: dK_j / dV_j (reads C; then WAR barrier; writes D in place) ----
    float dD[4][3];
    {
        float accv[4] = {0.f, 0.f, 0.f, 0.f};
        float k1[4] = {0.f, 0.f, 0.f, 0.f};
        float k2[4] = {0.f, 0.f, 0.f, 0.f};
        #pragma unroll 2
        for (int i = 0; i < NDIM; ++i) {
            #pragma unroll
            for (int r = 0; r < 4; ++r) {
                const float4 c4 = S.sKC[r0 + r][i];
                const float e = fexp2(c4.w * Kv[r]);
                accv[r] = fmaf(e, c4.x, accv[r]);
                k1[r]   = fmaf(e, c4.y, k1[r]);
                k2[r]   = fmaf(e, c4.z, k2[r]);
            }
        }
        #pragma unroll
        for (int r = 0; r < 4; ++r) {
            dD[r][0] = dQp_[r];
            dD[r][1] = fmaf(Vv[r], k1[r], -k2[r]) * dsiluf(Kp[r]);
            dD[r][2] = accv[r] * dsiluf(Vp[r]);
        }
    }
    __syncthreads();
    #pragma unroll
    for (int r = 0; r < 4; ++r)
        S.sKC[r0 + r][tl] = make_float4(dD[r][0], dD[r][1], dD[r][2], 0.f);
    __syncthreads();

    // ---- G: dh_d = sum_i Aq[i][d]dQp + Ak[i][d]dKp + Av[i][d]dVp ----
    float dhp[4];
    {
        float acc[4] = {0.f, 0.f, 0.f, 0.f};
        #pragma unroll 4
        for (int i = 0; i < NDIM; ++i) {
            const float aqv = Aq[i * NDIM + tl];
            const float akv = Ak[i * NDIM + tl];
            const float avv = Av[i * NDIM + tl];
            #pragma unroll
            for (int r = 0; r < 4; ++r) {
                const float4 d4 = S.sKC[r0 + r][i];
                acc[r] = fmaf(aqv, d4.x, acc[r]);
                acc[r] = fmaf(akv, d4.y, acc[r]);
                acc[r] = fmaf(avv, d4.z, acc[r]);
            }
        }
        #pragma unroll
        for (int r = 0; r < 4; ++r) dhp[r] = acc[r] * dsiluf(hp[r]);
    }

    // ---- dx_o (o=0,1): shuffle reduce per row, cross-wave combine ----
    {
        const float w0 = Win[tl], w1 = Win[NDIM + tl];
        float t0[4], t1[4];
        #pragma unroll
        for (int r = 0; r < 4; ++r) { t0[r] = w0 * dhp[r]; t1[r] = w1 * dhp[r]; }
        #pragma unroll
        for (int off = 32; off; off >>= 1) {
            #pragma unroll
            for (int r = 0; r < 4; ++r) {
                t0[r] += __shfl_xor(t0[r], off);
                t1[r] += __shfl_xor(t1[r], off);
            }
        }
        if ((tid & 63) == 0) {
            #pragma unroll
            for (int r = 0; r < 4; ++r) { S.sred[wid][r][0] = t0[r]; S.sred[wid][r][1] = t1[r]; }
        }
    }
    __syncthreads();
    if (tid < 16) {
        const int o = tid >> 3, ag = tid & 7;
        const int gg = ag >> 2, rr = ag & 3;
        out[b * 16 + o * 8 + ag] = S.sred[2 * gg][rr][o] + S.sred[2 * gg + 1][rr][o];
    }
}

// ---------------------------------------------------------------------------
// JR path: one block = one batch; J on tids 0-127, R on 128-255; one thread =
// one dim, all 8 agents (Q in registers). Writes g[32] + Jv to ws (doubles).
// ---------------------------------------------------------------------------
__device__ __forceinline__ void jr_path(
    int b, int tid, JRS& S,
    const float* __restrict__ x,
    const float* __restrict__ JWin, const float* __restrict__ Jbin,
    const float* __restrict__ JAq, const float* __restrict__ JAk, const float* __restrict__ JAv,
    const float* __restrict__ JBq, const float* __restrict__ JBk, const float* __restrict__ JBv,
    const float* __restrict__ JWout, const float* __restrict__ Jbout,
    const float* __restrict__ RWin, const float* __restrict__ Rbin,
    const float* __restrict__ RAq, const float* __restrict__ RAk, const float* __restrict__ RAv,
    const float* __restrict__ RBq, const float* __restrict__ RBk, const float* __restrict__ RBv,
    const float* __restrict__ RWout, const float* __restrict__ Rbout,
    double* __restrict__ ws)
{
    const int g  = tid >> 7;
    const int tl = tid & 127;
    const int wg = (tid >> 6) & 1;

    if (tid < 128) S.sx[tid] = x[b * 128 + tid];
    __syncthreads();

    const float* Win  = g ? RWin  : JWin;
    const float* bin_ = g ? Rbin  : Jbin;
    const float* Aq   = g ? RAq   : JAq;
    const float* Ak   = g ? RAk   : JAk;
    const float* Av   = g ? RAv   : JAv;
    const float* Bq   = g ? RBq   : JBq;
    const float* Bk   = g ? RBk   : JBk;
    const float* Bv   = g ? RBv   : JBv;

    // ---- A: h[a][tl] for all 8 agents ----
    {
        float acc[8];
        const float b0 = bin_[tl];
        #pragma unroll
        for (int a = 0; a < 8; ++a) acc[a] = b0;
        #pragma unroll
        for (int c = 0; c < 4; ++c) {
            const float w0 = Win[(4 * c + 0) * NDIM + tl];
            const float w1 = Win[(4 * c + 1) * NDIM + tl];
            const float w2 = Win[(4 * c + 2) * NDIM + tl];
            const float w3 = Win[(4 * c + 3) * NDIM + tl];
            #pragma unroll
            for (int a = 0; a < 8; ++a) {
                const float4 x4 = *(const float4*)&S.sx[a * 16 + 4 * c];
                acc[a] = fmaf(w0, x4.x, acc[a]);
                acc[a] = fmaf(w1, x4.y, acc[a]);
                acc[a] = fmaf(w2, x4.z, acc[a]);
                acc[a] = fmaf(w3, x4.w, acc[a]);
            }
        }
        *(float4*)&S.hz.sh[g][tl][0] =
            make_float4(siluf(acc[0]), siluf(acc[1]), siluf(acc[2]), siluf(acc[3]));
        *(float4*)&S.hz.sh[g][tl][4] =
            make_float4(siluf(acc[4]), siluf(acc[5]), siluf(acc[6]), siluf(acc[7]));
    }
    __syncthreads();

    // ---- B: Q (regs, log2-scaled), K, V (LDS); all 8 agents ----
    float Qe[8];
    {
        float aq[8], ak[8], av[8];
        const float bq = Bq[tl], bk = Bk[tl], bv = Bv[tl];
        #pragma unroll
        for (int s = 0; s < 8; ++s) { aq[s] = bq; ak[s] = bk; av[s] = bv; }
        const float4* Aq4 = (const float4*)(Aq + tl * NDIM);
        const float4* Ak4 = (const float4*)(Ak + tl * NDIM);
        const float4* Av4 = (const float4*)(Av + tl * NDIM);
        for (int c = 0; c < NDIM / 4; ++c) {
            const float4 wq = Aq4[c], wk = Ak4[c], wv = Av4[c];
            const float wqa[4] = {wq.x, wq.y, wq.z, wq.w};
            const float wka[4] = {wk.x, wk.y, wk.z, wk.w};
            const float wva[4] = {wv.x, wv.y, wv.z, wv.w};
            #pragma unroll
            for (int jj = 0; jj < 4; ++jj) {
                const float4 h0 = *(const float4*)&S.hz.sh[g][4 * c + jj][0];
                const float4 h1 = *(const float4*)&S.hz.sh[g][4 * c + jj][4];
                const float q = wqa[jj], k = wka[jj], v = wva[jj];
                aq[0] = fmaf(q, h0.x, aq[0]); aq[1] = fmaf(q, h0.y, aq[1]);
                aq[2] = fmaf(q, h0.z, aq[2]); aq[3] = fmaf(q, h0.w, aq[3]);
                aq[4] = fmaf(q, h1.x, aq[4]); aq[5] = fmaf(q, h1.y, aq[5]);
                aq[6] = fmaf(q, h1.z, aq[6]); aq[7] = fmaf(q, h1.w, aq[7]);
                ak[0] = fmaf(k, h0.x, ak[0]); ak[1] = fmaf(k, h0.y, ak[1]);
                ak[2] = fmaf(k, h0.z, ak[2]); ak[3] = fmaf(k, h0.w, ak[3]);
                ak[4] = fmaf(k, h1.x, ak[4]); ak[5] = fmaf(k, h1.y, ak[5]);
                ak[6] = fmaf(k, h1.z, ak[6]); ak[7] = fmaf(k, h1.w, ak[7]);
                av[0] = fmaf(v, h0.x, av[0]); av[1] = fmaf(v, h0.y, av[1]);
                av[2] = fmaf(v, h0.z, av[2]); av[3] = fmaf(v, h0.w, av[3]);
                av[4] = fmaf(v, h1.x, av[4]); av[5] = fmaf(v, h1.y, av[5]);
                av[6] = fmaf(v, h1.z, av[6]); av[7] = fmaf(v, h1.w, av[7]);
            }
        }
        float kk[8], kx[8], kn[8];
        #pragma unroll
        for (int s = 0; s < 8; ++s) {
            Qe[s] = siluf(aq[s]) * LOG2E;
            kk[s] = siluf(ak[s]);
            S.sK[g][tl][s] = kk[s];
            S.sV[g][tl][s] = siluf(av[s]);
            kx[s] = kk[s]; kn[s] = kk[s];
        }
        #pragma unroll
        for (int off = 32; off; off >>= 1) {
            #pragma unroll
            for (int s = 0; s < 8; ++s) {
                kx[s] = fmaxf(kx[s], __shfl_xor(kx[s], off));
                kn[s] = fminf(kn[s], __shfl_xor(kn[s], off));
            }
        }
        if ((tid & 63) == 0) {
            #pragma unroll
            for (int s = 0; s < 8; ++s) { S.skr[g][wg][0][s] = kx[s]; S.skr[g][wg][1][s] = kn[s]; }
        }
    }
    __syncthreads();

    // ---- C: attention row tl, single pass, global-bound shift (log2) ----
    {
        float bnd2 = 0.f;
        #pragma unroll
        for (int s = 0; s < 8; ++s) {
            const float kx = fmaxf(S.skr[g][0][0][s], S.skr[g][1][0][s]);
            const float kn = fminf(S.skr[g][0][1][s], S.skr[g][1][1][s]);
            bnd2 += fmaxf(Qe[s] * kx, Qe[s] * kn);
        }
        float l = 0.f;
        float t0 = 0.f, t1 = 0.f, t2 = 0.f, t3 = 0.f;
        float t4 = 0.f, t5 = 0.f, t6 = 0.f, t7 = 0.f;
        #pragma unroll 2
        for (int j = 0; j < NDIM; ++j) {
            const float4 k0 = *(const float4*)&S.sK[g][j][0];
            const float4 k1 = *(const float4*)&S.sK[g][j][4];
            float d = fmaf(Qe[0], k0.x, -bnd2);
            d = fmaf(Qe[1], k0.y, d); d = fmaf(Qe[2], k0.z, d); d = fmaf(Qe[3], k0.w, d);
            d = fmaf(Qe[4], k1.x, d); d = fmaf(Qe[5], k1.y, d);
            d = fmaf(Qe[6], k1.z, d); d = fmaf(Qe[7], k1.w, d);
            const float e = fexp2(d);
            const float4 v0 = *(const float4*)&S.sV[g][j][0];
            const float4 v1 = *(const float4*)&S.sV[g][j][4];
            l += e;
            t0 = fmaf(e, v0.x, t0); t1 = fmaf(e, v0.y, t1);
            t2 = fmaf(e, v0.z, t2); t3 = fmaf(e, v0.w, t3);
            t4 = fmaf(e, v1.x, t4); t5 = fmaf(e, v1.y, t5);
            t6 = fmaf(e, v1.z, t6); t7 = fmaf(e, v1.w, t7);
        }
        const float rl = frcp(l);
        S.hz.sz[g][0][tl] = siluf(t0 * rl); S.hz.sz[g][1][tl] = siluf(t1 * rl);
        S.hz.sz[g][2][tl] = siluf(t2 * rl); S.hz.sz[g][3][tl] = siluf(t3 * rl);
        S.hz.sz[g][4][tl] = siluf(t4 * rl); S.hz.sz[g][5][tl] = siluf(t5 * rl);
        S.hz.sz[g][6][tl] = siluf(t6 * rl); S.hz.sz[g][7][tl] = siluf(t7 * rl);
    }
    __syncthreads();

    // ---- D: w[s,o] = silu(z @ Wout + bout). R on tids 0-127, J on 128-191 ----
    if (tid < 192) {
        const int gm = (tid < 128) ? 1 : 0;
        const int t2 = (tid < 128) ? tid : tid - 128;
        const int lo2 = gm ? 4 : 3;
        const int outd = 1 << lo2;
        const int s = t2 >> lo2, o = t2 & (outd - 1);
        const float* Wo = gm ? RWout : JWout;
        const float* bo = gm ? Rbout : Jbout;
        float a = bo[o];
        #pragma unroll 8
        for (int c = 0; c < NDIM / 4; ++c) {
            const float4 z4 = *(const float4*)&S.hz.sz[gm][s][4 * c];
            a = fmaf(z4.x, Wo[(4 * c + 0) * outd + o], a);
            a = fmaf(z4.y, Wo[(4 * c + 1) * outd + o], a);
            a = fmaf(z4.z, Wo[(4 * c + 2) * outd + o], a);
            a = fmaf(z4.w, Wo[(4 * c + 3) * outd + o], a);
        }
        S.sw[gm][t2] = siluf(a);
    }
    __syncthreads();

    // ---- write J scalar + R group sums to workspace ----
    if (tid < 64) {
        float v = S.sw[0][tid];
        #pragma unroll
        for (int off = 32; off; off >>= 1) v += __shfl_xor(v, off);
        if (tid == 0) ws[b * 34 + 32] = (double)v;
    } else if (tid < 96) {
        const int t = tid - 64, pq = t >> 3, c = t & 7;
        const int base = c * 16 + pq * 4;
        ws[b * 34 + t] = (double)S.sw[1][base] + (double)S.sw[1][base + 1]
                       + (double)S.sw[1][base + 2] + (double)S.sw[1][base + 3];
    }
}

// ---------------------------------------------------------------------------
// Fused kernel: even blocks = H path (batch blk>>1), odd blocks = JR path.
// ---------------------------------------------------------------------------
__global__ __launch_bounds__(256, 4) void k_fused(
    const float* __restrict__ x,
    const float* __restrict__ HWin, const float* __restrict__ Hbin,
    const float* __restrict__ HAq, const float* __restrict__ HAk, const float* __restrict__ HAv,
    const float* __restrict__ HBq, const float* __restrict__ HBk, const float* __restrict__ HBv,
    const float* __restrict__ HWout, const float* __restrict__ Hbout,
    const float* __restrict__ JWin, const float* __restrict__ Jbin,
    const float* __restrict__ JAq, const float* __restrict__ JAk, const float* __restrict__ JAv,
    const float* __restrict__ JBq, const float* __restrict__ JBk, const float* __restrict__ JBv,
    const float* __restrict__ JWout, const float* __restrict__ Jbout,
    const float* __restrict__ RWin, const float* __restrict__ Rbin,
    const float* __restrict__ RAq, const float* __restrict__ RAk, const float* __restrict__ RAv,
    const float* __restrict__ RBq, const float* __restrict__ RBk, const float* __restrict__ RBv,
    const float* __restrict__ RWout, const float* __restrict__ Rbout,
    float* __restrict__ out, double* __restrict__ ws)
{
    __shared__ SU smem;
    const int b = blockIdx.x >> 1;
    if ((blockIdx.x & 1) == 0) {
        h_path(b, threadIdx.x, smem.h, x, HWin, Hbin, HAq, HAk, HAv,
               HBq, HBk, HBv, HWout, Hbout, out);
    } else {
        jr_path(b, threadIdx.x, smem.jr, x,
                JWin, Jbin, JAq, JAk, JAv, JBq, JBk, JBv, JWout, Jbout,
                RWin, Rbin, RAq, RAk, RAv, RBq, RBk, RBv, RWout, Rbout, ws);
    }
}

// ---------------------------------------------------------------------------
// Final assembly: u = (J_eff - Rm Rm^T) dHdz per batch. Reads dHdz from out
// (written by H blocks) and g/Jv from ws (written by JR blocks).
// ---------------------------------------------------------------------------
__global__ __launch_bounds__(256) void k_fin(
    const double* __restrict__ ws, float* __restrict__ inout)
{
    __shared__ double sdH[16], sg[32], sRm[16][17], srs[16], svv[16];
    __shared__ double sJv;

    const int b = blockIdx.x, tid = threadIdx.x;

    if (tid < 16) sdH[tid] = (double)inout[b * 16 + tid];
    else if (tid < 48) sg[tid - 16] = ws[b * 34 + (tid - 16)];
    else if (tid == 48) sJv = ws[b * 34 + 32];
    __syncthreads();

    const int ii = (tid >> 4) & 15, jj = tid & 15;
    {
        const double rij = sg[((ii >> 3) * 2 + (jj >> 3)) * 8 + (jj & 7)];
        const double rji = sg[((jj >> 3) * 2 + (ii >> 3)) * 8 + (ii & 7)];
        sRm[ii][jj] = rij * rij + rji * rji;
    }
    __syncthreads();

    if (tid < 16) {
        double a = 0.0;
        for (int j = 0; j < 16; ++j) a += sRm[tid][j];
        srs[tid] = a;
    }
    __syncthreads();

    const double vtmp = (ii == jj) ? srs[ii] : -sRm[ii][jj];
    __syncthreads();
    sRm[ii][jj] = vtmp;
    __syncthreads();

    if (tid < 16) {
        double a = 0.0;
        for (int j = 0; j < 16; ++j) a += sRm[tid][j] * sdH[j];
        svv[tid] = a;
    }
    __syncthreads();

    if (tid < 16) {
        double a = 0.0;
        for (int k = 0; k < 16; ++k) a += sRm[tid][k] * svv[k];
        const double jterm = (tid < 8) ? 2.0 * sJv * sdH[8 + tid]
                                       : -2.0 * sJv * sdH[tid - 8];
        inout[b * 16 + tid] = (float)(jterm - a);
    }
}

// ---------------------------------------------------------------------------
extern "C" void kernel_launch(void* const* d_in, const int* in_sizes, int n_in,
                              void* d_out, int out_size, void* d_ws, size_t ws_size,
                              hipStream_t stream)
{
    const float* x = (const float*)d_in[0];
    float* out = (float*)d_out;
    double* ws = (double*)d_ws;   // needs 512*34*8 = 139,264 bytes

#define ARGS10(base) \
    (const float*)d_in[(base) + 0], (const float*)d_in[(base) + 1], \
    (const float*)d_in[(base) + 2], (const float*)d_in[(base) + 3], \
    (const float*)d_in[(base) + 4], (const float*)d_in[(base) + 5], \
    (const float*)d_in[(base) + 6], (const float*)d_in[(base) + 7], \
    (const float*)d_in[(base) + 8], (const float*)d_in[(base) + 9]

    k_fused<<<dim3(1024), dim3(256), 0, stream>>>(
        x, ARGS10(1), ARGS10(11), ARGS10(21), out, ws);
    k_fin<<<dim3(512), dim3(256), 0, stream>>>(ws, out);
#undef ARGS10
}

// Round 7
// 148.826 us; speedup vs baseline: 1.1224x; 1.0348x over previous
//
#include <hip/hip_runtime.h>

#define NDIM 128
#define NOBS 16
#define LOG2E 1.44269504088896341f

__device__ __forceinline__ float frcp(float x) { return __builtin_amdgcn_rcpf(x); }
__device__ __forceinline__ float fexp2(float x) { return __builtin_amdgcn_exp2f(x); }
__device__ __forceinline__ float fexp(float x) { return __builtin_amdgcn_exp2f(x * LOG2E); }
__device__ __forceinline__ float sigf(float v) { return frcp(1.0f + fexp(-v)); }
__device__ __forceinline__ float siluf(float v) { return v * sigf(v); }
__device__ __forceinline__ float dsiluf(float v) {
    float s = sigf(v);
    return s * (1.0f + v * (1.0f - s));
}

// ---------------------------------------------------------------------------
// Kernel 1: H-module gradient. One block = one BATCH (8 rows), 256 threads.
// tl = tid&127 owns dim tl; tg = tid>>7 owns rows 4*tg..4*tg+3 (4 rows/thread
// -> 12 FMA per loaded weight float). exp2-domain softmax. Clean inner loop
// (round-3 structure, no duplicated passes). LDS ~23 KB.
// Writes dHdz (512 x 16) into d_out staging; k_jr overwrites with u.
// ---------------------------------------------------------------------------
__global__ __launch_bounds__(256) void k_hgrad(
    const float* __restrict__ x,
    const float* __restrict__ Win, const float* __restrict__ bin,
    const float* __restrict__ Aq, const float* __restrict__ Ak, const float* __restrict__ Av,
    const float* __restrict__ Bq, const float* __restrict__ Bk, const float* __restrict__ Bv,
    const float* __restrict__ Wout, const float* __restrict__ bout,
    float* __restrict__ dHdz)
{
    const int b   = blockIdx.x;
    const int tid = threadIdx.x;
    const int tl  = tid & 127;
    const int tg  = tid >> 7;
    const int wid = tid >> 6;
    const int r0  = tg * 4;

    __shared__ float  sx[8][NOBS];
    __shared__ float  shz[8][NDIM];      // h, later z
    __shared__ float4 sKC[8][NDIM];      // {K,V,K*V,Qe} -> {wt,c1,c2,Qe} -> {dQp,dKp,dVp,0}
    __shared__ float  sy[8][26], swp[8][26], sdwp[8][26];
    __shared__ float  skmax[4][4], skmin[4][4];
    __shared__ float  sred[4][4][2];

    if (tid < 128) sx[tid >> 4][tid & 15] = x[b * 128 + tid];
    __syncthreads();

    // ---- A: h = silu(x @ Win + bin) ----
    float hp[4];
    {
        float acc[4];
        const float b0 = bin[tl];
        #pragma unroll
        for (int r = 0; r < 4; ++r) acc[r] = b0;
        #pragma unroll
        for (int o = 0; o < NOBS; ++o) {
            const float w = Win[o * NDIM + tl];
            #pragma unroll
            for (int r = 0; r < 4; ++r) acc[r] = fmaf(w, sx[r0 + r][o], acc[r]);
        }
        #pragma unroll
        for (int r = 0; r < 4; ++r) { hp[r] = acc[r]; shz[r0 + r][tl] = siluf(acc[r]); }
    }
    __syncthreads();

    // ---- B: Q,K,V = silu(A h + B), 4 rows per weight load ----
    float Qp[4], Kp[4], Vp[4], Qv[4], Kv[4], Vv[4], Qe[4];
    {
        float aq[4], ak[4], av[4];
        const float bq = Bq[tl], bk = Bk[tl], bv = Bv[tl];
        #pragma unroll
        for (int r = 0; r < 4; ++r) { aq[r] = bq; ak[r] = bk; av[r] = bv; }
        const float4* Aq4 = (const float4*)(Aq + tl * NDIM);
        const float4* Ak4 = (const float4*)(Ak + tl * NDIM);
        const float4* Av4 = (const float4*)(Av + tl * NDIM);
        #pragma unroll 2
        for (int c = 0; c < NDIM / 4; ++c) {
            const float4 wq = Aq4[c], wk = Ak4[c], wv = Av4[c];
            #pragma unroll
            for (int r = 0; r < 4; ++r) {
                const float4 h4 = *(const float4*)&shz[r0 + r][4 * c];
                aq[r] = fmaf(wq.x, h4.x, aq[r]); aq[r] = fmaf(wq.y, h4.y, aq[r]);
                aq[r] = fmaf(wq.z, h4.z, aq[r]); aq[r] = fmaf(wq.w, h4.w, aq[r]);
                ak[r] = fmaf(wk.x, h4.x, ak[r]); ak[r] = fmaf(wk.y, h4.y, ak[r]);
                ak[r] = fmaf(wk.z, h4.z, ak[r]); ak[r] = fmaf(wk.w, h4.w, ak[r]);
                av[r] = fmaf(wv.x, h4.x, av[r]); av[r] = fmaf(wv.y, h4.y, av[r]);
                av[r] = fmaf(wv.z, h4.z, av[r]); av[r] = fmaf(wv.w, h4.w, av[r]);
            }
        }
        float kmx[4], kmn[4];
        #pragma unroll
        for (int r = 0; r < 4; ++r) {
            Qp[r] = aq[r]; Kp[r] = ak[r]; Vp[r] = av[r];
            Qv[r] = siluf(aq[r]); Kv[r] = siluf(ak[r]); Vv[r] = siluf(av[r]);
            Qe[r] = Qv[r] * LOG2E;
            sKC[r0 + r][tl] = make_float4(Kv[r], Vv[r], Kv[r] * Vv[r], Qe[r]);
            kmx[r] = Kv[r]; kmn[r] = Kv[r];
        }
        #pragma unroll
        for (int off = 32; off; off >>= 1) {
            #pragma unroll
            for (int r = 0; r < 4; ++r) {
                kmx[r] = fmaxf(kmx[r], __shfl_xor(kmx[r], off));
                kmn[r] = fminf(kmn[r], __shfl_xor(kmn[r], off));
            }
        }
        if ((tid & 63) == 0) {
            #pragma unroll
            for (int r = 0; r < 4; ++r) { skmax[wid][r] = kmx[r]; skmin[wid][r] = kmn[r]; }
        }
    }
    __syncthreads();

    // ---- C: softmax fwd (+ dQ sums folded), log2 domain ----
    float mi2[4], rl[4], ti[4], sk[4], skv[4];
    {
        float l[4], tn[4];
        #pragma unroll
        for (int r = 0; r < 4; ++r) {
            const float kx = fmaxf(skmax[2 * tg][r], skmax[2 * tg + 1][r]);
            const float kn = fminf(skmin[2 * tg][r], skmin[2 * tg + 1][r]);
            mi2[r] = fmaxf(Qe[r] * kx, Qe[r] * kn);
            l[r] = 0.f; tn[r] = 0.f; sk[r] = 0.f; skv[r] = 0.f;
        }
        #pragma unroll 2
        for (int j = 0; j < NDIM; ++j) {
            #pragma unroll
            for (int r = 0; r < 4; ++r) {
                const float4 kv4 = sKC[r0 + r][j];
                const float e = fexp2(fmaf(Qe[r], kv4.x, -mi2[r]));
                l[r] += e;
                tn[r]  = fmaf(e, kv4.y, tn[r]);
                sk[r]  = fmaf(e, kv4.x, sk[r]);
                skv[r] = fmaf(e, kv4.z, skv[r]);
            }
        }
        #pragma unroll
        for (int r = 0; r < 4; ++r) {
            rl[r] = frcp(l[r]);
            ti[r] = tn[r] * rl[r];
            shz[r0 + r][tl] = siluf(ti[r]);   // z overwrites h (dead)
        }
    }
    __syncthreads();

    // ---- y = silu(z @ Wout + bout), 8x25 tasks ----
    if (tid < 200) {
        const int r = tid / 25, o = tid - 25 * (tid / 25);
        float a = bout[o];
        #pragma unroll 8
        for (int c = 0; c < NDIM / 4; ++c) {
            const float4 z4 = *(const float4*)&shz[r][4 * c];
            a = fmaf(z4.x, Wout[(4 * c + 0) * 25 + o], a);
            a = fmaf(z4.y, Wout[(4 * c + 1) * 25 + o], a);
            a = fmaf(z4.z, Wout[(4 * c + 2) * 25 + o], a);
            a = fmaf(z4.w, Wout[(4 * c + 3) * 25 + o], a);
        }
        swp[r][o] = a;
        sy[r][o] = siluf(a);
    }
    __syncthreads();

    // ---- backward through the quadratic head ----
    if (tid < 200) {
        const int r = tid / 25, o = tid - 25 * (tid / 25);
        float m11 = 0.f, m12 = 0.f, m21 = 0.f, m22 = 0.f;
        for (int k = 0;  k < 5;  ++k) m11 += sy[r][k] * sy[r][k];
        for (int k = 5;  k < 10; ++k) m12 += sy[r][k] * sy[r][k];
        for (int k = 10; k < 15; ++k) m21 += sy[r][k] * sy[r][k];
        for (int k = 15; k < 20; ++k) m22 += sy[r][k] * sy[r][k];
        const float q0 = sy[r][0], q1 = sy[r][1], q2 = sy[r][2], q3 = sy[r][3];
        const float dm11 = q0 * q0 + q1 * q1;
        const float dm12 = q0 * q2 + q1 * q3;
        const float dm22 = q2 * q2 + q3 * q3;
        float dy;
        if      (o < 5)  dy = 2.0f * sy[r][o] * dm11;
        else if (o < 15) dy = 2.0f * sy[r][o] * dm12;
        else if (o < 20) dy = 2.0f * sy[r][o] * dm22;
        else             dy = 2.0f * sy[r][o];
        const float ms = m12 + m21;
        if (o == 0) dy += 2.0f * m11 * q0 + ms * q2;
        if (o == 1) dy += 2.0f * m11 * q1 + ms * q3;
        if (o == 2) dy += ms * q0 + 2.0f * m22 * q2;
        if (o == 3) dy += ms * q1 + 2.0f * m22 * q3;
        sdwp[r][o] = dy * dsiluf(swp[r][o]);
    }
    __syncthreads();

    // ---- E: dt, closed-form dQ, coefficient pack (overwrites sKC as C) ----
    float dQp_[4];
    {
        float wr[25];
        #pragma unroll
        for (int k = 0; k < 25; ++k) wr[k] = Wout[tl * 25 + k];
        float dt[4] = {0.f, 0.f, 0.f, 0.f};
        #pragma unroll
        for (int k = 0; k < 25; ++k) {
            #pragma unroll
            for (int r = 0; r < 4; ++r)
                dt[r] = fmaf(wr[k], sdwp[r0 + r][k], dt[r]);
        }
        #pragma unroll
        for (int r = 0; r < 4; ++r) {
            dt[r] *= dsiluf(ti[r]);
            const float w = dt[r] * rl[r];
            dQp_[r] = (w * fmaf(-ti[r], sk[r], skv[r])) * dsiluf(Qp[r]);
            const float wt = w * fexp2(-mi2[r]);
            const float c1 = wt * Qv[r];
            sKC[r0 + r][tl] = make_float4(wt, c1, c1 * ti[r], Qe[r]);
        }
    }
    __syncthreads();

    // ---- F: dK_j / dV_j (reads C; WAR barrier; writes D in place) ----
    float dD[4][3];
    {
        float accv[4] = {0.f, 0.f, 0.f, 0.f};
        float k1[4] = {0.f, 0.f, 0.f, 0.f};
        float k2[4] = {0.f, 0.f, 0.f, 0.f};
        #pragma unroll 2
        for (int i = 0; i < NDIM; ++i) {
            #pragma unroll
            for (int r = 0; r < 4; ++r) {
                const float4 c4 = sKC[r0 + r][i];
                const float e = fexp2(c4.w * Kv[r]);
                accv[r] = fmaf(e, c4.x, accv[r]);
                k1[r]   = fmaf(e, c4.y, k1[r]);
                k2[r]   = fmaf(e, c4.z, k2[r]);
            }
        }
        #pragma unroll
        for (int r = 0; r < 4; ++r) {
            dD[r][0] = dQp_[r];
            dD[r][1] = fmaf(Vv[r], k1[r], -k2[r]) * dsiluf(Kp[r]);
            dD[r][2] = accv[r] * dsiluf(Vp[r]);
        }
    }
    __syncthreads();
    #pragma unroll
    for (int r = 0; r < 4; ++r)
        sKC[r0 + r][tl] = make_float4(dD[r][0], dD[r][1], dD[r][2], 0.f);
    __syncthreads();

    // ---- G: dh_d = sum_i Aq[i][d]dQp + Ak[i][d]dKp + Av[i][d]dVp ----
    float dhp[4];
    {
        float acc[4] = {0.f, 0.f, 0.f, 0.f};
        #pragma unroll 4
        for (int i = 0; i < NDIM; ++i) {
            const float aqv = Aq[i * NDIM + tl];
            const float akv = Ak[i * NDIM + tl];
            const float avv = Av[i * NDIM + tl];
            #pragma unroll
            for (int r = 0; r < 4; ++r) {
                const float4 d4 = sKC[r0 + r][i];
                acc[r] = fmaf(aqv, d4.x, acc[r]);
                acc[r] = fmaf(akv, d4.y, acc[r]);
                acc[r] = fmaf(avv, d4.z, acc[r]);
            }
        }
        #pragma unroll
        for (int r = 0; r < 4; ++r) dhp[r] = acc[r] * dsiluf(hp[r]);
    }

    // ---- dx_o (o=0,1): shuffle reduce per row, cross-wave combine ----
    {
        const float w0 = Win[tl], w1 = Win[NDIM + tl];
        float t0[4], t1[4];
        #pragma unroll
        for (int r = 0; r < 4; ++r) { t0[r] = w0 * dhp[r]; t1[r] = w1 * dhp[r]; }
        #pragma unroll
        for (int off = 32; off; off >>= 1) {
            #pragma unroll
            for (int r = 0; r < 4; ++r) {
                t0[r] += __shfl_xor(t0[r], off);
                t1[r] += __shfl_xor(t1[r], off);
            }
        }
        if ((tid & 63) == 0) {
            #pragma unroll
            for (int r = 0; r < 4; ++r) { sred[wid][r][0] = t0[r]; sred[wid][r][1] = t1[r]; }
        }
    }
    __syncthreads();
    if (tid < 16) {
        const int o = tid >> 3, ag = tid & 7;
        const int gg = ag >> 2, rr = ag & 3;
        dHdz[b * 16 + o * 8 + ag] = sred[2 * gg][rr][o] + sred[2 * gg + 1][rr][o];
    }
}

// ---------------------------------------------------------------------------
// Kernel 2: one batch per 256-thread block. J on tids 0-127, R on 128-255.
// One thread = one dim, all 8 agents (Q in registers, log2-scaled); single-
// pass softmax with exact global-bound shift; in-block 16x16 assembly.
// `inout` holds dHdz on entry; overwritten with u.
// ---------------------------------------------------------------------------
__global__ __launch_bounds__(256) void k_jr(
    const float* __restrict__ x,
    const float* __restrict__ JWin, const float* __restrict__ Jbin,
    const float* __restrict__ JAq, const float* __restrict__ JAk, const float* __restrict__ JAv,
    const float* __restrict__ JBq, const float* __restrict__ JBk, const float* __restrict__ JBv,
    const float* __restrict__ JWout, const float* __restrict__ Jbout,
    const float* __restrict__ RWin, const float* __restrict__ Rbin,
    const float* __restrict__ RAq, const float* __restrict__ RAk, const float* __restrict__ RAv,
    const float* __restrict__ RBq, const float* __restrict__ RBk, const float* __restrict__ RBv,
    const float* __restrict__ RWout, const float* __restrict__ Rbout,
    float* __restrict__ inout)
{
    __shared__ float  sx[128];
    __shared__ float  sh[2][NDIM][8];     // [g][dim j][agent]; z aliases after B
    __shared__ float  sK[2][NDIM][8];
    __shared__ float  sV[2][NDIM][8];
    __shared__ float  sz[2][8][132];
    __shared__ float  sw[2][NDIM];
    __shared__ float  skr[2][2][2][8];    // [g][wave][max/min][agent]
    __shared__ float  sJv;
    __shared__ double sdH[16], sg[32], sRm[16][17], srs[16], svv[16];

    const int b   = blockIdx.x;
    const int tid = threadIdx.x;
    const int g   = tid >> 7;       // 0 = J, 1 = R
    const int tl  = tid & 127;      // dim / attention row
    const int wg  = (tid >> 6) & 1; // wave within group

    if (tid < 128) sx[tid] = x[b * 128 + tid];
    else if (tid < 144) sdH[tid - 128] = (double)inout[b * 16 + (tid - 128)];
    __syncthreads();

    const float* Win  = g ? RWin  : JWin;
    const float* bin_ = g ? Rbin  : Jbin;
    const float* Aq   = g ? RAq   : JAq;
    const float* Ak   = g ? RAk   : JAk;
    const float* Av   = g ? RAv   : JAv;
    const float* Bq   = g ? RBq   : JBq;
    const float* Bk   = g ? RBk   : JBk;
    const float* Bv   = g ? RBv   : JBv;

    // ---- A: h[a][tl] for all 8 agents ----
    {
        float acc[8];
        const float b0 = bin_[tl];
        #pragma unroll
        for (int a = 0; a < 8; ++a) acc[a] = b0;
        #pragma unroll
        for (int c = 0; c < 4; ++c) {
            const float w0 = Win[(4 * c + 0) * NDIM + tl];
            const float w1 = Win[(4 * c + 1) * NDIM + tl];
            const float w2 = Win[(4 * c + 2) * NDIM + tl];
            const float w3 = Win[(4 * c + 3) * NDIM + tl];
            #pragma unroll
            for (int a = 0; a < 8; ++a) {
                const float4 x4 = *(const float4*)&sx[a * 16 + 4 * c];
                acc[a] = fmaf(w0, x4.x, acc[a]);
                acc[a] = fmaf(w1, x4.y, acc[a]);
                acc[a] = fmaf(w2, x4.z, acc[a]);
                acc[a] = fmaf(w3, x4.w, acc[a]);
            }
        }
        *(float4*)&sh[g][tl][0] =
            make_float4(siluf(acc[0]), siluf(acc[1]), siluf(acc[2]), siluf(acc[3]));
        *(float4*)&sh[g][tl][4] =
            make_float4(siluf(acc[4]), siluf(acc[5]), siluf(acc[6]), siluf(acc[7]));
    }
    __syncthreads();

    // ---- B: Q (regs, log2-scaled), K, V (LDS); all 8 agents ----
    float Qe[8];
    {
        float aq[8], ak[8], av[8];
        const float bq = Bq[tl], bk = Bk[tl], bv = Bv[tl];
        #pragma unroll
        for (int s = 0; s < 8; ++s) { aq[s] = bq; ak[s] = bk; av[s] = bv; }
        const float4* Aq4 = (const float4*)(Aq + tl * NDIM);
        const float4* Ak4 = (const float4*)(Ak + tl * NDIM);
        const float4* Av4 = (const float4*)(Av + tl * NDIM);
        for (int c = 0; c < NDIM / 4; ++c) {
            const float4 wq = Aq4[c], wk = Ak4[c], wv = Av4[c];
            const float wqa[4] = {wq.x, wq.y, wq.z, wq.w};
            const float wka[4] = {wk.x, wk.y, wk.z, wk.w};
            const float wva[4] = {wv.x, wv.y, wv.z, wv.w};
            #pragma unroll
            for (int jj = 0; jj < 4; ++jj) {
                const float4 h0 = *(const float4*)&sh[g][4 * c + jj][0];
                const float4 h1 = *(const float4*)&sh[g][4 * c + jj][4];
                const float q = wqa[jj], k = wka[jj], v = wva[jj];
                aq[0] = fmaf(q, h0.x, aq[0]); aq[1] = fmaf(q, h0.y, aq[1]);
                aq[2] = fmaf(q, h0.z, aq[2]); aq[3] = fmaf(q, h0.w, aq[3]);
                aq[4] = fmaf(q, h1.x, aq[4]); aq[5] = fmaf(q, h1.y, aq[5]);
                aq[6] = fmaf(q, h1.z, aq[6]); aq[7] = fmaf(q, h1.w, aq[7]);
                ak[0] = fmaf(k, h0.x, ak[0]); ak[1] = fmaf(k, h0.y, ak[1]);
                ak[2] = fmaf(k, h0.z, ak[2]); ak[3] = fmaf(k, h0.w, ak[3]);
                ak[4] = fmaf(k, h1.x, ak[4]); ak[5] = fmaf(k, h1.y, ak[5]);
                ak[6] = fmaf(k, h1.z, ak[6]); ak[7] = fmaf(k, h1.w, ak[7]);
                av[0] = fmaf(v, h0.x, av[0]); av[1] = fmaf(v, h0.y, av[1]);
                av[2] = fmaf(v, h0.z, av[2]); av[3] = fmaf(v, h0.w, av[3]);
                av[4] = fmaf(v, h1.x, av[4]); av[5] = fmaf(v, h1.y, av[5]);
                av[6] = fmaf(v, h1.z, av[6]); av[7] = fmaf(v, h1.w, av[7]);
            }
        }
        float kk[8], kx[8], kn[8];
        #pragma unroll
        for (int s = 0; s < 8; ++s) {
            Qe[s] = siluf(aq[s]) * LOG2E;
            kk[s] = siluf(ak[s]);
            sK[g][tl][s] = kk[s];
            sV[g][tl][s] = siluf(av[s]);
            kx[s] = kk[s]; kn[s] = kk[s];
        }
        #pragma unroll
        for (int off = 32; off; off >>= 1) {
            #pragma unroll
            for (int s = 0; s < 8; ++s) {
                kx[s] = fmaxf(kx[s], __shfl_xor(kx[s], off));
                kn[s] = fminf(kn[s], __shfl_xor(kn[s], off));
            }
        }
        if ((tid & 63) == 0) {
            #pragma unroll
            for (int s = 0; s < 8; ++s) { skr[g][wg][0][s] = kx[s]; skr[g][wg][1][s] = kn[s]; }
        }
    }
    __syncthreads();

    // ---- C: attention row tl, single pass, global-bound shift (log2) ----
    {
        float bnd2 = 0.f;
        #pragma unroll
        for (int s = 0; s < 8; ++s) {
            const float kx = fmaxf(skr[g][0][0][s], skr[g][1][0][s]);
            const float kn = fminf(skr[g][0][1][s], skr[g][1][1][s]);
            bnd2 += fmaxf(Qe[s] * kx, Qe[s] * kn);
        }
        float l = 0.f;
        float t0 = 0.f, t1 = 0.f, t2 = 0.f, t3 = 0.f;
        float t4 = 0.f, t5 = 0.f, t6 = 0.f, t7 = 0.f;
        #pragma unroll 2
        for (int j = 0; j < NDIM; ++j) {
            const float4 k0 = *(const float4*)&sK[g][j][0];
            const float4 k1 = *(const float4*)&sK[g][j][4];
            float d = fmaf(Qe[0], k0.x, -bnd2);
            d = fmaf(Qe[1], k0.y, d); d = fmaf(Qe[2], k0.z, d); d = fmaf(Qe[3], k0.w, d);
            d = fmaf(Qe[4], k1.x, d); d = fmaf(Qe[5], k1.y, d);
            d = fmaf(Qe[6], k1.z, d); d = fmaf(Qe[7], k1.w, d);
            const float e = fexp2(d);
            const float4 v0 = *(const float4*)&sV[g][j][0];
            const float4 v1 = *(const float4*)&sV[g][j][4];
            l += e;
            t0 = fmaf(e, v0.x, t0); t1 = fmaf(e, v0.y, t1);
            t2 = fmaf(e, v0.z, t2); t3 = fmaf(e, v0.w, t3);
            t4 = fmaf(e, v1.x, t4); t5 = fmaf(e, v1.y, t5);
            t6 = fmaf(e, v1.z, t6); t7 = fmaf(e, v1.w, t7);
        }
        const float rl = frcp(l);
        sz[g][0][tl] = siluf(t0 * rl); sz[g][1][tl] = siluf(t1 * rl);
        sz[g][2][tl] = siluf(t2 * rl); sz[g][3][tl] = siluf(t3 * rl);
        sz[g][4][tl] = siluf(t4 * rl); sz[g][5][tl] = siluf(t5 * rl);
        sz[g][6][tl] = siluf(t6 * rl); sz[g][7][tl] = siluf(t7 * rl);
    }
    __syncthreads();

    // ---- D: w[s,o] = silu(z @ Wout + bout). R on tids 0-127, J on 128-191 ----
    if (tid < 192) {
        const int gm = (tid < 128) ? 1 : 0;
        const int t2 = (tid < 128) ? tid : tid - 128;
        const int lo2 = gm ? 4 : 3;
        const int outd = 1 << lo2;
        const int s = t2 >> lo2, o = t2 & (outd - 1);
        const float* Wo = gm ? RWout : JWout;
        const float* bo = gm ? Rbout : Jbout;
        float a = bo[o];
        #pragma unroll 8
        for (int c = 0; c < NDIM / 4; ++c) {
            const float4 z4 = *(const float4*)&sz[gm][s][4 * c];
            a = fmaf(z4.x, Wo[(4 * c + 0) * outd + o], a);
            a = fmaf(z4.y, Wo[(4 * c + 1) * outd + o], a);
            a = fmaf(z4.z, Wo[(4 * c + 2) * outd + o], a);
            a = fmaf(z4.w, Wo[(4 * c + 3) * outd + o], a);
        }
        sw[gm][t2] = siluf(a);
    }
    __syncthreads();

    // ---- J scalar + R group sums ----
    if (tid < 64) {
        float v = sw[0][tid];
        #pragma unroll
        for (int off = 32; off; off >>= 1) v += __shfl_xor(v, off);
        if (tid == 0) sJv = v;
    } else if (tid < 96) {
        const int t = tid - 64, pq = t >> 3, c = t & 7;
        const int base = c * 16 + pq * 4;
        sg[t] = (double)sw[1][base] + (double)sw[1][base + 1]
              + (double)sw[1][base + 2] + (double)sw[1][base + 3];
    }
    __syncthreads();

    // ---- assembly: Rupper, Laplacian Rm, u = (J_eff - Rm Rm^T) dH ----
    const int ii = (tid >> 4) & 15, jj = tid & 15;
    if (tid < 256) {
        const double rij = sg[((ii >> 3) * 2 + (jj >> 3)) * 8 + (jj & 7)];
        const double rji = sg[((jj >> 3) * 2 + (ii >> 3)) * 8 + (ii & 7)];
        sRm[ii][jj] = rij * rij + rji * rji;
    }
    __syncthreads();

    if (tid < 16) {
        double a = 0.0;
        for (int j = 0; j < 16; ++j) a += sRm[tid][j];
        srs[tid] = a;
    }
    __syncthreads();

    {
        const double v = (ii == jj) ? srs[ii] : -sRm[ii][jj];
        __syncthreads();
        sRm[ii][jj] = v;
    }
    __syncthreads();

    if (tid < 16) {
        double a = 0.0;
        for (int j = 0; j < 16; ++j) a += sRm[tid][j] * sdH[j];
        svv[tid] = a;
    }
    __syncthreads();

    if (tid < 16) {
        double a = 0.0;
        for (int k = 0; k < 16; ++k) a += sRm[tid][k] * svv[k];
        const double sj = (double)sJv;
        const double jterm = (tid < 8) ? 2.0 * sj * sdH[8 + tid]
                                       : -2.0 * sj * sdH[tid - 8];
        inout[b * 16 + tid] = (float)(jterm - a);
    }
}

// ---------------------------------------------------------------------------
extern "C" void kernel_launch(void* const* d_in, const int* in_sizes, int n_in,
                              void* d_out, int out_size, void* d_ws, size_t ws_size,
                              hipStream_t stream)
{
    const float* x = (const float*)d_in[0];
    float* out = (float*)d_out;

#define ARGS10(base) \
    (const float*)d_in[(base) + 0], (const float*)d_in[(base) + 1], \
    (const float*)d_in[(base) + 2], (const float*)d_in[(base) + 3], \
    (const float*)d_in[(base) + 4], (const float*)d_in[(base) + 5], \
    (const float*)d_in[(base) + 6], (const float*)d_in[(base) + 7], \
    (const float*)d_in[(base) + 8], (const float*)d_in[(base) + 9]

    k_hgrad<<<dim3(512), dim3(256), 0, stream>>>(x, ARGS10(1), out);
    k_jr<<<dim3(512), dim3(256), 0, stream>>>(x, ARGS10(11), ARGS10(21), out);
#undef ARGS10
}

// Round 8
// 143.156 us; speedup vs baseline: 1.1668x; 1.0396x over previous
//
#include <hip/hip_runtime.h>

#define NDIM 128
#define NOBS 16
#define LOG2E 1.44269504088896341f

__device__ __forceinline__ float frcp(float x) { return __builtin_amdgcn_rcpf(x); }
__device__ __forceinline__ float fexp2(float x) { return __builtin_amdgcn_exp2f(x); }
__device__ __forceinline__ float fexp(float x) { return __builtin_amdgcn_exp2f(x * LOG2E); }
__device__ __forceinline__ float sigf(float v) { return frcp(1.0f + fexp(-v)); }
__device__ __forceinline__ float siluf(float v) { return v * sigf(v); }
__device__ __forceinline__ float dsiluf(float v) {
    float s = sigf(v);
    return s * (1.0f + v * (1.0f - s));
}

// ---------------------------------------------------------------------------
// Kernel 1: H-module gradient. One block = one BATCH (8 rows), 256 threads.
// tl = tid&127 owns dim tl; tg = tid>>7 owns rows 4*tg..4*tg+3 (4 rows/thread
// -> 12 FMA per loaded weight float4-group). exp2-domain softmax.
// ROUND-3 LDS LAYOUT: separate sh/sKVQ/sz/sC/sD buffers, no aliasing, no
// extra WAR barriers (the round-7 in-place reuse cost ~26 us).
// Writes dHdz (512 x 16) into d_out staging; k_jr overwrites with u.
// ---------------------------------------------------------------------------
__global__ __launch_bounds__(256) void k_hgrad(
    const float* __restrict__ x,
    const float* __restrict__ Win, const float* __restrict__ bin,
    const float* __restrict__ Aq, const float* __restrict__ Ak, const float* __restrict__ Av,
    const float* __restrict__ Bq, const float* __restrict__ Bk, const float* __restrict__ Bv,
    const float* __restrict__ Wout, const float* __restrict__ bout,
    float* __restrict__ dHdz)
{
    const int b   = blockIdx.x;
    const int tid = threadIdx.x;
    const int tl  = tid & 127;
    const int tg  = tid >> 7;
    const int wid = tid >> 6;
    const int r0  = tg * 4;

    __shared__ float  sx[8][NOBS];
    __shared__ float  sh[8][NDIM];
    __shared__ float4 sKVQ[8][NDIM];   // {K, V, K*V, Qe}
    __shared__ float  sz[8][NDIM];
    __shared__ float4 sC[8][NDIM];     // {wt, wt*Q, wt*Q*t, Qe}
    __shared__ float4 sD[8][NDIM];     // {dQp, dKp, dVp, 0}
    __shared__ float  sy[8][26], swp[8][26], sdwp[8][26];
    __shared__ float  skmax[4][4], skmin[4][4];
    __shared__ float  sred[4][4][2];

    if (tid < 128) sx[tid >> 4][tid & 15] = x[b * 128 + tid];
    __syncthreads();

    // ---- A: h = silu(x @ Win + bin) ----
    float hp[4];
    {
        float acc[4];
        const float b0 = bin[tl];
        #pragma unroll
        for (int r = 0; r < 4; ++r) acc[r] = b0;
        #pragma unroll
        for (int o = 0; o < NOBS; ++o) {
            const float w = Win[o * NDIM + tl];
            #pragma unroll
            for (int r = 0; r < 4; ++r) acc[r] = fmaf(w, sx[r0 + r][o], acc[r]);
        }
        #pragma unroll
        for (int r = 0; r < 4; ++r) { hp[r] = acc[r]; sh[r0 + r][tl] = siluf(acc[r]); }
    }
    __syncthreads();

    // ---- B: Q,K,V = silu(A h + B), 4 rows per weight load ----
    float Qp[4], Kp[4], Vp[4], Qv[4], Kv[4], Vv[4], Qe[4];
    {
        float aq[4], ak[4], av[4];
        const float bq = Bq[tl], bk = Bk[tl], bv = Bv[tl];
        #pragma unroll
        for (int r = 0; r < 4; ++r) { aq[r] = bq; ak[r] = bk; av[r] = bv; }
        const float4* Aq4 = (const float4*)(Aq + tl * NDIM);
        const float4* Ak4 = (const float4*)(Ak + tl * NDIM);
        const float4* Av4 = (const float4*)(Av + tl * NDIM);
        #pragma unroll 2
        for (int c = 0; c < NDIM / 4; ++c) {
            const float4 wq = Aq4[c], wk = Ak4[c], wv = Av4[c];
            #pragma unroll
            for (int r = 0; r < 4; ++r) {
                const float4 h4 = *(const float4*)&sh[r0 + r][4 * c];
                aq[r] = fmaf(wq.x, h4.x, aq[r]); aq[r] = fmaf(wq.y, h4.y, aq[r]);
                aq[r] = fmaf(wq.z, h4.z, aq[r]); aq[r] = fmaf(wq.w, h4.w, aq[r]);
                ak[r] = fmaf(wk.x, h4.x, ak[r]); ak[r] = fmaf(wk.y, h4.y, ak[r]);
                ak[r] = fmaf(wk.z, h4.z, ak[r]); ak[r] = fmaf(wk.w, h4.w, ak[r]);
                av[r] = fmaf(wv.x, h4.x, av[r]); av[r] = fmaf(wv.y, h4.y, av[r]);
                av[r] = fmaf(wv.z, h4.z, av[r]); av[r] = fmaf(wv.w, h4.w, av[r]);
            }
        }
        float kmx[4], kmn[4];
        #pragma unroll
        for (int r = 0; r < 4; ++r) {
            Qp[r] = aq[r]; Kp[r] = ak[r]; Vp[r] = av[r];
            Qv[r] = siluf(aq[r]); Kv[r] = siluf(ak[r]); Vv[r] = siluf(av[r]);
            Qe[r] = Qv[r] * LOG2E;
            sKVQ[r0 + r][tl] = make_float4(Kv[r], Vv[r], Kv[r] * Vv[r], Qe[r]);
            kmx[r] = Kv[r]; kmn[r] = Kv[r];
        }
        #pragma unroll
        for (int off = 32; off; off >>= 1) {
            #pragma unroll
            for (int r = 0; r < 4; ++r) {
                kmx[r] = fmaxf(kmx[r], __shfl_xor(kmx[r], off));
                kmn[r] = fminf(kmn[r], __shfl_xor(kmn[r], off));
            }
        }
        if ((tid & 63) == 0) {
            #pragma unroll
            for (int r = 0; r < 4; ++r) { skmax[wid][r] = kmx[r]; skmin[wid][r] = kmn[r]; }
        }
    }
    __syncthreads();

    // ---- C: softmax fwd (+ dQ sums folded), log2 domain ----
    float mi2[4], rl[4], ti[4], sk[4], skv[4];
    {
        float l[4], tn[4];
        #pragma unroll
        for (int r = 0; r < 4; ++r) {
            const float kx = fmaxf(skmax[2 * tg][r], skmax[2 * tg + 1][r]);
            const float kn = fminf(skmin[2 * tg][r], skmin[2 * tg + 1][r]);
            mi2[r] = fmaxf(Qe[r] * kx, Qe[r] * kn);
            l[r] = 0.f; tn[r] = 0.f; sk[r] = 0.f; skv[r] = 0.f;
        }
        #pragma unroll 2
        for (int j = 0; j < NDIM; ++j) {
            #pragma unroll
            for (int r = 0; r < 4; ++r) {
                const float4 kv4 = sKVQ[r0 + r][j];
                const float e = fexp2(fmaf(Qe[r], kv4.x, -mi2[r]));
                l[r] += e;
                tn[r]  = fmaf(e, kv4.y, tn[r]);
                sk[r]  = fmaf(e, kv4.x, sk[r]);
                skv[r] = fmaf(e, kv4.z, skv[r]);
            }
        }
        #pragma unroll
        for (int r = 0; r < 4; ++r) {
            rl[r] = frcp(l[r]);
            ti[r] = tn[r] * rl[r];
            sz[r0 + r][tl] = siluf(ti[r]);
        }
    }
    __syncthreads();

    // ---- y = silu(z @ Wout + bout), 8x25 tasks ----
    if (tid < 200) {
        const int r = tid / 25, o = tid - 25 * (tid / 25);
        float a = bout[o];
        #pragma unroll 8
        for (int c = 0; c < NDIM / 4; ++c) {
            const float4 z4 = *(const float4*)&sz[r][4 * c];
            a = fmaf(z4.x, Wout[(4 * c + 0) * 25 + o], a);
            a = fmaf(z4.y, Wout[(4 * c + 1) * 25 + o], a);
            a = fmaf(z4.z, Wout[(4 * c + 2) * 25 + o], a);
            a = fmaf(z4.w, Wout[(4 * c + 3) * 25 + o], a);
        }
        swp[r][o] = a;
        sy[r][o] = siluf(a);
    }
    __syncthreads();

    // ---- backward through the quadratic head ----
    if (tid < 200) {
        const int r = tid / 25, o = tid - 25 * (tid / 25);
        float m11 = 0.f, m12 = 0.f, m21 = 0.f, m22 = 0.f;
        for (int k = 0;  k < 5;  ++k) m11 += sy[r][k] * sy[r][k];
        for (int k = 5;  k < 10; ++k) m12 += sy[r][k] * sy[r][k];
        for (int k = 10; k < 15; ++k) m21 += sy[r][k] * sy[r][k];
        for (int k = 15; k < 20; ++k) m22 += sy[r][k] * sy[r][k];
        const float q0 = sy[r][0], q1 = sy[r][1], q2 = sy[r][2], q3 = sy[r][3];
        const float dm11 = q0 * q0 + q1 * q1;
        const float dm12 = q0 * q2 + q1 * q3;
        const float dm22 = q2 * q2 + q3 * q3;
        float dy;
        if      (o < 5)  dy = 2.0f * sy[r][o] * dm11;
        else if (o < 15) dy = 2.0f * sy[r][o] * dm12;
        else if (o < 20) dy = 2.0f * sy[r][o] * dm22;
        else             dy = 2.0f * sy[r][o];
        const float ms = m12 + m21;
        if (o == 0) dy += 2.0f * m11 * q0 + ms * q2;
        if (o == 1) dy += 2.0f * m11 * q1 + ms * q3;
        if (o == 2) dy += ms * q0 + 2.0f * m22 * q2;
        if (o == 3) dy += ms * q1 + 2.0f * m22 * q3;
        sdwp[r][o] = dy * dsiluf(swp[r][o]);
    }
    __syncthreads();

    // ---- E: dt, closed-form dQ, coefficient pack into sC (2^-m folded) ----
    float dQp_[4];
    {
        float wr[25];
        #pragma unroll
        for (int k = 0; k < 25; ++k) wr[k] = Wout[tl * 25 + k];
        float dt[4] = {0.f, 0.f, 0.f, 0.f};
        #pragma unroll
        for (int k = 0; k < 25; ++k) {
            #pragma unroll
            for (int r = 0; r < 4; ++r)
                dt[r] = fmaf(wr[k], sdwp[r0 + r][k], dt[r]);
        }
        #pragma unroll
        for (int r = 0; r < 4; ++r) {
            dt[r] *= dsiluf(ti[r]);
            const float w = dt[r] * rl[r];
            dQp_[r] = (w * fmaf(-ti[r], sk[r], skv[r])) * dsiluf(Qp[r]);
            const float wt = w * fexp2(-mi2[r]);
            const float c1 = wt * Qv[r];
            sC[r0 + r][tl] = make_float4(wt, c1, c1 * ti[r], Qe[r]);
        }
    }
    __syncthreads();

    // ---- F: dK_j / dV_j -> write sD (separate buffer, single barrier) ----
    {
        float accv[4] = {0.f, 0.f, 0.f, 0.f};
        float k1[4] = {0.f, 0.f, 0.f, 0.f};
        float k2[4] = {0.f, 0.f, 0.f, 0.f};
        #pragma unroll 2
        for (int i = 0; i < NDIM; ++i) {
            #pragma unroll
            for (int r = 0; r < 4; ++r) {
                const float4 c4 = sC[r0 + r][i];
                const float e = fexp2(c4.w * Kv[r]);
                accv[r] = fmaf(e, c4.x, accv[r]);
                k1[r]   = fmaf(e, c4.y, k1[r]);
                k2[r]   = fmaf(e, c4.z, k2[r]);
            }
        }
        #pragma unroll
        for (int r = 0; r < 4; ++r) {
            const float dVp_ = accv[r] * dsiluf(Vp[r]);
            const float dKp_ = fmaf(Vv[r], k1[r], -k2[r]) * dsiluf(Kp[r]);
            sD[r0 + r][tl] = make_float4(dQp_[r], dKp_, dVp_, 0.f);
        }
    }
    __syncthreads();

    // ---- G: dh_d = sum_i Aq[i][d]dQp + Ak[i][d]dKp + Av[i][d]dVp ----
    float dhp[4];
    {
        float acc[4] = {0.f, 0.f, 0.f, 0.f};
        #pragma unroll 4
        for (int i = 0; i < NDIM; ++i) {
            const float aqv = Aq[i * NDIM + tl];
            const float akv = Ak[i * NDIM + tl];
            const float avv = Av[i * NDIM + tl];
            #pragma unroll
            for (int r = 0; r < 4; ++r) {
                const float4 d4 = sD[r0 + r][i];
                acc[r] = fmaf(aqv, d4.x, acc[r]);
                acc[r] = fmaf(akv, d4.y, acc[r]);
                acc[r] = fmaf(avv, d4.z, acc[r]);
            }
        }
        #pragma unroll
        for (int r = 0; r < 4; ++r) dhp[r] = acc[r] * dsiluf(hp[r]);
    }

    // ---- dx_o (o=0,1): shuffle reduce per row, cross-wave combine ----
    {
        const float w0 = Win[tl], w1 = Win[NDIM + tl];
        float t0[4], t1[4];
        #pragma unroll
        for (int r = 0; r < 4; ++r) { t0[r] = w0 * dhp[r]; t1[r] = w1 * dhp[r]; }
        #pragma unroll
        for (int off = 32; off; off >>= 1) {
            #pragma unroll
            for (int r = 0; r < 4; ++r) {
                t0[r] += __shfl_xor(t0[r], off);
                t1[r] += __shfl_xor(t1[r], off);
            }
        }
        if ((tid & 63) == 0) {
            #pragma unroll
            for (int r = 0; r < 4; ++r) { sred[wid][r][0] = t0[r]; sred[wid][r][1] = t1[r]; }
        }
    }
    __syncthreads();
    if (tid < 16) {
        const int o = tid >> 3, ag = tid & 7;
        const int gg = ag >> 2, rr = ag & 3;
        dHdz[b * 16 + o * 8 + ag] = sred[2 * gg][rr][o] + sred[2 * gg + 1][rr][o];
    }
}

// ---------------------------------------------------------------------------
// Kernel 2: one batch per 256-thread block. J on tids 0-127, R on 128-255.
// One thread = one dim, all 8 agents (Q in registers, log2-scaled); single-
// pass softmax with exact global-bound shift; in-block 16x16 assembly.
// (unchanged from round 7 — measured ~49 us)
// ---------------------------------------------------------------------------
__global__ __launch_bounds__(256) void k_jr(
    const float* __restrict__ x,
    const float* __restrict__ JWin, const float* __restrict__ Jbin,
    const float* __restrict__ JAq, const float* __restrict__ JAk, const float* __restrict__ JAv,
    const float* __restrict__ JBq, const float* __restrict__ JBk, const float* __restrict__ JBv,
    const float* __restrict__ JWout, const float* __restrict__ Jbout,
    const float* __restrict__ RWin, const float* __restrict__ Rbin,
    const float* __restrict__ RAq, const float* __restrict__ RAk, const float* __restrict__ RAv,
    const float* __restrict__ RBq, const float* __restrict__ RBk, const float* __restrict__ RBv,
    const float* __restrict__ RWout, const float* __restrict__ Rbout,
    float* __restrict__ inout)
{
    __shared__ float  sx[128];
    __shared__ float  sh[2][NDIM][8];
    __shared__ float  sK[2][NDIM][8];
    __shared__ float  sV[2][NDIM][8];
    __shared__ float  sz[2][8][132];
    __shared__ float  sw[2][NDIM];
    __shared__ float  skr[2][2][2][8];
    __shared__ float  sJv;
    __shared__ double sdH[16], sg[32], sRm[16][17], srs[16], svv[16];

    const int b   = blockIdx.x;
    const int tid = threadIdx.x;
    const int g   = tid >> 7;
    const int tl  = tid & 127;
    const int wg  = (tid >> 6) & 1;

    if (tid < 128) sx[tid] = x[b * 128 + tid];
    else if (tid < 144) sdH[tid - 128] = (double)inout[b * 16 + (tid - 128)];
    __syncthreads();

    const float* Win  = g ? RWin  : JWin;
    const float* bin_ = g ? Rbin  : Jbin;
    const float* Aq   = g ? RAq   : JAq;
    const float* Ak   = g ? RAk   : JAk;
    const float* Av   = g ? RAv   : JAv;
    const float* Bq   = g ? RBq   : JBq;
    const float* Bk   = g ? RBk   : JBk;
    const float* Bv   = g ? RBv   : JBv;

    // ---- A: h[a][tl] for all 8 agents ----
    {
        float acc[8];
        const float b0 = bin_[tl];
        #pragma unroll
        for (int a = 0; a < 8; ++a) acc[a] = b0;
        #pragma unroll
        for (int c = 0; c < 4; ++c) {
            const float w0 = Win[(4 * c + 0) * NDIM + tl];
            const float w1 = Win[(4 * c + 1) * NDIM + tl];
            const float w2 = Win[(4 * c + 2) * NDIM + tl];
            const float w3 = Win[(4 * c + 3) * NDIM + tl];
            #pragma unroll
            for (int a = 0; a < 8; ++a) {
                const float4 x4 = *(const float4*)&sx[a * 16 + 4 * c];
                acc[a] = fmaf(w0, x4.x, acc[a]);
                acc[a] = fmaf(w1, x4.y, acc[a]);
                acc[a] = fmaf(w2, x4.z, acc[a]);
                acc[a] = fmaf(w3, x4.w, acc[a]);
            }
        }
        *(float4*)&sh[g][tl][0] =
            make_float4(siluf(acc[0]), siluf(acc[1]), siluf(acc[2]), siluf(acc[3]));
        *(float4*)&sh[g][tl][4] =
            make_float4(siluf(acc[4]), siluf(acc[5]), siluf(acc[6]), siluf(acc[7]));
    }
    __syncthreads();

    // ---- B: Q (regs, log2-scaled), K, V (LDS); all 8 agents ----
    float Qe[8];
    {
        float aq[8], ak[8], av[8];
        const float bq = Bq[tl], bk = Bk[tl], bv = Bv[tl];
        #pragma unroll
        for (int s = 0; s < 8; ++s) { aq[s] = bq; ak[s] = bk; av[s] = bv; }
        const float4* Aq4 = (const float4*)(Aq + tl * NDIM);
        const float4* Ak4 = (const float4*)(Ak + tl * NDIM);
        const float4* Av4 = (const float4*)(Av + tl * NDIM);
        for (int c = 0; c < NDIM / 4; ++c) {
            const float4 wq = Aq4[c], wk = Ak4[c], wv = Av4[c];
            const float wqa[4] = {wq.x, wq.y, wq.z, wq.w};
            const float wka[4] = {wk.x, wk.y, wk.z, wk.w};
            const float wva[4] = {wv.x, wv.y, wv.z, wv.w};
            #pragma unroll
            for (int jj = 0; jj < 4; ++jj) {
                const float4 h0 = *(const float4*)&sh[g][4 * c + jj][0];
                const float4 h1 = *(const float4*)&sh[g][4 * c + jj][4];
                const float q = wqa[jj], k = wka[jj], v = wva[jj];
                aq[0] = fmaf(q, h0.x, aq[0]); aq[1] = fmaf(q, h0.y, aq[1]);
                aq[2] = fmaf(q, h0.z, aq[2]); aq[3] = fmaf(q, h0.w, aq[3]);
                aq[4] = fmaf(q, h1.x, aq[4]); aq[5] = fmaf(q, h1.y, aq[5]);
                aq[6] = fmaf(q, h1.z, aq[6]); aq[7] = fmaf(q, h1.w, aq[7]);
                ak[0] = fmaf(k, h0.x, ak[0]); ak[1] = fmaf(k, h0.y, ak[1]);
                ak[2] = fmaf(k, h0.z, ak[2]); ak[3] = fmaf(k, h0.w, ak[3]);
                ak[4] = fmaf(k, h1.x, ak[4]); ak[5] = fmaf(k, h1.y, ak[5]);
                ak[6] = fmaf(k, h1.z, ak[6]); ak[7] = fmaf(k, h1.w, ak[7]);
                av[0] = fmaf(v, h0.x, av[0]); av[1] = fmaf(v, h0.y, av[1]);
                av[2] = fmaf(v, h0.z, av[2]); av[3] = fmaf(v, h0.w, av[3]);
                av[4] = fmaf(v, h1.x, av[4]); av[5] = fmaf(v, h1.y, av[5]);
                av[6] = fmaf(v, h1.z, av[6]); av[7] = fmaf(v, h1.w, av[7]);
            }
        }
        float kk[8], kx[8], kn[8];
        #pragma unroll
        for (int s = 0; s < 8; ++s) {
            Qe[s] = siluf(aq[s]) * LOG2E;
            kk[s] = siluf(ak[s]);
            sK[g][tl][s] = kk[s];
            sV[g][tl][s] = siluf(av[s]);
            kx[s] = kk[s]; kn[s] = kk[s];
        }
        #pragma unroll
        for (int off = 32; off; off >>= 1) {
            #pragma unroll
            for (int s = 0; s < 8; ++s) {
                kx[s] = fmaxf(kx[s], __shfl_xor(kx[s], off));
                kn[s] = fminf(kn[s], __shfl_xor(kn[s], off));
            }
        }
        if ((tid & 63) == 0) {
            #pragma unroll
            for (int s = 0; s < 8; ++s) { skr[g][wg][0][s] = kx[s]; skr[g][wg][1][s] = kn[s]; }
        }
    }
    __syncthreads();

    // ---- C: attention row tl, single pass, global-bound shift (log2) ----
    {
        float bnd2 = 0.f;
        #pragma unroll
        for (int s = 0; s < 8; ++s) {
            const float kx = fmaxf(skr[g][0][0][s], skr[g][1][0][s]);
            const float kn = fminf(skr[g][0][1][s], skr[g][1][1][s]);
            bnd2 += fmaxf(Qe[s] * kx, Qe[s] * kn);
        }
        float l = 0.f;
        float t0 = 0.f, t1 = 0.f, t2 = 0.f, t3 = 0.f;
        float t4 = 0.f, t5 = 0.f, t6 = 0.f, t7 = 0.f;
        #pragma unroll 2
        for (int j = 0; j < NDIM; ++j) {
            const float4 k0 = *(const float4*)&sK[g][j][0];
            const float4 k1 = *(const float4*)&sK[g][j][4];
            float d = fmaf(Qe[0], k0.x, -bnd2);
            d = fmaf(Qe[1], k0.y, d); d = fmaf(Qe[2], k0.z, d); d = fmaf(Qe[3], k0.w, d);
            d = fmaf(Qe[4], k1.x, d); d = fmaf(Qe[5], k1.y, d);
            d = fmaf(Qe[6], k1.z, d); d = fmaf(Qe[7], k1.w, d);
            const float e = fexp2(d);
            const float4 v0 = *(const float4*)&sV[g][j][0];
            const float4 v1 = *(const float4*)&sV[g][j][4];
            l += e;
            t0 = fmaf(e, v0.x, t0); t1 = fmaf(e, v0.y, t1);
            t2 = fmaf(e, v0.z, t2); t3 = fmaf(e, v0.w, t3);
            t4 = fmaf(e, v1.x, t4); t5 = fmaf(e, v1.y, t5);
            t6 = fmaf(e, v1.z, t6); t7 = fmaf(e, v1.w, t7);
        }
        const float rl = frcp(l);
        sz[g][0][tl] = siluf(t0 * rl); sz[g][1][tl] = siluf(t1 * rl);
        sz[g][2][tl] = siluf(t2 * rl); sz[g][3][tl] = siluf(t3 * rl);
        sz[g][4][tl] = siluf(t4 * rl); sz[g][5][tl] = siluf(t5 * rl);
        sz[g][6][tl] = siluf(t6 * rl); sz[g][7][tl] = siluf(t7 * rl);
    }
    __syncthreads();

    // ---- D: w[s,o] = silu(z @ Wout + bout). R on tids 0-127, J on 128-191 ----
    if (tid < 192) {
        const int gm = (tid < 128) ? 1 : 0;
        const int t2 = (tid < 128) ? tid : tid - 128;
        const int lo2 = gm ? 4 : 3;
        const int outd = 1 << lo2;
        const int s = t2 >> lo2, o = t2 & (outd - 1);
        const float* Wo = gm ? RWout : JWout;
        const float* bo = gm ? Rbout : Jbout;
        float a = bo[o];
        #pragma unroll 8
        for (int c = 0; c < NDIM / 4; ++c) {
            const float4 z4 = *(const float4*)&sz[gm][s][4 * c];
            a = fmaf(z4.x, Wo[(4 * c + 0) * outd + o], a);
            a = fmaf(z4.y, Wo[(4 * c + 1) * outd + o], a);
            a = fmaf(z4.z, Wo[(4 * c + 2) * outd + o], a);
            a = fmaf(z4.w, Wo[(4 * c + 3) * outd + o], a);
        }
        sw[gm][t2] = siluf(a);
    }
    __syncthreads();

    // ---- J scalar + R group sums ----
    if (tid < 64) {
        float v = sw[0][tid];
        #pragma unroll
        for (int off = 32; off; off >>= 1) v += __shfl_xor(v, off);
        if (tid == 0) sJv = v;
    } else if (tid < 96) {
        const int t = tid - 64, pq = t >> 3, c = t & 7;
        const int base = c * 16 + pq * 4;
        sg[t] = (double)sw[1][base] + (double)sw[1][base + 1]
              + (double)sw[1][base + 2] + (double)sw[1][base + 3];
    }
    __syncthreads();

    // ---- assembly: Rupper, Laplacian Rm, u = (J_eff - Rm Rm^T) dH ----
    const int ii = (tid >> 4) & 15, jj = tid & 15;
    {
        const double rij = sg[((ii >> 3) * 2 + (jj >> 3)) * 8 + (jj & 7)];
        const double rji = sg[((jj >> 3) * 2 + (ii >> 3)) * 8 + (ii & 7)];
        sRm[ii][jj] = rij * rij + rji * rji;
    }
    __syncthreads();

    if (tid < 16) {
        double a = 0.0;
        for (int j = 0; j < 16; ++j) a += sRm[tid][j];
        srs[tid] = a;
    }
    __syncthreads();

    {
        const double v = (ii == jj) ? srs[ii] : -sRm[ii][jj];
        __syncthreads();
        sRm[ii][jj] = v;
    }
    __syncthreads();

    if (tid < 16) {
        double a = 0.0;
        for (int j = 0; j < 16; ++j) a += sRm[tid][j] * sdH[j];
        svv[tid] = a;
    }
    __syncthreads();

    if (tid < 16) {
        double a = 0.0;
        for (int k = 0; k < 16; ++k) a += sRm[tid][k] * svv[k];
        const double sj = (double)sJv;
        const double jterm = (tid < 8) ? 2.0 * sj * sdH[8 + tid]
                                       : -2.0 * sj * sdH[tid - 8];
        inout[b * 16 + tid] = (float)(jterm - a);
    }
}

// ---------------------------------------------------------------------------
extern "C" void kernel_launch(void* const* d_in, const int* in_sizes, int n_in,
                              void* d_out, int out_size, void* d_ws, size_t ws_size,
                              hipStream_t stream)
{
    const float* x = (const float*)d_in[0];
    float* out = (float*)d_out;

#define ARGS10(base) \
    (const float*)d_in[(base) + 0], (const float*)d_in[(base) + 1], \
    (const float*)d_in[(base) + 2], (const float*)d_in[(base) + 3], \
    (const float*)d_in[(base) + 4], (const float*)d_in[(base) + 5], \
    (const float*)d_in[(base) + 6], (const float*)d_in[(base) + 7], \
    (const float*)d_in[(base) + 8], (const float*)d_in[(base) + 9]

    k_hgrad<<<dim3(512), dim3(256), 0, stream>>>(x, ARGS10(1), out);
    k_jr<<<dim3(512), dim3(256), 0, stream>>>(x, ARGS10(11), ARGS10(21), out);
#undef ARGS10
}

// Round 9
// 140.040 us; speedup vs baseline: 1.1928x; 1.0223x over previous
//
#include <hip/hip_runtime.h>

#define NDIM 128
#define NOBS 16
#define LOG2E 1.44269504088896341f

typedef float f32x2 __attribute__((ext_vector_type(2)));

__device__ __forceinline__ float frcp(float x) { return __builtin_amdgcn_rcpf(x); }
__device__ __forceinline__ float fexp2(float x) { return __builtin_amdgcn_exp2f(x); }
__device__ __forceinline__ float fexp(float x) { return __builtin_amdgcn_exp2f(x * LOG2E); }
__device__ __forceinline__ float sigf(float v) { return frcp(1.0f + fexp(-v)); }
__device__ __forceinline__ float siluf(float v) { return v * sigf(v); }
__device__ __forceinline__ float dsiluf(float v) {
    float s = sigf(v);
    return s * (1.0f + v * (1.0f - s));
}
// 2-wide fma; selects v_pk_fma_f32 on CDNA when operands are register pairs.
__device__ __forceinline__ f32x2 pkfma(f32x2 a, f32x2 b, f32x2 c) {
    return __builtin_elementwise_fma(a, b, c);
}

// ---------------------------------------------------------------------------
// Kernel 1: H-module gradient. One block = one BATCH (8 rows), 256 threads.
// tl = tid&127 owns dim tl; tg = tid>>7 owns rows 4*tg..4*tg+3.
// Round-8 structure (separate LDS buffers) + packed-f32 hot loops.
// Writes dHdz (512 x 16) into d_out staging; k_jr overwrites with u.
// ---------------------------------------------------------------------------
__global__ __launch_bounds__(256) void k_hgrad(
    const float* __restrict__ x,
    const float* __restrict__ Win, const float* __restrict__ bin,
    const float* __restrict__ Aq, const float* __restrict__ Ak, const float* __restrict__ Av,
    const float* __restrict__ Bq, const float* __restrict__ Bk, const float* __restrict__ Bv,
    const float* __restrict__ Wout, const float* __restrict__ bout,
    float* __restrict__ dHdz)
{
    const int b   = blockIdx.x;
    const int tid = threadIdx.x;
    const int tl  = tid & 127;
    const int tg  = tid >> 7;
    const int wid = tid >> 6;
    const int r0  = tg * 4;

    __shared__ float  sx[8][NOBS];
    __shared__ float  sh[8][NDIM];
    __shared__ float4 sKVQ[8][NDIM];   // {K, V, 1.0, K*V}
    __shared__ float  sz[8][NDIM];
    __shared__ float4 sC[8][NDIM];     // {wt, wt*Q, wt*Q*t, Qe}
    __shared__ float4 sD[8][NDIM];     // {dQp, dKp, dVp, 0}
    __shared__ float  sy[8][26], swp[8][26], sdwp[8][26];
    __shared__ float  skmax[4][4], skmin[4][4];
    __shared__ float  sred[4][4][2];

    if (tid < 128) sx[tid >> 4][tid & 15] = x[b * 128 + tid];
    __syncthreads();

    // ---- A: h = silu(x @ Win + bin) ----
    float hp[4];
    {
        float acc[4];
        const float b0 = bin[tl];
        #pragma unroll
        for (int r = 0; r < 4; ++r) acc[r] = b0;
        #pragma unroll
        for (int o = 0; o < NOBS; ++o) {
            const float w = Win[o * NDIM + tl];
            #pragma unroll
            for (int r = 0; r < 4; ++r) acc[r] = fmaf(w, sx[r0 + r][o], acc[r]);
        }
        #pragma unroll
        for (int r = 0; r < 4; ++r) { hp[r] = acc[r]; sh[r0 + r][tl] = siluf(acc[r]); }
    }
    __syncthreads();

    // ---- B: Q,K,V = silu(A h + B); packed pairs over the k-dimension ----
    float Qp[4], Kp[4], Vp[4], Qv[4], Kv[4], Vv[4], Qe[4];
    {
        f32x2 aq2[4], ak2[4], av2[4];
        const float bq = Bq[tl], bk = Bk[tl], bv = Bv[tl];
        #pragma unroll
        for (int r = 0; r < 4; ++r) {
            aq2[r] = (f32x2){bq, 0.f}; ak2[r] = (f32x2){bk, 0.f}; av2[r] = (f32x2){bv, 0.f};
        }
        const float4* Aq4 = (const float4*)(Aq + tl * NDIM);
        const float4* Ak4 = (const float4*)(Ak + tl * NDIM);
        const float4* Av4 = (const float4*)(Av + tl * NDIM);
        #pragma unroll 2
        for (int c = 0; c < NDIM / 4; ++c) {
            const float4 wq = Aq4[c], wk = Ak4[c], wv = Av4[c];
            const f32x2* wqp = (const f32x2*)&wq;
            const f32x2* wkp = (const f32x2*)&wk;
            const f32x2* wvp = (const f32x2*)&wv;
            #pragma unroll
            for (int r = 0; r < 4; ++r) {
                const float4 h4 = *(const float4*)&sh[r0 + r][4 * c];
                const f32x2* hp2 = (const f32x2*)&h4;
                aq2[r] = pkfma(wqp[0], hp2[0], aq2[r]);
                aq2[r] = pkfma(wqp[1], hp2[1], aq2[r]);
                ak2[r] = pkfma(wkp[0], hp2[0], ak2[r]);
                ak2[r] = pkfma(wkp[1], hp2[1], ak2[r]);
                av2[r] = pkfma(wvp[0], hp2[0], av2[r]);
                av2[r] = pkfma(wvp[1], hp2[1], av2[r]);
            }
        }
        float kmx[4], kmn[4];
        #pragma unroll
        for (int r = 0; r < 4; ++r) {
            Qp[r] = aq2[r].x + aq2[r].y;
            Kp[r] = ak2[r].x + ak2[r].y;
            Vp[r] = av2[r].x + av2[r].y;
            Qv[r] = siluf(Qp[r]); Kv[r] = siluf(Kp[r]); Vv[r] = siluf(Vp[r]);
            Qe[r] = Qv[r] * LOG2E;
            sKVQ[r0 + r][tl] = make_float4(Kv[r], Vv[r], 1.0f, Kv[r] * Vv[r]);
            kmx[r] = Kv[r]; kmn[r] = Kv[r];
        }
        #pragma unroll
        for (int off = 32; off; off >>= 1) {
            #pragma unroll
            for (int r = 0; r < 4; ++r) {
                kmx[r] = fmaxf(kmx[r], __shfl_xor(kmx[r], off));
                kmn[r] = fminf(kmn[r], __shfl_xor(kmn[r], off));
            }
        }
        if ((tid & 63) == 0) {
            #pragma unroll
            for (int r = 0; r < 4; ++r) { skmax[wid][r] = kmx[r]; skmin[wid][r] = kmn[r]; }
        }
    }
    __syncthreads();

    // ---- C: softmax fwd (+ dQ sums folded), log2 domain, packed accums ----
    float mi2[4], rl[4], ti[4], sk[4], skv[4];
    {
        f32x2 st[4], lv[4];   // st = {sk, tn}; lv = {l, skv}
        #pragma unroll
        for (int r = 0; r < 4; ++r) {
            const float kx = fmaxf(skmax[2 * tg][r], skmax[2 * tg + 1][r]);
            const float kn = fminf(skmin[2 * tg][r], skmin[2 * tg + 1][r]);
            mi2[r] = fmaxf(Qe[r] * kx, Qe[r] * kn);
            st[r] = (f32x2){0.f, 0.f}; lv[r] = (f32x2){0.f, 0.f};
        }
        #pragma unroll 2
        for (int j = 0; j < NDIM; ++j) {
            #pragma unroll
            for (int r = 0; r < 4; ++r) {
                const float4 kv4 = sKVQ[r0 + r][j];
                const f32x2* kvp = (const f32x2*)&kv4;
                const float e = fexp2(fmaf(Qe[r], kv4.x, -mi2[r]));
                const f32x2 e2 = {e, e};
                st[r] = pkfma(e2, kvp[0], st[r]);   // {sk,tn} += e*{K,V}
                lv[r] = pkfma(e2, kvp[1], lv[r]);   // {l,skv} += e*{1,KV}
            }
        }
        #pragma unroll
        for (int r = 0; r < 4; ++r) {
            sk[r] = st[r].x; skv[r] = lv[r].y;
            rl[r] = frcp(lv[r].x);
            ti[r] = st[r].y * rl[r];
            sz[r0 + r][tl] = siluf(ti[r]);
        }
    }
    __syncthreads();

    // ---- y = silu(z @ Wout + bout), 8x25 tasks ----
    if (tid < 200) {
        const int r = tid / 25, o = tid - 25 * (tid / 25);
        float a = bout[o];
        #pragma unroll 8
        for (int c = 0; c < NDIM / 4; ++c) {
            const float4 z4 = *(const float4*)&sz[r][4 * c];
            a = fmaf(z4.x, Wout[(4 * c + 0) * 25 + o], a);
            a = fmaf(z4.y, Wout[(4 * c + 1) * 25 + o], a);
            a = fmaf(z4.z, Wout[(4 * c + 2) * 25 + o], a);
            a = fmaf(z4.w, Wout[(4 * c + 3) * 25 + o], a);
        }
        swp[r][o] = a;
        sy[r][o] = siluf(a);
    }
    __syncthreads();

    // ---- backward through the quadratic head ----
    if (tid < 200) {
        const int r = tid / 25, o = tid - 25 * (tid / 25);
        float m11 = 0.f, m12 = 0.f, m21 = 0.f, m22 = 0.f;
        for (int k = 0;  k < 5;  ++k) m11 += sy[r][k] * sy[r][k];
        for (int k = 5;  k < 10; ++k) m12 += sy[r][k] * sy[r][k];
        for (int k = 10; k < 15; ++k) m21 += sy[r][k] * sy[r][k];
        for (int k = 15; k < 20; ++k) m22 += sy[r][k] * sy[r][k];
        const float q0 = sy[r][0], q1 = sy[r][1], q2 = sy[r][2], q3 = sy[r][3];
        const float dm11 = q0 * q0 + q1 * q1;
        const float dm12 = q0 * q2 + q1 * q3;
        const float dm22 = q2 * q2 + q3 * q3;
        float dy;
        if      (o < 5)  dy = 2.0f * sy[r][o] * dm11;
        else if (o < 15) dy = 2.0f * sy[r][o] * dm12;
        else if (o < 20) dy = 2.0f * sy[r][o] * dm22;
        else             dy = 2.0f * sy[r][o];
        const float ms = m12 + m21;
        if (o == 0) dy += 2.0f * m11 * q0 + ms * q2;
        if (o == 1) dy += 2.0f * m11 * q1 + ms * q3;
        if (o == 2) dy += ms * q0 + 2.0f * m22 * q2;
        if (o == 3) dy += ms * q1 + 2.0f * m22 * q3;
        sdwp[r][o] = dy * dsiluf(swp[r][o]);
    }
    __syncthreads();

    // ---- E: dt, closed-form dQ, coefficient pack into sC (2^-m folded) ----
    float dQp_[4];
    {
        float wr[25];
        #pragma unroll
        for (int k = 0; k < 25; ++k) wr[k] = Wout[tl * 25 + k];
        float dt[4] = {0.f, 0.f, 0.f, 0.f};
        #pragma unroll
        for (int k = 0; k < 25; ++k) {
            #pragma unroll
            for (int r = 0; r < 4; ++r)
                dt[r] = fmaf(wr[k], sdwp[r0 + r][k], dt[r]);
        }
        #pragma unroll
        for (int r = 0; r < 4; ++r) {
            dt[r] *= dsiluf(ti[r]);
            const float w = dt[r] * rl[r];
            dQp_[r] = (w * fmaf(-ti[r], sk[r], skv[r])) * dsiluf(Qp[r]);
            const float wt = w * fexp2(-mi2[r]);
            const float c1 = wt * Qv[r];
            sC[r0 + r][tl] = make_float4(wt, c1, c1 * ti[r], Qe[r]);
        }
    }
    __syncthreads();

    // ---- F: dK_j / dV_j -> sD; packed {accv,k1} pair ----
    {
        f32x2 vk[4];
        float k2s[4];
        #pragma unroll
        for (int r = 0; r < 4; ++r) { vk[r] = (f32x2){0.f, 0.f}; k2s[r] = 0.f; }
        #pragma unroll 2
        for (int i = 0; i < NDIM; ++i) {
            #pragma unroll
            for (int r = 0; r < 4; ++r) {
                const float4 c4 = sC[r0 + r][i];
                const f32x2* cp = (const f32x2*)&c4;
                const float e = fexp2(c4.w * Kv[r]);
                const f32x2 e2 = {e, e};
                vk[r] = pkfma(e2, cp[0], vk[r]);       // {accv,k1} += e*{wt,c1}
                k2s[r] = fmaf(e, c4.z, k2s[r]);
            }
        }
        #pragma unroll
        for (int r = 0; r < 4; ++r) {
            const float dVp_ = vk[r].x * dsiluf(Vp[r]);
            const float dKp_ = fmaf(Vv[r], vk[r].y, -k2s[r]) * dsiluf(Kp[r]);
            sD[r0 + r][tl] = make_float4(dQp_[r], dKp_, dVp_, 0.f);
        }
    }
    __syncthreads();

    // ---- G: dh_d = sum_i Aq[i][d]dQp + Ak[i][d]dKp + Av[i][d]dVp ----
    float dhp[4];
    {
        float acc[4] = {0.f, 0.f, 0.f, 0.f};
        #pragma unroll 4
        for (int i = 0; i < NDIM; ++i) {
            const float aqv = Aq[i * NDIM + tl];
            const float akv = Ak[i * NDIM + tl];
            const float avv = Av[i * NDIM + tl];
            #pragma unroll
            for (int r = 0; r < 4; ++r) {
                const float4 d4 = sD[r0 + r][i];
                acc[r] = fmaf(aqv, d4.x, acc[r]);
                acc[r] = fmaf(akv, d4.y, acc[r]);
                acc[r] = fmaf(avv, d4.z, acc[r]);
            }
        }
        #pragma unroll
        for (int r = 0; r < 4; ++r) dhp[r] = acc[r] * dsiluf(hp[r]);
    }

    // ---- dx_o (o=0,1): shuffle reduce per row, cross-wave combine ----
    {
        const float w0 = Win[tl], w1 = Win[NDIM + tl];
        float t0[4], t1[4];
        #pragma unroll
        for (int r = 0; r < 4; ++r) { t0[r] = w0 * dhp[r]; t1[r] = w1 * dhp[r]; }
        #pragma unroll
        for (int off = 32; off; off >>= 1) {
            #pragma unroll
            for (int r = 0; r < 4; ++r) {
                t0[r] += __shfl_xor(t0[r], off);
                t1[r] += __shfl_xor(t1[r], off);
            }
        }
        if ((tid & 63) == 0) {
            #pragma unroll
            for (int r = 0; r < 4; ++r) { sred[wid][r][0] = t0[r]; sred[wid][r][1] = t1[r]; }
        }
    }
    __syncthreads();
    if (tid < 16) {
        const int o = tid >> 3, ag = tid & 7;
        const int gg = ag >> 2, rr = ag & 3;
        dHdz[b * 16 + o * 8 + ag] = sred[2 * gg][rr][o] + sred[2 * gg + 1][rr][o];
    }
}

// ---------------------------------------------------------------------------
// Kernel 2: one batch per 256-thread block. J on tids 0-127, R on 128-255.
// One thread = one dim, all 8 agents; packed pairs over agents (stage B) and
// over the dot/accumulate (stage C). In-block 16x16 assembly.
// ---------------------------------------------------------------------------
__global__ __launch_bounds__(256) void k_jr(
    const float* __restrict__ x,
    const float* __restrict__ JWin, const float* __restrict__ Jbin,
    const float* __restrict__ JAq, const float* __restrict__ JAk, const float* __restrict__ JAv,
    const float* __restrict__ JBq, const float* __restrict__ JBk, const float* __restrict__ JBv,
    const float* __restrict__ JWout, const float* __restrict__ Jbout,
    const float* __restrict__ RWin, const float* __restrict__ Rbin,
    const float* __restrict__ RAq, const float* __restrict__ RAk, const float* __restrict__ RAv,
    const float* __restrict__ RBq, const float* __restrict__ RBk, const float* __restrict__ RBv,
    const float* __restrict__ RWout, const float* __restrict__ Rbout,
    float* __restrict__ inout)
{
    __shared__ float  sx[128];
    __shared__ float  sh[2][NDIM][8];
    __shared__ float  sK[2][NDIM][8];
    __shared__ float  sV[2][NDIM][8];
    __shared__ float  sz[2][8][132];
    __shared__ float  sw[2][NDIM];
    __shared__ float  skr[2][2][2][8];
    __shared__ float  sJv;
    __shared__ double sdH[16], sg[32], sRm[16][17], srs[16], svv[16];

    const int b   = blockIdx.x;
    const int tid = threadIdx.x;
    const int g   = tid >> 7;
    const int tl  = tid & 127;
    const int wg  = (tid >> 6) & 1;

    if (tid < 128) sx[tid] = x[b * 128 + tid];
    else if (tid < 144) sdH[tid - 128] = (double)inout[b * 16 + (tid - 128)];
    __syncthreads();

    const float* Win  = g ? RWin  : JWin;
    const float* bin_ = g ? Rbin  : Jbin;
    const float* Aq   = g ? RAq   : JAq;
    const float* Ak   = g ? RAk   : JAk;
    const float* Av   = g ? RAv   : JAv;
    const float* Bq   = g ? RBq   : JBq;
    const float* Bk   = g ? RBk   : JBk;
    const float* Bv   = g ? RBv   : JBv;

    // ---- A: h[a][tl] for all 8 agents ----
    {
        float acc[8];
        const float b0 = bin_[tl];
        #pragma unroll
        for (int a = 0; a < 8; ++a) acc[a] = b0;
        #pragma unroll
        for (int c = 0; c < 4; ++c) {
            const float w0 = Win[(4 * c + 0) * NDIM + tl];
            const float w1 = Win[(4 * c + 1) * NDIM + tl];
            const float w2 = Win[(4 * c + 2) * NDIM + tl];
            const float w3 = Win[(4 * c + 3) * NDIM + tl];
            #pragma unroll
            for (int a = 0; a < 8; ++a) {
                const float4 x4 = *(const float4*)&sx[a * 16 + 4 * c];
                acc[a] = fmaf(w0, x4.x, acc[a]);
                acc[a] = fmaf(w1, x4.y, acc[a]);
                acc[a] = fmaf(w2, x4.z, acc[a]);
                acc[a] = fmaf(w3, x4.w, acc[a]);
            }
        }
        *(float4*)&sh[g][tl][0] =
            make_float4(siluf(acc[0]), siluf(acc[1]), siluf(acc[2]), siluf(acc[3]));
        *(float4*)&sh[g][tl][4] =
            make_float4(siluf(acc[4]), siluf(acc[5]), siluf(acc[6]), siluf(acc[7]));
    }
    __syncthreads();

    // ---- B: Q,K,V for all 8 agents; packed agent-pairs, broadcast weight ----
    f32x2 qe2[4];
    {
        f32x2 aq2[4], ak2[4], av2[4];
        const float bq = Bq[tl], bk = Bk[tl], bv = Bv[tl];
        #pragma unroll
        for (int p = 0; p < 4; ++p) {
            aq2[p] = (f32x2){bq, bq}; ak2[p] = (f32x2){bk, bk}; av2[p] = (f32x2){bv, bv};
        }
        const float4* Aq4 = (const float4*)(Aq + tl * NDIM);
        const float4* Ak4 = (const float4*)(Ak + tl * NDIM);
        const float4* Av4 = (const float4*)(Av + tl * NDIM);
        for (int c = 0; c < NDIM / 4; ++c) {
            const float4 wq = Aq4[c], wk = Ak4[c], wv = Av4[c];
            const float wqa[4] = {wq.x, wq.y, wq.z, wq.w};
            const float wka[4] = {wk.x, wk.y, wk.z, wk.w};
            const float wva[4] = {wv.x, wv.y, wv.z, wv.w};
            #pragma unroll
            for (int jj = 0; jj < 4; ++jj) {
                const float4 h0 = *(const float4*)&sh[g][4 * c + jj][0];
                const float4 h1 = *(const float4*)&sh[g][4 * c + jj][4];
                const f32x2* h0p = (const f32x2*)&h0;
                const f32x2* h1p = (const f32x2*)&h1;
                const f32x2 qq = {wqa[jj], wqa[jj]};
                const f32x2 kk2 = {wka[jj], wka[jj]};
                const f32x2 vv2 = {wva[jj], wva[jj]};
                aq2[0] = pkfma(qq, h0p[0], aq2[0]); aq2[1] = pkfma(qq, h0p[1], aq2[1]);
                aq2[2] = pkfma(qq, h1p[0], aq2[2]); aq2[3] = pkfma(qq, h1p[1], aq2[3]);
                ak2[0] = pkfma(kk2, h0p[0], ak2[0]); ak2[1] = pkfma(kk2, h0p[1], ak2[1]);
                ak2[2] = pkfma(kk2, h1p[0], ak2[2]); ak2[3] = pkfma(kk2, h1p[1], ak2[3]);
                av2[0] = pkfma(vv2, h0p[0], av2[0]); av2[1] = pkfma(vv2, h0p[1], av2[1]);
                av2[2] = pkfma(vv2, h1p[0], av2[2]); av2[3] = pkfma(vv2, h1p[1], av2[3]);
            }
        }
        float kk[8], kx[8], kn[8];
        #pragma unroll
        for (int s = 0; s < 8; ++s) {
            const int p = s >> 1, e = s & 1;
            qe2[p][e] = siluf(aq2[p][e]) * LOG2E;
            kk[s] = siluf(ak2[p][e]);
            sK[g][tl][s] = kk[s];
            sV[g][tl][s] = siluf(av2[p][e]);
            kx[s] = kk[s]; kn[s] = kk[s];
        }
        #pragma unroll
        for (int off = 32; off; off >>= 1) {
            #pragma unroll
            for (int s = 0; s < 8; ++s) {
                kx[s] = fmaxf(kx[s], __shfl_xor(kx[s], off));
                kn[s] = fminf(kn[s], __shfl_xor(kn[s], off));
            }
        }
        if ((tid & 63) == 0) {
            #pragma unroll
            for (int s = 0; s < 8; ++s) { skr[g][wg][0][s] = kx[s]; skr[g][wg][1][s] = kn[s]; }
        }
    }
    __syncthreads();

    // ---- C: attention row tl, single pass, global-bound shift; packed ----
    {
        float bnd2 = 0.f;
        #pragma unroll
        for (int s = 0; s < 8; ++s) {
            const float kx = fmaxf(skr[g][0][0][s], skr[g][1][0][s]);
            const float kn = fminf(skr[g][0][1][s], skr[g][1][1][s]);
            const float q = qe2[s >> 1][s & 1];
            bnd2 += fmaxf(q * kx, q * kn);
        }
        float l = 0.f;
        f32x2 t2[4];
        #pragma unroll
        for (int p = 0; p < 4; ++p) t2[p] = (f32x2){0.f, 0.f};
        #pragma unroll 2
        for (int j = 0; j < NDIM; ++j) {
            const float4 k0 = *(const float4*)&sK[g][j][0];
            const float4 k1 = *(const float4*)&sK[g][j][4];
            const f32x2* k0p = (const f32x2*)&k0;
            const f32x2* k1p = (const f32x2*)&k1;
            f32x2 d2 = {-bnd2, 0.f};
            d2 = pkfma(qe2[0], k0p[0], d2);
            d2 = pkfma(qe2[1], k0p[1], d2);
            d2 = pkfma(qe2[2], k1p[0], d2);
            d2 = pkfma(qe2[3], k1p[1], d2);
            const float e = fexp2(d2.x + d2.y);
            const float4 v0 = *(const float4*)&sV[g][j][0];
            const float4 v1 = *(const float4*)&sV[g][j][4];
            const f32x2* v0p = (const f32x2*)&v0;
            const f32x2* v1p = (const f32x2*)&v1;
            const f32x2 e2 = {e, e};
            l += e;
            t2[0] = pkfma(e2, v0p[0], t2[0]);
            t2[1] = pkfma(e2, v0p[1], t2[1]);
            t2[2] = pkfma(e2, v1p[0], t2[2]);
            t2[3] = pkfma(e2, v1p[1], t2[3]);
        }
        const float rl = frcp(l);
        #pragma unroll
        for (int s = 0; s < 8; ++s)
            sz[g][s][tl] = siluf(t2[s >> 1][s & 1] * rl);
    }
    __syncthreads();

    // ---- D: w[s,o] = silu(z @ Wout + bout). R on tids 0-127, J on 128-191 ----
    if (tid < 192) {
        const int gm = (tid < 128) ? 1 : 0;
        const int t2 = (tid < 128) ? tid : tid - 128;
        const int lo2 = gm ? 4 : 3;
        const int outd = 1 << lo2;
        const int s = t2 >> lo2, o = t2 & (outd - 1);
        const float* Wo = gm ? RWout : JWout;
        const float* bo = gm ? Rbout : Jbout;
        float a = bo[o];
        #pragma unroll 8
        for (int c = 0; c < NDIM / 4; ++c) {
            const float4 z4 = *(const float4*)&sz[gm][s][4 * c];
            a = fmaf(z4.x, Wo[(4 * c + 0) * outd + o], a);
            a = fmaf(z4.y, Wo[(4 * c + 1) * outd + o], a);
            a = fmaf(z4.z, Wo[(4 * c + 2) * outd + o], a);
            a = fmaf(z4.w, Wo[(4 * c + 3) * outd + o], a);
        }
        sw[gm][t2] = siluf(a);
    }
    __syncthreads();

    // ---- J scalar + R group sums ----
    if (tid < 64) {
        float v = sw[0][tid];
        #pragma unroll
        for (int off = 32; off; off >>= 1) v += __shfl_xor(v, off);
        if (tid == 0) sJv = v;
    } else if (tid < 96) {
        const int t = tid - 64, pq = t >> 3, c = t & 7;
        const int base = c * 16 + pq * 4;
        sg[t] = (double)sw[1][base] + (double)sw[1][base + 1]
              + (double)sw[1][base + 2] + (double)sw[1][base + 3];
    }
    __syncthreads();

    // ---- assembly: Rupper, Laplacian Rm, u = (J_eff - Rm Rm^T) dH ----
    const int ii = (tid >> 4) & 15, jj = tid & 15;
    {
        const double rij = sg[((ii >> 3) * 2 + (jj >> 3)) * 8 + (jj & 7)];
        const double rji = sg[((jj >> 3) * 2 + (ii >> 3)) * 8 + (ii & 7)];
        sRm[ii][jj] = rij * rij + rji * rji;
    }
    __syncthreads();

    if (tid < 16) {
        double a = 0.0;
        for (int j = 0; j < 16; ++j) a += sRm[tid][j];
        srs[tid] = a;
    }
    __syncthreads();

    {
        const double v = (ii == jj) ? srs[ii] : -sRm[ii][jj];
        __syncthreads();
        sRm[ii][jj] = v;
    }
    __syncthreads();

    if (tid < 16) {
        double a = 0.0;
        for (int j = 0; j < 16; ++j) a += sRm[tid][j] * sdH[j];
        svv[tid] = a;
    }
    __syncthreads();

    if (tid < 16) {
        double a = 0.0;
        for (int k = 0; k < 16; ++k) a += sRm[tid][k] * svv[k];
        const double sj = (double)sJv;
        const double jterm = (tid < 8) ? 2.0 * sj * sdH[8 + tid]
                                       : -2.0 * sj * sdH[tid - 8];
        inout[b * 16 + tid] = (float)(jterm - a);
    }
}

// ---------------------------------------------------------------------------
extern "C" void kernel_launch(void* const* d_in, const int* in_sizes, int n_in,
                              void* d_out, int out_size, void* d_ws, size_t ws_size,
                              hipStream_t stream)
{
    const float* x = (const float*)d_in[0];
    float* out = (float*)d_out;

#define ARGS10(base) \
    (const float*)d_in[(base) + 0], (const float*)d_in[(base) + 1], \
    (const float*)d_in[(base) + 2], (const float*)d_in[(base) + 3], \
    (const float*)d_in[(base) + 4], (const float*)d_in[(base) + 5], \
    (const float*)d_in[(base) + 6], (const float*)d_in[(base) + 7], \
    (const float*)d_in[(base) + 8], (const float*)d_in[(base) + 9]

    k_hgrad<<<dim3(512), dim3(256), 0, stream>>>(x, ARGS10(1), out);
    k_jr<<<dim3(512), dim3(256), 0, stream>>>(x, ARGS10(11), ARGS10(21), out);
#undef ARGS10
}

// Round 10
// 133.422 us; speedup vs baseline: 1.2520x; 1.0496x over previous
//
#include <hip/hip_runtime.h>

#define NDIM 128
#define NOBS 16
#define LOG2E 1.44269504088896341f

typedef float f32x2 __attribute__((ext_vector_type(2)));

__device__ __forceinline__ float frcp(float x) { return __builtin_amdgcn_rcpf(x); }
__device__ __forceinline__ float fexp2(float x) { return __builtin_amdgcn_exp2f(x); }
__device__ __forceinline__ float fexp(float x) { return __builtin_amdgcn_exp2f(x * LOG2E); }
__device__ __forceinline__ float sigf(float v) { return frcp(1.0f + fexp(-v)); }
__device__ __forceinline__ float siluf(float v) { return v * sigf(v); }
__device__ __forceinline__ float dsiluf(float v) {
    float s = sigf(v);
    return s * (1.0f + v * (1.0f - s));
}
__device__ __forceinline__ f32x2 pkfma(f32x2 a, f32x2 b, f32x2 c) {
    return __builtin_elementwise_fma(a, b, c);
}

// ---- LDS layouts: both phases union into one 60.6 KB block ----------------
// Both structs BEGIN with the identical 512-byte x image, so x loaded in the
// H phase persists into the JR phase (no H-phase field aliases offset 0-511).
struct HS {
    float  sx[8][NOBS];
    float  sh[8][NDIM];
    float4 sKVQ[8][NDIM];   // {K, V, 1.0, K*V}
    float  sz[8][NDIM];
    float4 sC[8][NDIM];     // {wt, wt*Q, wt*Q*t, Qe}
    float4 sD[8][NDIM];     // {dQp, dKp, dVp, 0}
    float  sy[8][26], swp[8][26], sdwp[8][26];
    float  skmax[4][4], skmin[4][4];
    float  sred[4][4][2];
};
struct JRS {
    float sx[128];          // aliases HS::sx — same linear layout
    float sh[2][NDIM][8];
    float sK[2][NDIM][8];
    float sV[2][NDIM][8];
    float sz[2][8][132];
    float sw[2][NDIM];
    float skr[2][2][2][8];
};
union SU { HS h; JRS jr; };

// ---------------------------------------------------------------------------
// Phase 1: H-module gradient for one batch (8 rows). Round-9 proven body;
// writes the 16 dHdz values to sdHf (LDS) instead of global.
// ---------------------------------------------------------------------------
__device__ __forceinline__ void h_path(
    int b, int tid, HS& S,
    const float* __restrict__ x,
    const float* __restrict__ Win, const float* __restrict__ bin,
    const float* __restrict__ Aq, const float* __restrict__ Ak, const float* __restrict__ Av,
    const float* __restrict__ Bq, const float* __restrict__ Bk, const float* __restrict__ Bv,
    const float* __restrict__ Wout, const float* __restrict__ bout,
    float* sdHf)
{
    const int tl = tid & 127, tg = tid >> 7, wid = tid >> 6, r0 = tg * 4;

    if (tid < 128) S.sx[tid >> 4][tid & 15] = x[b * 128 + tid];
    __syncthreads();

    // ---- A: h = silu(x @ Win + bin) ----
    float hp[4];
    {
        float acc[4];
        const float b0 = bin[tl];
        #pragma unroll
        for (int r = 0; r < 4; ++r) acc[r] = b0;
        #pragma unroll
        for (int o = 0; o < NOBS; ++o) {
            const float w = Win[o * NDIM + tl];
            #pragma unroll
            for (int r = 0; r < 4; ++r) acc[r] = fmaf(w, S.sx[r0 + r][o], acc[r]);
        }
        #pragma unroll
        for (int r = 0; r < 4; ++r) { hp[r] = acc[r]; S.sh[r0 + r][tl] = siluf(acc[r]); }
    }
    __syncthreads();

    // ---- B: Q,K,V = silu(A h + B); packed pairs over the k-dimension ----
    float Qp[4], Kp[4], Vp[4], Qv[4], Kv[4], Vv[4], Qe[4];
    {
        f32x2 aq2[4], ak2[4], av2[4];
        const float bq = Bq[tl], bk = Bk[tl], bv = Bv[tl];
        #pragma unroll
        for (int r = 0; r < 4; ++r) {
            aq2[r] = (f32x2){bq, 0.f}; ak2[r] = (f32x2){bk, 0.f}; av2[r] = (f32x2){bv, 0.f};
        }
        const float4* Aq4 = (const float4*)(Aq + tl * NDIM);
        const float4* Ak4 = (const float4*)(Ak + tl * NDIM);
        const float4* Av4 = (const float4*)(Av + tl * NDIM);
        #pragma unroll 2
        for (int c = 0; c < NDIM / 4; ++c) {
            const float4 wq = Aq4[c], wk = Ak4[c], wv = Av4[c];
            const f32x2* wqp = (const f32x2*)&wq;
            const f32x2* wkp = (const f32x2*)&wk;
            const f32x2* wvp = (const f32x2*)&wv;
            #pragma unroll
            for (int r = 0; r < 4; ++r) {
                const float4 h4 = *(const float4*)&S.sh[r0 + r][4 * c];
                const f32x2* hp2 = (const f32x2*)&h4;
                aq2[r] = pkfma(wqp[0], hp2[0], aq2[r]);
                aq2[r] = pkfma(wqp[1], hp2[1], aq2[r]);
                ak2[r] = pkfma(wkp[0], hp2[0], ak2[r]);
                ak2[r] = pkfma(wkp[1], hp2[1], ak2[r]);
                av2[r] = pkfma(wvp[0], hp2[0], av2[r]);
                av2[r] = pkfma(wvp[1], hp2[1], av2[r]);
            }
        }
        float kmx[4], kmn[4];
        #pragma unroll
        for (int r = 0; r < 4; ++r) {
            Qp[r] = aq2[r].x + aq2[r].y;
            Kp[r] = ak2[r].x + ak2[r].y;
            Vp[r] = av2[r].x + av2[r].y;
            Qv[r] = siluf(Qp[r]); Kv[r] = siluf(Kp[r]); Vv[r] = siluf(Vp[r]);
            Qe[r] = Qv[r] * LOG2E;
            S.sKVQ[r0 + r][tl] = make_float4(Kv[r], Vv[r], 1.0f, Kv[r] * Vv[r]);
            kmx[r] = Kv[r]; kmn[r] = Kv[r];
        }
        #pragma unroll
        for (int off = 32; off; off >>= 1) {
            #pragma unroll
            for (int r = 0; r < 4; ++r) {
                kmx[r] = fmaxf(kmx[r], __shfl_xor(kmx[r], off));
                kmn[r] = fminf(kmn[r], __shfl_xor(kmn[r], off));
            }
        }
        if ((tid & 63) == 0) {
            #pragma unroll
            for (int r = 0; r < 4; ++r) { S.skmax[wid][r] = kmx[r]; S.skmin[wid][r] = kmn[r]; }
        }
    }
    __syncthreads();

    // ---- C: softmax fwd (+ dQ sums folded), log2 domain, packed accums ----
    float mi2[4], rl[4], ti[4], sk[4], skv[4];
    {
        f32x2 st[4], lv[4];   // st = {sk, tn}; lv = {l, skv}
        #pragma unroll
        for (int r = 0; r < 4; ++r) {
            const float kx = fmaxf(S.skmax[2 * tg][r], S.skmax[2 * tg + 1][r]);
            const float kn = fminf(S.skmin[2 * tg][r], S.skmin[2 * tg + 1][r]);
            mi2[r] = fmaxf(Qe[r] * kx, Qe[r] * kn);
            st[r] = (f32x2){0.f, 0.f}; lv[r] = (f32x2){0.f, 0.f};
        }
        #pragma unroll 2
        for (int j = 0; j < NDIM; ++j) {
            #pragma unroll
            for (int r = 0; r < 4; ++r) {
                const float4 kv4 = S.sKVQ[r0 + r][j];
                const f32x2* kvp = (const f32x2*)&kv4;
                const float e = fexp2(fmaf(Qe[r], kv4.x, -mi2[r]));
                const f32x2 e2 = {e, e};
                st[r] = pkfma(e2, kvp[0], st[r]);
                lv[r] = pkfma(e2, kvp[1], lv[r]);
            }
        }
        #pragma unroll
        for (int r = 0; r < 4; ++r) {
            sk[r] = st[r].x; skv[r] = lv[r].y;
            rl[r] = frcp(lv[r].x);
            ti[r] = st[r].y * rl[r];
            S.sz[r0 + r][tl] = siluf(ti[r]);
        }
    }
    __syncthreads();

    // ---- y = silu(z @ Wout + bout), 8x25 tasks ----
    if (tid < 200) {
        const int r = tid / 25, o = tid - 25 * (tid / 25);
        float a = bout[o];
        #pragma unroll 8
        for (int c = 0; c < NDIM / 4; ++c) {
            const float4 z4 = *(const float4*)&S.sz[r][4 * c];
            a = fmaf(z4.x, Wout[(4 * c + 0) * 25 + o], a);
            a = fmaf(z4.y, Wout[(4 * c + 1) * 25 + o], a);
            a = fmaf(z4.z, Wout[(4 * c + 2) * 25 + o], a);
            a = fmaf(z4.w, Wout[(4 * c + 3) * 25 + o], a);
        }
        S.swp[r][o] = a;
        S.sy[r][o] = siluf(a);
    }
    __syncthreads();

    // ---- backward through the quadratic head ----
    if (tid < 200) {
        const int r = tid / 25, o = tid - 25 * (tid / 25);
        float m11 = 0.f, m12 = 0.f, m21 = 0.f, m22 = 0.f;
        for (int k = 0;  k < 5;  ++k) m11 += S.sy[r][k] * S.sy[r][k];
        for (int k = 5;  k < 10; ++k) m12 += S.sy[r][k] * S.sy[r][k];
        for (int k = 10; k < 15; ++k) m21 += S.sy[r][k] * S.sy[r][k];
        for (int k = 15; k < 20; ++k) m22 += S.sy[r][k] * S.sy[r][k];
        const float q0 = S.sy[r][0], q1 = S.sy[r][1], q2 = S.sy[r][2], q3 = S.sy[r][3];
        const float dm11 = q0 * q0 + q1 * q1;
        const float dm12 = q0 * q2 + q1 * q3;
        const float dm22 = q2 * q2 + q3 * q3;
        float dy;
        if      (o < 5)  dy = 2.0f * S.sy[r][o] * dm11;
        else if (o < 15) dy = 2.0f * S.sy[r][o] * dm12;
        else if (o < 20) dy = 2.0f * S.sy[r][o] * dm22;
        else             dy = 2.0f * S.sy[r][o];
        const float ms = m12 + m21;
        if (o == 0) dy += 2.0f * m11 * q0 + ms * q2;
        if (o == 1) dy += 2.0f * m11 * q1 + ms * q3;
        if (o == 2) dy += ms * q0 + 2.0f * m22 * q2;
        if (o == 3) dy += ms * q1 + 2.0f * m22 * q3;
        S.sdwp[r][o] = dy * dsiluf(S.swp[r][o]);
    }
    __syncthreads();

    // ---- E: dt, closed-form dQ, coefficient pack into sC (2^-m folded) ----
    float dQp_[4];
    {
        float wr[25];
        #pragma unroll
        for (int k = 0; k < 25; ++k) wr[k] = Wout[tl * 25 + k];
        float dt[4] = {0.f, 0.f, 0.f, 0.f};
        #pragma unroll
        for (int k = 0; k < 25; ++k) {
            #pragma unroll
            for (int r = 0; r < 4; ++r)
                dt[r] = fmaf(wr[k], S.sdwp[r0 + r][k], dt[r]);
        }
        #pragma unroll
        for (int r = 0; r < 4; ++r) {
            dt[r] *= dsiluf(ti[r]);
            const float w = dt[r] * rl[r];
            dQp_[r] = (w * fmaf(-ti[r], sk[r], skv[r])) * dsiluf(Qp[r]);
            const float wt = w * fexp2(-mi2[r]);
            const float c1 = wt * Qv[r];
            S.sC[r0 + r][tl] = make_float4(wt, c1, c1 * ti[r], Qe[r]);
        }
    }
    __syncthreads();

    // ---- F: dK_j / dV_j -> sD; packed {accv,k1} pair ----
    {
        f32x2 vk[4];
        float k2s[4];
        #pragma unroll
        for (int r = 0; r < 4; ++r) { vk[r] = (f32x2){0.f, 0.f}; k2s[r] = 0.f; }
        #pragma unroll 2
        for (int i = 0; i < NDIM; ++i) {
            #pragma unroll
            for (int r = 0; r < 4; ++r) {
                const float4 c4 = S.sC[r0 + r][i];
                const f32x2* cp = (const f32x2*)&c4;
                const float e = fexp2(c4.w * Kv[r]);
                const f32x2 e2 = {e, e};
                vk[r] = pkfma(e2, cp[0], vk[r]);
                k2s[r] = fmaf(e, c4.z, k2s[r]);
            }
        }
        #pragma unroll
        for (int r = 0; r < 4; ++r) {
            const float dVp_ = vk[r].x * dsiluf(Vp[r]);
            const float dKp_ = fmaf(Vv[r], vk[r].y, -k2s[r]) * dsiluf(Kp[r]);
            S.sD[r0 + r][tl] = make_float4(dQp_[r], dKp_, dVp_, 0.f);
        }
    }
    __syncthreads();

    // ---- G: dh_d = sum_i Aq[i][d]dQp + Ak[i][d]dKp + Av[i][d]dVp ----
    float dhp[4];
    {
        float acc[4] = {0.f, 0.f, 0.f, 0.f};
        #pragma unroll 4
        for (int i = 0; i < NDIM; ++i) {
            const float aqv = Aq[i * NDIM + tl];
            const float akv = Ak[i * NDIM + tl];
            const float avv = Av[i * NDIM + tl];
            #pragma unroll
            for (int r = 0; r < 4; ++r) {
                const float4 d4 = S.sD[r0 + r][i];
                acc[r] = fmaf(aqv, d4.x, acc[r]);
                acc[r] = fmaf(akv, d4.y, acc[r]);
                acc[r] = fmaf(avv, d4.z, acc[r]);
            }
        }
        #pragma unroll
        for (int r = 0; r < 4; ++r) dhp[r] = acc[r] * dsiluf(hp[r]);
    }

    // ---- dx_o (o=0,1): shuffle reduce per row, cross-wave combine ----
    {
        const float w0 = Win[tl], w1 = Win[NDIM + tl];
        float t0[4], t1[4];
        #pragma unroll
        for (int r = 0; r < 4; ++r) { t0[r] = w0 * dhp[r]; t1[r] = w1 * dhp[r]; }
        #pragma unroll
        for (int off = 32; off; off >>= 1) {
            #pragma unroll
            for (int r = 0; r < 4; ++r) {
                t0[r] += __shfl_xor(t0[r], off);
                t1[r] += __shfl_xor(t1[r], off);
            }
        }
        if ((tid & 63) == 0) {
            #pragma unroll
            for (int r = 0; r < 4; ++r) { S.sred[wid][r][0] = t0[r]; S.sred[wid][r][1] = t1[r]; }
        }
    }
    __syncthreads();
    if (tid < 16) {
        const int o = tid >> 3, ag = tid & 7;
        const int gg = ag >> 2, rr = ag & 3;
        sdHf[o * 8 + ag] = S.sred[2 * gg][rr][o] + S.sred[2 * gg + 1][rr][o];
    }
    // caller issues the inter-phase __syncthreads()
}

// ---------------------------------------------------------------------------
// Phase 2: J + R forwards + assembly. Round-9 proven body; x already resident
// in S.sx (aliases H-phase image); dHdz read from sdHf (LDS).
// ---------------------------------------------------------------------------
__device__ __forceinline__ void jr_path(
    int b, int tid, JRS& S,
    const float* __restrict__ JWin, const float* __restrict__ Jbin,
    const float* __restrict__ JAq, const float* __restrict__ JAk, const float* __restrict__ JAv,
    const float* __restrict__ JBq, const float* __restrict__ JBk, const float* __restrict__ JBv,
    const float* __restrict__ JWout, const float* __restrict__ Jbout,
    const float* __restrict__ RWin, const float* __restrict__ Rbin,
    const float* __restrict__ RAq, const float* __restrict__ RAk, const float* __restrict__ RAv,
    const float* __restrict__ RBq, const float* __restrict__ RBk, const float* __restrict__ RBv,
    const float* __restrict__ RWout, const float* __restrict__ Rbout,
    const float* sdHf, double* sdH, double* sg, double (*sRm)[17],
    double* srs, double* svv, float* sJvp,
    float* __restrict__ out)
{
    const int g  = tid >> 7;
    const int tl = tid & 127;
    const int wg = (tid >> 6) & 1;

    if (tid < 16) sdH[tid] = (double)sdHf[tid];   // consumed much later

    const float* Win  = g ? RWin  : JWin;
    const float* bin_ = g ? Rbin  : Jbin;
    const float* Aq   = g ? RAq   : JAq;
    const float* Ak   = g ? RAk   : JAk;
    const float* Av   = g ? RAv   : JAv;
    const float* Bq   = g ? RBq   : JBq;
    const float* Bk   = g ? RBk   : JBk;
    const float* Bv   = g ? RBv   : JBv;

    // ---- A: h[a][tl] for all 8 agents (x already in S.sx) ----
    {
        float acc[8];
        const float b0 = bin_[tl];
        #pragma unroll
        for (int a = 0; a < 8; ++a) acc[a] = b0;
        #pragma unroll
        for (int c = 0; c < 4; ++c) {
            const float w0 = Win[(4 * c + 0) * NDIM + tl];
            const float w1 = Win[(4 * c + 1) * NDIM + tl];
            const float w2 = Win[(4 * c + 2) * NDIM + tl];
            const float w3 = Win[(4 * c + 3) * NDIM + tl];
            #pragma unroll
            for (int a = 0; a < 8; ++a) {
                const float4 x4 = *(const float4*)&S.sx[a * 16 + 4 * c];
                acc[a] = fmaf(w0, x4.x, acc[a]);
                acc[a] = fmaf(w1, x4.y, acc[a]);
                acc[a] = fmaf(w2, x4.z, acc[a]);
                acc[a] = fmaf(w3, x4.w, acc[a]);
            }
        }
        *(float4*)&S.sh[g][tl][0] =
            make_float4(siluf(acc[0]), siluf(acc[1]), siluf(acc[2]), siluf(acc[3]));
        *(float4*)&S.sh[g][tl][4] =
            make_float4(siluf(acc[4]), siluf(acc[5]), siluf(acc[6]), siluf(acc[7]));
    }
    __syncthreads();

    // ---- B: Q,K,V for all 8 agents; packed agent-pairs, broadcast weight ----
    f32x2 qe2[4];
    {
        f32x2 aq2[4], ak2[4], av2[4];
        const float bq = Bq[tl], bk = Bk[tl], bv = Bv[tl];
        #pragma unroll
        for (int p = 0; p < 4; ++p) {
            aq2[p] = (f32x2){bq, bq}; ak2[p] = (f32x2){bk, bk}; av2[p] = (f32x2){bv, bv};
        }
        const float4* Aq4 = (const float4*)(Aq + tl * NDIM);
        const float4* Ak4 = (const float4*)(Ak + tl * NDIM);
        const float4* Av4 = (const float4*)(Av + tl * NDIM);
        for (int c = 0; c < NDIM / 4; ++c) {
            const float4 wq = Aq4[c], wk = Ak4[c], wv = Av4[c];
            const float wqa[4] = {wq.x, wq.y, wq.z, wq.w};
            const float wka[4] = {wk.x, wk.y, wk.z, wk.w};
            const float wva[4] = {wv.x, wv.y, wv.z, wv.w};
            #pragma unroll
            for (int jj = 0; jj < 4; ++jj) {
                const float4 h0 = *(const float4*)&S.sh[g][4 * c + jj][0];
                const float4 h1 = *(const float4*)&S.sh[g][4 * c + jj][4];
                const f32x2* h0p = (const f32x2*)&h0;
                const f32x2* h1p = (const f32x2*)&h1;
                const f32x2 qq = {wqa[jj], wqa[jj]};
                const f32x2 kk2 = {wka[jj], wka[jj]};
                const f32x2 vv2 = {wva[jj], wva[jj]};
                aq2[0] = pkfma(qq, h0p[0], aq2[0]); aq2[1] = pkfma(qq, h0p[1], aq2[1]);
                aq2[2] = pkfma(qq, h1p[0], aq2[2]); aq2[3] = pkfma(qq, h1p[1], aq2[3]);
                ak2[0] = pkfma(kk2, h0p[0], ak2[0]); ak2[1] = pkfma(kk2, h0p[1], ak2[1]);
                ak2[2] = pkfma(kk2, h1p[0], ak2[2]); ak2[3] = pkfma(kk2, h1p[1], ak2[3]);
                av2[0] = pkfma(vv2, h0p[0], av2[0]); av2[1] = pkfma(vv2, h0p[1], av2[1]);
                av2[2] = pkfma(vv2, h1p[0], av2[2]); av2[3] = pkfma(vv2, h1p[1], av2[3]);
            }
        }
        float kk[8], kx[8], kn[8];
        #pragma unroll
        for (int s = 0; s < 8; ++s) {
            const int p = s >> 1, e = s & 1;
            qe2[p][e] = siluf(aq2[p][e]) * LOG2E;
            kk[s] = siluf(ak2[p][e]);
            S.sK[g][tl][s] = kk[s];
            S.sV[g][tl][s] = siluf(av2[p][e]);
            kx[s] = kk[s]; kn[s] = kk[s];
        }
        #pragma unroll
        for (int off = 32; off; off >>= 1) {
            #pragma unroll
            for (int s = 0; s < 8; ++s) {
                kx[s] = fmaxf(kx[s], __shfl_xor(kx[s], off));
                kn[s] = fminf(kn[s], __shfl_xor(kn[s], off));
            }
        }
        if ((tid & 63) == 0) {
            #pragma unroll
            for (int s = 0; s < 8; ++s) { S.skr[g][wg][0][s] = kx[s]; S.skr[g][wg][1][s] = kn[s]; }
        }
    }
    __syncthreads();

    // ---- C: attention row tl, single pass, global-bound shift; packed ----
    {
        float bnd2 = 0.f;
        #pragma unroll
        for (int s = 0; s < 8; ++s) {
            const float kx = fmaxf(S.skr[g][0][0][s], S.skr[g][1][0][s]);
            const float kn = fminf(S.skr[g][0][1][s], S.skr[g][1][1][s]);
            const float q = qe2[s >> 1][s & 1];
            bnd2 += fmaxf(q * kx, q * kn);
        }
        float l = 0.f;
        f32x2 t2[4];
        #pragma unroll
        for (int p = 0; p < 4; ++p) t2[p] = (f32x2){0.f, 0.f};
        #pragma unroll 2
        for (int j = 0; j < NDIM; ++j) {
            const float4 k0 = *(const float4*)&S.sK[g][j][0];
            const float4 k1 = *(const float4*)&S.sK[g][j][4];
            const f32x2* k0p = (const f32x2*)&k0;
            const f32x2* k1p = (const f32x2*)&k1;
            f32x2 d2 = {-bnd2, 0.f};
            d2 = pkfma(qe2[0], k0p[0], d2);
            d2 = pkfma(qe2[1], k0p[1], d2);
            d2 = pkfma(qe2[2], k1p[0], d2);
            d2 = pkfma(qe2[3], k1p[1], d2);
            const float e = fexp2(d2.x + d2.y);
            const float4 v0 = *(const float4*)&S.sV[g][j][0];
            const float4 v1 = *(const float4*)&S.sV[g][j][4];
            const f32x2* v0p = (const f32x2*)&v0;
            const f32x2* v1p = (const f32x2*)&v1;
            const f32x2 e2 = {e, e};
            l += e;
            t2[0] = pkfma(e2, v0p[0], t2[0]);
            t2[1] = pkfma(e2, v0p[1], t2[1]);
            t2[2] = pkfma(e2, v1p[0], t2[2]);
            t2[3] = pkfma(e2, v1p[1], t2[3]);
        }
        const float rl = frcp(l);
        #pragma unroll
        for (int s = 0; s < 8; ++s)
            S.sz[g][s][tl] = siluf(t2[s >> 1][s & 1] * rl);
    }
    __syncthreads();

    // ---- D: w[s,o] = silu(z @ Wout + bout). R on tids 0-127, J on 128-191 ----
    if (tid < 192) {
        const int gm = (tid < 128) ? 1 : 0;
        const int t2 = (tid < 128) ? tid : tid - 128;
        const int lo2 = gm ? 4 : 3;
        const int outd = 1 << lo2;
        const int s = t2 >> lo2, o = t2 & (outd - 1);
        const float* Wo = gm ? RWout : JWout;
        const float* bo = gm ? Rbout : Jbout;
        float a = bo[o];
        #pragma unroll 8
        for (int c = 0; c < NDIM / 4; ++c) {
            const float4 z4 = *(const float4*)&S.sz[gm][s][4 * c];
            a = fmaf(z4.x, Wo[(4 * c + 0) * outd + o], a);
            a = fmaf(z4.y, Wo[(4 * c + 1) * outd + o], a);
            a = fmaf(z4.z, Wo[(4 * c + 2) * outd + o], a);
            a = fmaf(z4.w, Wo[(4 * c + 3) * outd + o], a);
        }
        S.sw[gm][t2] = siluf(a);
    }
    __syncthreads();

    // ---- J scalar + R group sums ----
    if (tid < 64) {
        float v = S.sw[0][tid];
        #pragma unroll
        for (int off = 32; off; off >>= 1) v += __shfl_xor(v, off);
        if (tid == 0) *sJvp = v;
    } else if (tid < 96) {
        const int t = tid - 64, pq = t >> 3, c = t & 7;
        const int base = c * 16 + pq * 4;
        sg[t] = (double)S.sw[1][base] + (double)S.sw[1][base + 1]
              + (double)S.sw[1][base + 2] + (double)S.sw[1][base + 3];
    }
    __syncthreads();

    // ---- assembly: Rupper, Laplacian Rm, u = (J_eff - Rm Rm^T) dH ----
    const int ii = (tid >> 4) & 15, jj = tid & 15;
    {
        const double rij = sg[((ii >> 3) * 2 + (jj >> 3)) * 8 + (jj & 7)];
        const double rji = sg[((jj >> 3) * 2 + (ii >> 3)) * 8 + (ii & 7)];
        sRm[ii][jj] = rij * rij + rji * rji;
    }
    __syncthreads();

    if (tid < 16) {
        double a = 0.0;
        for (int j = 0; j < 16; ++j) a += sRm[tid][j];
        srs[tid] = a;
    }
    __syncthreads();

    {
        const double v = (ii == jj) ? srs[ii] : -sRm[ii][jj];
        __syncthreads();
        sRm[ii][jj] = v;
    }
    __syncthreads();

    if (tid < 16) {
        double a = 0.0;
        for (int j = 0; j < 16; ++j) a += sRm[tid][j] * sdH[j];
        svv[tid] = a;
    }
    __syncthreads();

    if (tid < 16) {
        double a = 0.0;
        for (int k = 0; k < 16; ++k) a += sRm[tid][k] * svv[k];
        const double sj = (double)(*sJvp);
        const double jterm = (tid < 8) ? 2.0 * sj * sdH[8 + tid]
                                       : -2.0 * sj * sdH[tid - 8];
        out[b * 16 + tid] = (float)(jterm - a);
    }
}

// ---------------------------------------------------------------------------
// One kernel, one block per batch: H phase -> LDS handoff -> JR phase.
// ---------------------------------------------------------------------------
__global__ __launch_bounds__(256) void k_all(
    const float* __restrict__ x,
    const float* __restrict__ HWin, const float* __restrict__ Hbin,
    const float* __restrict__ HAq, const float* __restrict__ HAk, const float* __restrict__ HAv,
    const float* __restrict__ HBq, const float* __restrict__ HBk, const float* __restrict__ HBv,
    const float* __restrict__ HWout, const float* __restrict__ Hbout,
    const float* __restrict__ JWin, const float* __restrict__ Jbin,
    const float* __restrict__ JAq, const float* __restrict__ JAk, const float* __restrict__ JAv,
    const float* __restrict__ JBq, const float* __restrict__ JBk, const float* __restrict__ JBv,
    const float* __restrict__ JWout, const float* __restrict__ Jbout,
    const float* __restrict__ RWin, const float* __restrict__ Rbin,
    const float* __restrict__ RAq, const float* __restrict__ RAk, const float* __restrict__ RAv,
    const float* __restrict__ RBq, const float* __restrict__ RBk, const float* __restrict__ RBv,
    const float* __restrict__ RWout, const float* __restrict__ Rbout,
    float* __restrict__ out)
{
    __shared__ SU S;
    __shared__ float  sdHf[16];
    __shared__ float  sJv;
    __shared__ double sdH[16], sg[32], sRm[16][17], srs[16], svv[16];

    const int b = blockIdx.x;

    h_path(b, threadIdx.x, S.h, x, HWin, Hbin, HAq, HAk, HAv,
           HBq, HBk, HBv, HWout, Hbout, sdHf);
    __syncthreads();   // inter-phase: sdHf visible; HS buffers dead

    jr_path(b, threadIdx.x, S.jr,
            JWin, Jbin, JAq, JAk, JAv, JBq, JBk, JBv, JWout, Jbout,
            RWin, Rbin, RAq, RAk, RAv, RBq, RBk, RBv, RWout, Rbout,
            sdHf, sdH, sg, sRm, srs, svv, &sJv, out);
}

// ---------------------------------------------------------------------------
extern "C" void kernel_launch(void* const* d_in, const int* in_sizes, int n_in,
                              void* d_out, int out_size, void* d_ws, size_t ws_size,
                              hipStream_t stream)
{
    const float* x = (const float*)d_in[0];
    float* out = (float*)d_out;

#define ARGS10(base) \
    (const float*)d_in[(base) + 0], (const float*)d_in[(base) + 1], \
    (const float*)d_in[(base) + 2], (const float*)d_in[(base) + 3], \
    (const float*)d_in[(base) + 4], (const float*)d_in[(base) + 5], \
    (const float*)d_in[(base) + 6], (const float*)d_in[(base) + 7], \
    (const float*)d_in[(base) + 8], (const float*)d_in[(base) + 9]

    k_all<<<dim3(512), dim3(256), 0, stream>>>(
        x, ARGS10(1), ARGS10(11), ARGS10(21), out);
#undef ARGS10
}

// Round 11
// 111.202 us; speedup vs baseline: 1.5021x; 1.1998x over previous
//
#include <hip/hip_runtime.h>

#define NDIM 128
#define NOBS 16
#define LOG2E 1.44269504088896341f

typedef float f32x2 __attribute__((ext_vector_type(2)));

__device__ __forceinline__ float frcp(float x) { return __builtin_amdgcn_rcpf(x); }
__device__ __forceinline__ float fexp2(float x) { return __builtin_amdgcn_exp2f(x); }
__device__ __forceinline__ float fexp(float x) { return __builtin_amdgcn_exp2f(x * LOG2E); }
__device__ __forceinline__ float sigf(float v) { return frcp(1.0f + fexp(-v)); }
__device__ __forceinline__ float siluf(float v) { return v * sigf(v); }
__device__ __forceinline__ float dsiluf(float v) {
    float s = sigf(v);
    return s * (1.0f + v * (1.0f - s));
}
__device__ __forceinline__ f32x2 pkfma(f32x2 a, f32x2 b, f32x2 c) {
    return __builtin_elementwise_fma(a, b, c);
}

// ---- LDS layouts: both phases union into one 60.6 KB block ----------------
// Both structs BEGIN with the identical 512-byte x image, so x loaded in the
// H phase persists into the JR phase (no H-phase field aliases offset 0-511).
struct HS {
    float  sx[8][NOBS];
    float  sh[8][NDIM];
    float4 sKVQ[8][NDIM];   // {K, V, 1.0, K*V}
    float  sz[8][NDIM];
    float4 sC[8][NDIM];     // {wt, wt*Q, wt*Q*t, Qe}
    float4 sD[8][NDIM];     // {dQp, dKp, dVp, 0}
    float  sy[8][26], swp[8][26], sdwp[8][26];
    float  skmax[4][4], skmin[4][4];
    float  sred[4][4][2];
};
struct JRS {
    float sx[128];          // aliases HS::sx — same linear layout
    float sh[2][NDIM][8];
    float sK[2][NDIM][8];
    float sV[2][NDIM][8];
    float sz[2][8][132];
    float sw[2][NDIM];
    float skr[2][2][2][8];
};
union SU { HS h; JRS jr; };

// ---------------------------------------------------------------------------
// Phase 1: H-module gradient for one batch (8 rows). Round-10 body with
// deeper unrolls (B/C/F: 4, G: 8) for more outstanding loads per wave.
// ---------------------------------------------------------------------------
__device__ __forceinline__ void h_path(
    int b, int tid, HS& S,
    const float* __restrict__ x,
    const float* __restrict__ Win, const float* __restrict__ bin,
    const float* __restrict__ Aq, const float* __restrict__ Ak, const float* __restrict__ Av,
    const float* __restrict__ Bq, const float* __restrict__ Bk, const float* __restrict__ Bv,
    const float* __restrict__ Wout, const float* __restrict__ bout,
    float* sdHf)
{
    const int tl = tid & 127, tg = tid >> 7, wid = tid >> 6, r0 = tg * 4;

    if (tid < 128) S.sx[tid >> 4][tid & 15] = x[b * 128 + tid];
    __syncthreads();

    // ---- A: h = silu(x @ Win + bin) ----
    float hp[4];
    {
        float acc[4];
        const float b0 = bin[tl];
        #pragma unroll
        for (int r = 0; r < 4; ++r) acc[r] = b0;
        #pragma unroll
        for (int o = 0; o < NOBS; ++o) {
            const float w = Win[o * NDIM + tl];
            #pragma unroll
            for (int r = 0; r < 4; ++r) acc[r] = fmaf(w, S.sx[r0 + r][o], acc[r]);
        }
        #pragma unroll
        for (int r = 0; r < 4; ++r) { hp[r] = acc[r]; S.sh[r0 + r][tl] = siluf(acc[r]); }
    }
    __syncthreads();

    // ---- B: Q,K,V = silu(A h + B); packed pairs; unroll 4 ----
    float Qp[4], Kp[4], Vp[4], Qv[4], Kv[4], Vv[4], Qe[4];
    {
        f32x2 aq2[4], ak2[4], av2[4];
        const float bq = Bq[tl], bk = Bk[tl], bv = Bv[tl];
        #pragma unroll
        for (int r = 0; r < 4; ++r) {
            aq2[r] = (f32x2){bq, 0.f}; ak2[r] = (f32x2){bk, 0.f}; av2[r] = (f32x2){bv, 0.f};
        }
        const float4* Aq4 = (const float4*)(Aq + tl * NDIM);
        const float4* Ak4 = (const float4*)(Ak + tl * NDIM);
        const float4* Av4 = (const float4*)(Av + tl * NDIM);
        #pragma unroll 4
        for (int c = 0; c < NDIM / 4; ++c) {
            const float4 wq = Aq4[c], wk = Ak4[c], wv = Av4[c];
            const f32x2* wqp = (const f32x2*)&wq;
            const f32x2* wkp = (const f32x2*)&wk;
            const f32x2* wvp = (const f32x2*)&wv;
            #pragma unroll
            for (int r = 0; r < 4; ++r) {
                const float4 h4 = *(const float4*)&S.sh[r0 + r][4 * c];
                const f32x2* hp2 = (const f32x2*)&h4;
                aq2[r] = pkfma(wqp[0], hp2[0], aq2[r]);
                aq2[r] = pkfma(wqp[1], hp2[1], aq2[r]);
                ak2[r] = pkfma(wkp[0], hp2[0], ak2[r]);
                ak2[r] = pkfma(wkp[1], hp2[1], ak2[r]);
                av2[r] = pkfma(wvp[0], hp2[0], av2[r]);
                av2[r] = pkfma(wvp[1], hp2[1], av2[r]);
            }
        }
        float kmx[4], kmn[4];
        #pragma unroll
        for (int r = 0; r < 4; ++r) {
            Qp[r] = aq2[r].x + aq2[r].y;
            Kp[r] = ak2[r].x + ak2[r].y;
            Vp[r] = av2[r].x + av2[r].y;
            Qv[r] = siluf(Qp[r]); Kv[r] = siluf(Kp[r]); Vv[r] = siluf(Vp[r]);
            Qe[r] = Qv[r] * LOG2E;
            S.sKVQ[r0 + r][tl] = make_float4(Kv[r], Vv[r], 1.0f, Kv[r] * Vv[r]);
            kmx[r] = Kv[r]; kmn[r] = Kv[r];
        }
        #pragma unroll
        for (int off = 32; off; off >>= 1) {
            #pragma unroll
            for (int r = 0; r < 4; ++r) {
                kmx[r] = fmaxf(kmx[r], __shfl_xor(kmx[r], off));
                kmn[r] = fminf(kmn[r], __shfl_xor(kmn[r], off));
            }
        }
        if ((tid & 63) == 0) {
            #pragma unroll
            for (int r = 0; r < 4; ++r) { S.skmax[wid][r] = kmx[r]; S.skmin[wid][r] = kmn[r]; }
        }
    }
    __syncthreads();

    // ---- C: softmax fwd (+ dQ sums folded), log2 domain; unroll 4 ----
    float mi2[4], rl[4], ti[4], sk[4], skv[4];
    {
        f32x2 st[4], lv[4];   // st = {sk, tn}; lv = {l, skv}
        #pragma unroll
        for (int r = 0; r < 4; ++r) {
            const float kx = fmaxf(S.skmax[2 * tg][r], S.skmax[2 * tg + 1][r]);
            const float kn = fminf(S.skmin[2 * tg][r], S.skmin[2 * tg + 1][r]);
            mi2[r] = fmaxf(Qe[r] * kx, Qe[r] * kn);
            st[r] = (f32x2){0.f, 0.f}; lv[r] = (f32x2){0.f, 0.f};
        }
        #pragma unroll 4
        for (int j = 0; j < NDIM; ++j) {
            #pragma unroll
            for (int r = 0; r < 4; ++r) {
                const float4 kv4 = S.sKVQ[r0 + r][j];
                const f32x2* kvp = (const f32x2*)&kv4;
                const float e = fexp2(fmaf(Qe[r], kv4.x, -mi2[r]));
                const f32x2 e2 = {e, e};
                st[r] = pkfma(e2, kvp[0], st[r]);
                lv[r] = pkfma(e2, kvp[1], lv[r]);
            }
        }
        #pragma unroll
        for (int r = 0; r < 4; ++r) {
            sk[r] = st[r].x; skv[r] = lv[r].y;
            rl[r] = frcp(lv[r].x);
            ti[r] = st[r].y * rl[r];
            S.sz[r0 + r][tl] = siluf(ti[r]);
        }
    }
    __syncthreads();

    // ---- y = silu(z @ Wout + bout), 8x25 tasks ----
    if (tid < 200) {
        const int r = tid / 25, o = tid - 25 * (tid / 25);
        float a = bout[o];
        #pragma unroll 8
        for (int c = 0; c < NDIM / 4; ++c) {
            const float4 z4 = *(const float4*)&S.sz[r][4 * c];
            a = fmaf(z4.x, Wout[(4 * c + 0) * 25 + o], a);
            a = fmaf(z4.y, Wout[(4 * c + 1) * 25 + o], a);
            a = fmaf(z4.z, Wout[(4 * c + 2) * 25 + o], a);
            a = fmaf(z4.w, Wout[(4 * c + 3) * 25 + o], a);
        }
        S.swp[r][o] = a;
        S.sy[r][o] = siluf(a);
    }
    __syncthreads();

    // ---- backward through the quadratic head ----
    if (tid < 200) {
        const int r = tid / 25, o = tid - 25 * (tid / 25);
        float m11 = 0.f, m12 = 0.f, m21 = 0.f, m22 = 0.f;
        for (int k = 0;  k < 5;  ++k) m11 += S.sy[r][k] * S.sy[r][k];
        for (int k = 5;  k < 10; ++k) m12 += S.sy[r][k] * S.sy[r][k];
        for (int k = 10; k < 15; ++k) m21 += S.sy[r][k] * S.sy[r][k];
        for (int k = 15; k < 20; ++k) m22 += S.sy[r][k] * S.sy[r][k];
        const float q0 = S.sy[r][0], q1 = S.sy[r][1], q2 = S.sy[r][2], q3 = S.sy[r][3];
        const float dm11 = q0 * q0 + q1 * q1;
        const float dm12 = q0 * q2 + q1 * q3;
        const float dm22 = q2 * q2 + q3 * q3;
        float dy;
        if      (o < 5)  dy = 2.0f * S.sy[r][o] * dm11;
        else if (o < 15) dy = 2.0f * S.sy[r][o] * dm12;
        else if (o < 20) dy = 2.0f * S.sy[r][o] * dm22;
        else             dy = 2.0f * S.sy[r][o];
        const float ms = m12 + m21;
        if (o == 0) dy += 2.0f * m11 * q0 + ms * q2;
        if (o == 1) dy += 2.0f * m11 * q1 + ms * q3;
        if (o == 2) dy += ms * q0 + 2.0f * m22 * q2;
        if (o == 3) dy += ms * q1 + 2.0f * m22 * q3;
        S.sdwp[r][o] = dy * dsiluf(S.swp[r][o]);
    }
    __syncthreads();

    // ---- E: dt, closed-form dQ, coefficient pack into sC (2^-m folded) ----
    float dQp_[4];
    {
        float wr[25];
        #pragma unroll
        for (int k = 0; k < 25; ++k) wr[k] = Wout[tl * 25 + k];
        float dt[4] = {0.f, 0.f, 0.f, 0.f};
        #pragma unroll
        for (int k = 0; k < 25; ++k) {
            #pragma unroll
            for (int r = 0; r < 4; ++r)
                dt[r] = fmaf(wr[k], S.sdwp[r0 + r][k], dt[r]);
        }
        #pragma unroll
        for (int r = 0; r < 4; ++r) {
            dt[r] *= dsiluf(ti[r]);
            const float w = dt[r] * rl[r];
            dQp_[r] = (w * fmaf(-ti[r], sk[r], skv[r])) * dsiluf(Qp[r]);
            const float wt = w * fexp2(-mi2[r]);
            const float c1 = wt * Qv[r];
            S.sC[r0 + r][tl] = make_float4(wt, c1, c1 * ti[r], Qe[r]);
        }
    }
    __syncthreads();

    // ---- F: dK_j / dV_j -> sD; packed {accv,k1} pair; unroll 4 ----
    {
        f32x2 vk[4];
        float k2s[4];
        #pragma unroll
        for (int r = 0; r < 4; ++r) { vk[r] = (f32x2){0.f, 0.f}; k2s[r] = 0.f; }
        #pragma unroll 4
        for (int i = 0; i < NDIM; ++i) {
            #pragma unroll
            for (int r = 0; r < 4; ++r) {
                const float4 c4 = S.sC[r0 + r][i];
                const f32x2* cp = (const f32x2*)&c4;
                const float e = fexp2(c4.w * Kv[r]);
                const f32x2 e2 = {e, e};
                vk[r] = pkfma(e2, cp[0], vk[r]);
                k2s[r] = fmaf(e, c4.z, k2s[r]);
            }
        }
        #pragma unroll
        for (int r = 0; r < 4; ++r) {
            const float dVp_ = vk[r].x * dsiluf(Vp[r]);
            const float dKp_ = fmaf(Vv[r], vk[r].y, -k2s[r]) * dsiluf(Kp[r]);
            S.sD[r0 + r][tl] = make_float4(dQp_[r], dKp_, dVp_, 0.f);
        }
    }
    __syncthreads();

    // ---- G: dh_d = sum_i Aq[i][d]dQp + Ak[i][d]dKp + Av[i][d]dVp; unroll 8 ----
    float dhp[4];
    {
        float acc[4] = {0.f, 0.f, 0.f, 0.f};
        #pragma unroll 8
        for (int i = 0; i < NDIM; ++i) {
            const float aqv = Aq[i * NDIM + tl];
            const float akv = Ak[i * NDIM + tl];
            const float avv = Av[i * NDIM + tl];
            #pragma unroll
            for (int r = 0; r < 4; ++r) {
                const float4 d4 = S.sD[r0 + r][i];
                acc[r] = fmaf(aqv, d4.x, acc[r]);
                acc[r] = fmaf(akv, d4.y, acc[r]);
                acc[r] = fmaf(avv, d4.z, acc[r]);
            }
        }
        #pragma unroll
        for (int r = 0; r < 4; ++r) dhp[r] = acc[r] * dsiluf(hp[r]);
    }

    // ---- dx_o (o=0,1): shuffle reduce per row, cross-wave combine ----
    {
        const float w0 = Win[tl], w1 = Win[NDIM + tl];
        float t0[4], t1[4];
        #pragma unroll
        for (int r = 0; r < 4; ++r) { t0[r] = w0 * dhp[r]; t1[r] = w1 * dhp[r]; }
        #pragma unroll
        for (int off = 32; off; off >>= 1) {
            #pragma unroll
            for (int r = 0; r < 4; ++r) {
                t0[r] += __shfl_xor(t0[r], off);
                t1[r] += __shfl_xor(t1[r], off);
            }
        }
        if ((tid & 63) == 0) {
            #pragma unroll
            for (int r = 0; r < 4; ++r) { S.sred[wid][r][0] = t0[r]; S.sred[wid][r][1] = t1[r]; }
        }
    }
    __syncthreads();
    if (tid < 16) {
        const int o = tid >> 3, ag = tid & 7;
        const int gg = ag >> 2, rr = ag & 3;
        sdHf[o * 8 + ag] = S.sred[2 * gg][rr][o] + S.sred[2 * gg + 1][rr][o];
    }
    // caller issues the inter-phase __syncthreads()
}

// ---------------------------------------------------------------------------
// Phase 2: J + R forwards + assembly. Round-10 body; JR-B unroll 2, JR-C 4.
// ---------------------------------------------------------------------------
__device__ __forceinline__ void jr_path(
    int b, int tid, JRS& S,
    const float* __restrict__ JWin, const float* __restrict__ Jbin,
    const float* __restrict__ JAq, const float* __restrict__ JAk, const float* __restrict__ JAv,
    const float* __restrict__ JBq, const float* __restrict__ JBk, const float* __restrict__ JBv,
    const float* __restrict__ JWout, const float* __restrict__ Jbout,
    const float* __restrict__ RWin, const float* __restrict__ Rbin,
    const float* __restrict__ RAq, const float* __restrict__ RAk, const float* __restrict__ RAv,
    const float* __restrict__ RBq, const float* __restrict__ RBk, const float* __restrict__ RBv,
    const float* __restrict__ RWout, const float* __restrict__ Rbout,
    const float* sdHf, double* sdH, double* sg, double (*sRm)[17],
    double* srs, double* svv, float* sJvp,
    float* __restrict__ out)
{
    const int g  = tid >> 7;
    const int tl = tid & 127;
    const int wg = (tid >> 6) & 1;

    if (tid < 16) sdH[tid] = (double)sdHf[tid];   // consumed much later

    const float* Win  = g ? RWin  : JWin;
    const float* bin_ = g ? Rbin  : Jbin;
    const float* Aq   = g ? RAq   : JAq;
    const float* Ak   = g ? RAk   : JAk;
    const float* Av   = g ? RAv   : JAv;
    const float* Bq   = g ? RBq   : JBq;
    const float* Bk   = g ? RBk   : JBk;
    const float* Bv   = g ? RBv   : JBv;

    // ---- A: h[a][tl] for all 8 agents (x already in S.sx) ----
    {
        float acc[8];
        const float b0 = bin_[tl];
        #pragma unroll
        for (int a = 0; a < 8; ++a) acc[a] = b0;
        #pragma unroll
        for (int c = 0; c < 4; ++c) {
            const float w0 = Win[(4 * c + 0) * NDIM + tl];
            const float w1 = Win[(4 * c + 1) * NDIM + tl];
            const float w2 = Win[(4 * c + 2) * NDIM + tl];
            const float w3 = Win[(4 * c + 3) * NDIM + tl];
            #pragma unroll
            for (int a = 0; a < 8; ++a) {
                const float4 x4 = *(const float4*)&S.sx[a * 16 + 4 * c];
                acc[a] = fmaf(w0, x4.x, acc[a]);
                acc[a] = fmaf(w1, x4.y, acc[a]);
                acc[a] = fmaf(w2, x4.z, acc[a]);
                acc[a] = fmaf(w3, x4.w, acc[a]);
            }
        }
        *(float4*)&S.sh[g][tl][0] =
            make_float4(siluf(acc[0]), siluf(acc[1]), siluf(acc[2]), siluf(acc[3]));
        *(float4*)&S.sh[g][tl][4] =
            make_float4(siluf(acc[4]), siluf(acc[5]), siluf(acc[6]), siluf(acc[7]));
    }
    __syncthreads();

    // ---- B: Q,K,V for all 8 agents; packed agent-pairs; unroll 2 ----
    f32x2 qe2[4];
    {
        f32x2 aq2[4], ak2[4], av2[4];
        const float bq = Bq[tl], bk = Bk[tl], bv = Bv[tl];
        #pragma unroll
        for (int p = 0; p < 4; ++p) {
            aq2[p] = (f32x2){bq, bq}; ak2[p] = (f32x2){bk, bk}; av2[p] = (f32x2){bv, bv};
        }
        const float4* Aq4 = (const float4*)(Aq + tl * NDIM);
        const float4* Ak4 = (const float4*)(Ak + tl * NDIM);
        const float4* Av4 = (const float4*)(Av + tl * NDIM);
        #pragma unroll 2
        for (int c = 0; c < NDIM / 4; ++c) {
            const float4 wq = Aq4[c], wk = Ak4[c], wv = Av4[c];
            const float wqa[4] = {wq.x, wq.y, wq.z, wq.w};
            const float wka[4] = {wk.x, wk.y, wk.z, wk.w};
            const float wva[4] = {wv.x, wv.y, wv.z, wv.w};
            #pragma unroll
            for (int jj = 0; jj < 4; ++jj) {
                const float4 h0 = *(const float4*)&S.sh[g][4 * c + jj][0];
                const float4 h1 = *(const float4*)&S.sh[g][4 * c + jj][4];
                const f32x2* h0p = (const f32x2*)&h0;
                const f32x2* h1p = (const f32x2*)&h1;
                const f32x2 qq = {wqa[jj], wqa[jj]};
                const f32x2 kk2 = {wka[jj], wka[jj]};
                const f32x2 vv2 = {wva[jj], wva[jj]};
                aq2[0] = pkfma(qq, h0p[0], aq2[0]); aq2[1] = pkfma(qq, h0p[1], aq2[1]);
                aq2[2] = pkfma(qq, h1p[0], aq2[2]); aq2[3] = pkfma(qq, h1p[1], aq2[3]);
                ak2[0] = pkfma(kk2, h0p[0], ak2[0]); ak2[1] = pkfma(kk2, h0p[1], ak2[1]);
                ak2[2] = pkfma(kk2, h1p[0], ak2[2]); ak2[3] = pkfma(kk2, h1p[1], ak2[3]);
                av2[0] = pkfma(vv2, h0p[0], av2[0]); av2[1] = pkfma(vv2, h0p[1], av2[1]);
                av2[2] = pkfma(vv2, h1p[0], av2[2]); av2[3] = pkfma(vv2, h1p[1], av2[3]);
            }
        }
        float kk[8], kx[8], kn[8];
        #pragma unroll
        for (int s = 0; s < 8; ++s) {
            const int p = s >> 1, e = s & 1;
            qe2[p][e] = siluf(aq2[p][e]) * LOG2E;
            kk[s] = siluf(ak2[p][e]);
            S.sK[g][tl][s] = kk[s];
            S.sV[g][tl][s] = siluf(av2[p][e]);
            kx[s] = kk[s]; kn[s] = kk[s];
        }
        #pragma unroll
        for (int off = 32; off; off >>= 1) {
            #pragma unroll
            for (int s = 0; s < 8; ++s) {
                kx[s] = fmaxf(kx[s], __shfl_xor(kx[s], off));
                kn[s] = fminf(kn[s], __shfl_xor(kn[s], off));
            }
        }
        if ((tid & 63) == 0) {
            #pragma unroll
            for (int s = 0; s < 8; ++s) { S.skr[g][wg][0][s] = kx[s]; S.skr[g][wg][1][s] = kn[s]; }
        }
    }
    __syncthreads();

    // ---- C: attention row tl, single pass, global-bound shift; unroll 4 ----
    {
        float bnd2 = 0.f;
        #pragma unroll
        for (int s = 0; s < 8; ++s) {
            const float kx = fmaxf(S.skr[g][0][0][s], S.skr[g][1][0][s]);
            const float kn = fminf(S.skr[g][0][1][s], S.skr[g][1][1][s]);
            const float q = qe2[s >> 1][s & 1];
            bnd2 += fmaxf(q * kx, q * kn);
        }
        float l = 0.f;
        f32x2 t2[4];
        #pragma unroll
        for (int p = 0; p < 4; ++p) t2[p] = (f32x2){0.f, 0.f};
        #pragma unroll 4
        for (int j = 0; j < NDIM; ++j) {
            const float4 k0 = *(const float4*)&S.sK[g][j][0];
            const float4 k1 = *(const float4*)&S.sK[g][j][4];
            const f32x2* k0p = (const f32x2*)&k0;
            const f32x2* k1p = (const f32x2*)&k1;
            f32x2 d2 = {-bnd2, 0.f};
            d2 = pkfma(qe2[0], k0p[0], d2);
            d2 = pkfma(qe2[1], k0p[1], d2);
            d2 = pkfma(qe2[2], k1p[0], d2);
            d2 = pkfma(qe2[3], k1p[1], d2);
            const float e = fexp2(d2.x + d2.y);
            const float4 v0 = *(const float4*)&S.sV[g][j][0];
            const float4 v1 = *(const float4*)&S.sV[g][j][4];
            const f32x2* v0p = (const f32x2*)&v0;
            const f32x2* v1p = (const f32x2*)&v1;
            const f32x2 e2 = {e, e};
            l += e;
            t2[0] = pkfma(e2, v0p[0], t2[0]);
            t2[1] = pkfma(e2, v0p[1], t2[1]);
            t2[2] = pkfma(e2, v1p[0], t2[2]);
            t2[3] = pkfma(e2, v1p[1], t2[3]);
        }
        const float rl = frcp(l);
        #pragma unroll
        for (int s = 0; s < 8; ++s)
            S.sz[g][s][tl] = siluf(t2[s >> 1][s & 1] * rl);
    }
    __syncthreads();

    // ---- D: w[s,o] = silu(z @ Wout + bout). R on tids 0-127, J on 128-191 ----
    if (tid < 192) {
        const int gm = (tid < 128) ? 1 : 0;
        const int t2 = (tid < 128) ? tid : tid - 128;
        const int lo2 = gm ? 4 : 3;
        const int outd = 1 << lo2;
        const int s = t2 >> lo2, o = t2 & (outd - 1);
        const float* Wo = gm ? RWout : JWout;
        const float* bo = gm ? Rbout : Jbout;
        float a = bo[o];
        #pragma unroll 8
        for (int c = 0; c < NDIM / 4; ++c) {
            const float4 z4 = *(const float4*)&S.sz[gm][s][4 * c];
            a = fmaf(z4.x, Wo[(4 * c + 0) * outd + o], a);
            a = fmaf(z4.y, Wo[(4 * c + 1) * outd + o], a);
            a = fmaf(z4.z, Wo[(4 * c + 2) * outd + o], a);
            a = fmaf(z4.w, Wo[(4 * c + 3) * outd + o], a);
        }
        S.sw[gm][t2] = siluf(a);
    }
    __syncthreads();

    // ---- J scalar + R group sums ----
    if (tid < 64) {
        float v = S.sw[0][tid];
        #pragma unroll
        for (int off = 32; off; off >>= 1) v += __shfl_xor(v, off);
        if (tid == 0) *sJvp = v;
    } else if (tid < 96) {
        const int t = tid - 64, pq = t >> 3, c = t & 7;
        const int base = c * 16 + pq * 4;
        sg[t] = (double)S.sw[1][base] + (double)S.sw[1][base + 1]
              + (double)S.sw[1][base + 2] + (double)S.sw[1][base + 3];
    }
    __syncthreads();

    // ---- assembly: Rupper, Laplacian Rm, u = (J_eff - Rm Rm^T) dH ----
    const int ii = (tid >> 4) & 15, jj = tid & 15;
    {
        const double rij = sg[((ii >> 3) * 2 + (jj >> 3)) * 8 + (jj & 7)];
        const double rji = sg[((jj >> 3) * 2 + (ii >> 3)) * 8 + (ii & 7)];
        sRm[ii][jj] = rij * rij + rji * rji;
    }
    __syncthreads();

    if (tid < 16) {
        double a = 0.0;
        for (int j = 0; j < 16; ++j) a += sRm[tid][j];
        srs[tid] = a;
    }
    __syncthreads();

    {
        const double v = (ii == jj) ? srs[ii] : -sRm[ii][jj];
        __syncthreads();
        sRm[ii][jj] = v;
    }
    __syncthreads();

    if (tid < 16) {
        double a = 0.0;
        for (int j = 0; j < 16; ++j) a += sRm[tid][j] * sdH[j];
        svv[tid] = a;
    }
    __syncthreads();

    if (tid < 16) {
        double a = 0.0;
        for (int k = 0; k < 16; ++k) a += sRm[tid][k] * svv[k];
        const double sj = (double)(*sJvp);
        const double jterm = (tid < 8) ? 2.0 * sj * sdH[8 + tid]
                                       : -2.0 * sj * sdH[tid - 8];
        out[b * 16 + tid] = (float)(jterm - a);
    }
}

// ---------------------------------------------------------------------------
// One kernel, one block per batch: H phase -> LDS handoff -> JR phase.
// ---------------------------------------------------------------------------
__global__ __launch_bounds__(256) void k_all(
    const float* __restrict__ x,
    const float* __restrict__ HWin, const float* __restrict__ Hbin,
    const float* __restrict__ HAq, const float* __restrict__ HAk, const float* __restrict__ HAv,
    const float* __restrict__ HBq, const float* __restrict__ HBk, const float* __restrict__ HBv,
    const float* __restrict__ HWout, const float* __restrict__ Hbout,
    const float* __restrict__ JWin, const float* __restrict__ Jbin,
    const float* __restrict__ JAq, const float* __restrict__ JAk, const float* __restrict__ JAv,
    const float* __restrict__ JBq, const float* __restrict__ JBk, const float* __restrict__ JBv,
    const float* __restrict__ JWout, const float* __restrict__ Jbout,
    const float* __restrict__ RWin, const float* __restrict__ Rbin,
    const float* __restrict__ RAq, const float* __restrict__ RAk, const float* __restrict__ RAv,
    const float* __restrict__ RBq, const float* __restrict__ RBk, const float* __restrict__ RBv,
    const float* __restrict__ RWout, const float* __restrict__ Rbout,
    float* __restrict__ out)
{
    __shared__ SU S;
    __shared__ float  sdHf[16];
    __shared__ float  sJv;
    __shared__ double sdH[16], sg[32], sRm[16][17], srs[16], svv[16];

    const int b = blockIdx.x;

    h_path(b, threadIdx.x, S.h, x, HWin, Hbin, HAq, HAk, HAv,
           HBq, HBk, HBv, HWout, Hbout, sdHf);
    __syncthreads();   // inter-phase: sdHf visible; HS buffers dead

    jr_path(b, threadIdx.x, S.jr,
            JWin, Jbin, JAq, JAk, JAv, JBq, JBk, JBv, JWout, Jbout,
            RWin, Rbin, RAq, RAk, RAv, RBq, RBk, RBv, RWout, Rbout,
            sdHf, sdH, sg, sRm, srs, svv, &sJv, out);
}

// ---------------------------------------------------------------------------
extern "C" void kernel_launch(void* const* d_in, const int* in_sizes, int n_in,
                              void* d_out, int out_size, void* d_ws, size_t ws_size,
                              hipStream_t stream)
{
    const float* x = (const float*)d_in[0];
    float* out = (float*)d_out;

#define ARGS10(base) \
    (const float*)d_in[(base) + 0], (const float*)d_in[(base) + 1], \
    (const float*)d_in[(base) + 2], (const float*)d_in[(base) + 3], \
    (const float*)d_in[(base) + 4], (const float*)d_in[(base) + 5], \
    (const float*)d_in[(base) + 6], (const float*)d_in[(base) + 7], \
    (const float*)d_in[(base) + 8], (const float*)d_in[(base) + 9]

    k_all<<<dim3(512), dim3(256), 0, stream>>>(
        x, ARGS10(1), ARGS10(11), ARGS10(21), out);
#undef ARGS10
}